// Round 8
// baseline (1425.993 us; speedup 1.0000x reference)
//
#include <hip/hip_runtime.h>
#include <hip/hip_bf16.h>
#include <math.h>

#define DM 256
#define NHEAD 8
#define HD 32
#define NL 4
#define BATCH 8
#define SEQ 4096
#define KCLS 10
#define M_TOK (BATCH*SEQ)   // 32768

#define BM 128
#define BN 128
#define BKG 64

#define PADPOS 5120          // padded sorted positions per batch (each cluster 64-aligned)
#define NWIN (PADPOS/64)     // 80 msg windows per batch
#define KVWIN (PADPOS/512)   // 10 kv windows per batch (512 positions each)
#define PART_STRIDE (KCLS * 1056)   // per-block partial: 10 clusters x (1024 KV + 32 Ks)

using bf16x8 = __attribute__((ext_vector_type(8))) short;
using f32x4  = __attribute__((ext_vector_type(4))) float;

__device__ __forceinline__ unsigned short f2bf(float f) {
    __hip_bfloat16 b = __float2bfloat16(f);
    return __builtin_bit_cast(unsigned short, b);
}
__device__ __forceinline__ float bf2f(unsigned short u) {
    unsigned v = (unsigned)u << 16;
    return __builtin_bit_cast(float, v);
}

__device__ __forceinline__ float wave_reduce_sum(float v) {
    #pragma unroll
    for (int off = 32; off > 0; off >>= 1) v += __shfl_xor(v, off, 64);
    return v;
}

// ---------------- init: x = feat (fp32), xm[:,0:256] = bf16(feat) ----------------
__global__ __launch_bounds__(256) void init_kernel(const float* __restrict__ feat,
                                                   float* __restrict__ x,
                                                   unsigned short* __restrict__ xm) {
    int i = blockIdx.x * 256 + threadIdx.x;      // over M_TOK*64 quads
    int row = i >> 6, c4 = (i & 63) * 4;
    float4 v = *(const float4*)(feat + (size_t)row * DM + c4);
    *(float4*)(x + (size_t)row * DM + c4) = v;
    ushort4 u; u.x = f2bf(v.x); u.y = f2bf(v.y); u.z = f2bf(v.z); u.w = f2bf(v.w);
    *(ushort4*)(xm + (size_t)row * 512 + c4) = u;
}

// ---------------- routing ----------------
__global__ void route_kernel(const float* __restrict__ x, const float* __restrict__ fc,
                             int* __restrict__ seg) {
    int wid = (int)((blockIdx.x * (size_t)blockDim.x + threadIdx.x) >> 6);
    int lane = threadIdx.x & 63;
    if (wid >= M_TOK) return;
    int b = wid / SEQ;
    float4 xv = *(const float4*)(x + (size_t)wid * DM + lane * 4);
    float nb2 = xv.x*xv.x + xv.y*xv.y + xv.z*xv.z + xv.w*xv.w;
    nb2 = wave_reduce_sum(nb2);
    float nb = sqrtf(nb2);
    float best = -1e30f; int bestk = 0;
    for (int k = 0; k < KCLS; ++k) {
        float4 fv = *(const float4*)(fc + ((size_t)(b * KCLS + k)) * DM + lane * 4);
        float d = fv.x*xv.x + fv.y*xv.y + fv.z*xv.z + fv.w*xv.w;
        float n = fv.x*fv.x + fv.y*fv.y + fv.z*fv.z + fv.w*fv.w;
        d = wave_reduce_sum(d);
        n = wave_reduce_sum(n);
        float sim = d / fmaxf(sqrtf(n) * nb, 1e-8f);
        if (sim > best) { best = sim; bestk = k; }
    }
    if (lane == 0) seg[wid] = bestk;
}

// ---------------- deterministic cluster counting-sort (per batch, 64-aligned clusters) ----------------
__global__ __launch_bounds__(256) void seg_count(const int* __restrict__ seg,
                                                 int* __restrict__ cnt) {
    __shared__ int wc[4][KCLS];
    int b = blockIdx.x >> 4, chunk = blockIdx.x & 15;
    int t = threadIdx.x, w = t >> 6, lane = t & 63;
    int c = seg[b * SEQ + chunk * 256 + t];
    #pragma unroll
    for (int cc = 0; cc < KCLS; ++cc) {
        unsigned long long m = __ballot(c == cc);
        if (lane == 0) wc[w][cc] = __popcll(m);
    }
    __syncthreads();
    if (t < KCLS)
        cnt[(b * 16 + chunk) * KCLS + t] = wc[0][t] + wc[1][t] + wc[2][t] + wc[3][t];
}

__global__ __launch_bounds__(256) void seg_scan(const int* __restrict__ cnt,
                                                int* __restrict__ chunkbase,
                                                int* __restrict__ wseg,
                                                int* __restrict__ psegp) {
    __shared__ int sTot[BATCH][KCLS];
    __shared__ int sBase[BATCH][KCLS];
    int tid = threadIdx.x;
    if (tid < BATCH * KCLS) {
        int b = tid / KCLS, c = tid % KCLS;
        int run = 0;
        #pragma unroll
        for (int j = 0; j < 16; ++j) run += cnt[(b * 16 + j) * KCLS + c];
        sTot[b][c] = run;
    }
    __syncthreads();
    if (tid < BATCH) {
        int b = tid, pb = 0;
        for (int c = 0; c < KCLS; ++c) {
            sBase[b][c] = pb;
            int psz = (sTot[b][c] + 63) & ~63;
            int w0 = pb >> 6, w1 = (pb + psz) >> 6;
            for (int w = w0; w < w1; ++w) wseg[b * NWIN + w] = c;
            pb += psz;
        }
        for (int w = pb >> 6; w < NWIN; ++w) wseg[b * NWIN + w] = -1;
    }
    __syncthreads();
    for (int i = tid; i < BATCH * PADPOS; i += 256) {
        int b = i / PADPOS, pos = i % PADPOS;
        int c = KCLS - 1;
        #pragma unroll
        for (int cc = KCLS - 1; cc >= 1; --cc)
            if (pos < sBase[b][cc]) c = cc - 1;
        psegp[i] = c;
    }
    if (tid < BATCH * KCLS) {
        int b = tid / KCLS, c = tid % KCLS;
        int pre = 0;
        #pragma unroll
        for (int j = 0; j < 16; ++j) {
            chunkbase[(b * 16 + j) * KCLS + c] = sBase[b][c] + pre;
            pre += cnt[(b * 16 + j) * KCLS + c];
        }
    }
}

__global__ __launch_bounds__(256) void seg_scatter(const int* __restrict__ seg,
                                                   const int* __restrict__ chunkbase,
                                                   int* __restrict__ pidxp) {
    __shared__ int wc[4][KCLS];
    int b = blockIdx.x >> 4, chunk = blockIdx.x & 15;
    int t = threadIdx.x, w = t >> 6, lane = t & 63;
    int l = chunk * 256 + t;
    int c = seg[b * SEQ + l];
    int rank_w = 0;
    #pragma unroll
    for (int cc = 0; cc < KCLS; ++cc) {
        unsigned long long m = __ballot(c == cc);
        if (lane == 0) wc[w][cc] = __popcll(m);
        if (cc == c) rank_w = __popcll(m & ((1ULL << lane) - 1ULL));
    }
    __syncthreads();
    int rank = rank_w;
    for (int wp = 0; wp < 4; ++wp)
        if (wp < w) rank += wc[wp][c];
    int pos = chunkbase[(b * 16 + chunk) * KCLS + c] + rank;
    pidxp[b * PADPOS + pos] = l;
}

// ---------------- weight transpose+convert: src [K][N] fp32 -> dst [N][K] bf16 ----------------
__global__ __launch_bounds__(256) void transpose_bf16(const float* __restrict__ src,
                                                      unsigned short* __restrict__ dst,
                                                      int K, int N) {
    __shared__ float s[64][65];
    int k0 = blockIdx.x * 64, n0 = blockIdx.y * 64;
    int t = threadIdx.x;
    int r = t >> 4, c4 = (t & 15) * 4;
    #pragma unroll
    for (int i = 0; i < 4; ++i) {
        float4 v = *(const float4*)(src + (size_t)(k0 + r + i*16) * N + n0 + c4);
        s[c4+0][r+i*16] = v.x; s[c4+1][r+i*16] = v.y;
        s[c4+2][r+i*16] = v.z; s[c4+3][r+i*16] = v.w;
    }
    __syncthreads();
    #pragma unroll
    for (int i = 0; i < 4; ++i) {
        int nr = r + i*16;
        ushort4 u;
        u.x = f2bf(s[nr][c4+0]); u.y = f2bf(s[nr][c4+1]);
        u.z = f2bf(s[nr][c4+2]); u.w = f2bf(s[nr][c4+3]);
        *(ushort4*)(dst + (size_t)(n0 + nr) * K + k0 + c4) = u;
    }
}

// ---------------- bf16 MFMA GEMM (128x128 tile): out = act( A[M,KD] * Bt[N,KD]^T ) ----------------
template<int KD, int AS, int MODE>
__global__ __launch_bounds__(256) void mfma_gemm(
    const unsigned short* __restrict__ A, const unsigned short* __restrict__ Bt,
    unsigned short* __restrict__ Ob0, unsigned short* __restrict__ Ob1,
    unsigned short* __restrict__ Ob2)
{
    __shared__ unsigned short As[BM * BKG];
    __shared__ unsigned short Bs[BN * BKG];
    int t = threadIdx.x;
    int lane = t & 63;
    int w = t >> 6;
    int wm = w & 1, wn = w >> 1;         // 2x2 wave grid, each wave 64x64
    int bm = blockIdx.x * BM;
    int bn = blockIdx.y * BN;

    f32x4 acc[4][4];
    #pragma unroll
    for (int m = 0; m < 4; ++m)
        #pragma unroll
        for (int n = 0; n < 4; ++n)
            acc[m][n] = (f32x4){0.f, 0.f, 0.f, 0.f};

    for (int k0 = 0; k0 < KD; k0 += BKG) {
        #pragma unroll
        for (int i = 0; i < 4; ++i) {
            int chunk = i * 256 + t;
            int row = chunk >> 3, cc = chunk & 7;
            __builtin_amdgcn_global_load_lds(
                (const __attribute__((address_space(1))) void*)(A + (size_t)(bm + row) * AS + k0 + cc * 8),
                (__attribute__((address_space(3))) void*)((char*)As + chunk * 16), 16, 0, 0);
            __builtin_amdgcn_global_load_lds(
                (const __attribute__((address_space(1))) void*)(Bt + (size_t)(bn + row) * KD + k0 + cc * 8),
                (__attribute__((address_space(3))) void*)((char*)Bs + chunk * 16), 16, 0, 0);
        }
        asm volatile("s_waitcnt vmcnt(0)");
        __syncthreads();
        #pragma unroll
        for (int kk = 0; kk < 2; ++kk) {
            int kbyte = (kk * 32 + (lane >> 4) * 8) * 2;
            bf16x8 af[4], bfr[4];
            #pragma unroll
            for (int m = 0; m < 4; ++m)
                af[m] = *(const bf16x8*)((const char*)As + (wm*64 + m*16 + (lane & 15)) * 128 + kbyte);
            #pragma unroll
            for (int n = 0; n < 4; ++n)
                bfr[n] = *(const bf16x8*)((const char*)Bs + (wn*64 + n*16 + (lane & 15)) * 128 + kbyte);
            #pragma unroll
            for (int m = 0; m < 4; ++m)
                #pragma unroll
                for (int n = 0; n < 4; ++n)
                    acc[m][n] = __builtin_amdgcn_mfma_f32_16x16x32_bf16(af[m], bfr[n], acc[m][n], 0, 0, 0);
        }
        __syncthreads();
    }

    int row0 = bm + wm * 64 + (lane >> 4) * 4;
    int lcol = wn * 64 + (lane & 15);
    if (MODE == 1) {
        unsigned short* Obuf = (bn < 256) ? Ob0 : (bn < 512) ? Ob1 : Ob2;
        const bool act = (bn < 512);
        int cc0 = (bn & 255) + lcol;
        #pragma unroll
        for (int m = 0; m < 4; ++m)
            #pragma unroll
            for (int n = 0; n < 4; ++n)
                #pragma unroll
                for (int j = 0; j < 4; ++j) {
                    float v = acc[m][n][j];
                    if (act) v = (v > 0.f) ? v + 1.f : expf(v);
                    Obuf[(size_t)(row0 + m*16 + j) * 256 + cc0 + n*16] = f2bf(v);
                }
    } else {
        #pragma unroll
        for (int m = 0; m < 4; ++m)
            #pragma unroll
            for (int n = 0; n < 4; ++n)
                #pragma unroll
                for (int j = 0; j < 4; ++j)
                    Ob0[(size_t)(row0 + m*16 + j) * 512 + bn + lcol + n*16] =
                        f2bf(fmaxf(acc[m][n][j], 0.f));
    }
}

// ---------------- fused GEMM + LayerNorm (full rows per block: BM=64, BN=256) ----------------
template<int KD, int LNMODE>
__global__ __launch_bounds__(256) void gemm_ln(
    const unsigned short* __restrict__ A, const unsigned short* __restrict__ Bt,
    const float* __restrict__ g, const float* __restrict__ bb,
    float* __restrict__ x, unsigned short* __restrict__ xm)
{
    __shared__ unsigned short As[64 * BKG];
    __shared__ unsigned short Bs[256 * BKG];
    __shared__ float redS[4][64];
    __shared__ float redQ[4][64];
    int t = threadIdx.x;
    int lane = t & 63;
    int w = t >> 6;                      // wave covers cols [w*64, w*64+64)
    int li = lane & 15, lg = lane >> 4;
    int bm = blockIdx.x * 64;

    f32x4 acc[4][4];
    #pragma unroll
    for (int m = 0; m < 4; ++m)
        #pragma unroll
        for (int n = 0; n < 4; ++n)
            acc[m][n] = (f32x4){0.f, 0.f, 0.f, 0.f};

    for (int k0 = 0; k0 < KD; k0 += BKG) {
        #pragma unroll
        for (int i = 0; i < 2; ++i) {
            int chunk = i * 256 + t;
            int row = chunk >> 3, cc = chunk & 7;
            __builtin_amdgcn_global_load_lds(
                (const __attribute__((address_space(1))) void*)(A + (size_t)(bm + row) * KD + k0 + cc * 8),
                (__attribute__((address_space(3))) void*)((char*)As + chunk * 16), 16, 0, 0);
        }
        #pragma unroll
        for (int i = 0; i < 8; ++i) {
            int chunk = i * 256 + t;
            int row = chunk >> 3, cc = chunk & 7;
            __builtin_amdgcn_global_load_lds(
                (const __attribute__((address_space(1))) void*)(Bt + (size_t)row * KD + k0 + cc * 8),
                (__attribute__((address_space(3))) void*)((char*)Bs + chunk * 16), 16, 0, 0);
        }
        asm volatile("s_waitcnt vmcnt(0)");
        __syncthreads();
        #pragma unroll
        for (int kk = 0; kk < 2; ++kk) {
            int kbyte = (kk * 32 + lg * 8) * 2;
            bf16x8 af[4], bfr[4];
            #pragma unroll
            for (int m = 0; m < 4; ++m)
                af[m] = *(const bf16x8*)((const char*)As + (m*16 + li) * 128 + kbyte);
            #pragma unroll
            for (int n = 0; n < 4; ++n)
                bfr[n] = *(const bf16x8*)((const char*)Bs + (w*64 + n*16 + li) * 128 + kbyte);
            #pragma unroll
            for (int m = 0; m < 4; ++m)
                #pragma unroll
                for (int n = 0; n < 4; ++n)
                    acc[m][n] = __builtin_amdgcn_mfma_f32_16x16x32_bf16(af[m], bfr[n], acc[m][n], 0, 0, 0);
        }
        __syncthreads();
    }

    float vs[4][4], vq[4][4];
    #pragma unroll
    for (int m = 0; m < 4; ++m)
        #pragma unroll
        for (int j = 0; j < 4; ++j) {
            float s = 0.f, q = 0.f;
            #pragma unroll
            for (int n = 0; n < 4; ++n) {
                float v = acc[m][n][j];
                s += v; q += v * v;
            }
            #pragma unroll
            for (int msk = 1; msk < 16; msk <<= 1) {
                s += __shfl_xor(s, msk, 64);
                q += __shfl_xor(q, msk, 64);
            }
            vs[m][j] = s; vq[m][j] = q;
        }
    if (li == 0) {
        #pragma unroll
        for (int m = 0; m < 4; ++m)
            #pragma unroll
            for (int j = 0; j < 4; ++j) {
                redS[w][m*16 + lg*4 + j] = vs[m][j];
                redQ[w][m*16 + lg*4 + j] = vq[m][j];
            }
    }
    __syncthreads();

    float gv[4], bv[4];
    #pragma unroll
    for (int n = 0; n < 4; ++n) {
        int col = w*64 + n*16 + li;
        gv[n] = g[col]; bv[n] = bb[col];
    }
    #pragma unroll
    for (int m = 0; m < 4; ++m)
        #pragma unroll
        for (int j = 0; j < 4; ++j) {
            int r = m*16 + lg*4 + j;
            float S = redS[0][r] + redS[1][r] + redS[2][r] + redS[3][r];
            float Q = redQ[0][r] + redQ[1][r] + redQ[2][r] + redQ[3][r];
            float mu = S * (1.f / 256.f);
            float var = Q * (1.f / 256.f) - mu * mu;
            float rs = rsqrtf(var + 1e-5f);
            #pragma unroll
            for (int n = 0; n < 4; ++n) {
                int col = w*64 + n*16 + li;
                float o = gv[n] * (acc[m][n][j] - mu) * rs + bv[n];
                if (LNMODE == 1) {
                    xm[(size_t)(bm + r) * 512 + 256 + col] = f2bf(o);
                } else {
                    size_t idx = (size_t)(bm + r) * 256 + col;
                    float xv = x[idx] + o;
                    x[idx] = xv;
                    xm[(size_t)(bm + r) * 512 + col] = f2bf(xv);
                }
            }
        }
}

// ---------------- KV / Ksum partials over padded cluster-sorted tokens ----------------
__global__ __launch_bounds__(256) void kv_kernel(
    const unsigned short* __restrict__ Kf, const unsigned short* __restrict__ V,
    const int* __restrict__ pidxp, const int* __restrict__ psegp,
    float* __restrict__ part)
{
    __shared__ float mg[KCLS * 1056];
    __shared__ int sIdx[512];
    __shared__ int sSeg[512];
    int blk = blockIdx.x;
    int s = blk % KVWIN;
    int bh = blk / KVWIN;
    int b = bh >> 3, h = bh & 7;
    int t = threadIdx.x;
    int d = t >> 3, e0 = (t & 7) * 4;

    for (int i = t; i < KCLS * 1056; i += 256) mg[i] = 0.f;
    sIdx[t] = pidxp[b * PADPOS + s * 512 + t];
    sIdx[t + 256] = pidxp[b * PADPOS + s * 512 + 256 + t];
    sSeg[t] = psegp[b * PADPOS + s * 512 + t];
    sSeg[t + 256] = psegp[b * PADPOS + s * 512 + 256 + t];
    __syncthreads();

    const unsigned short* Kp = Kf + (size_t)(b * SEQ) * DM + h * HD + d;
    const unsigned short* Vp = V  + (size_t)(b * SEQ) * DM + h * HD + e0;

    float4 a = {0.f, 0.f, 0.f, 0.f};
    float ks = 0.f;
    int ccur = __builtin_amdgcn_readfirstlane(sSeg[0]);

    for (int l0 = 0; l0 < 512; l0 += 8) {
        int idxv[8], csegv[8];
        #pragma unroll
        for (int u = 0; u < 8; ++u) { idxv[u] = sIdx[l0 + u]; csegv[u] = sSeg[l0 + u]; }
        unsigned short ku[8]; ushort4 vu[8];
        #pragma unroll
        for (int u = 0; u < 8; ++u) {
            if (idxv[u] >= 0) {
                size_t off = (size_t)idxv[u] * DM;
                ku[u] = Kp[off];
                vu[u] = *(const ushort4*)(Vp + off);
            } else {
                ku[u] = 0; vu[u] = (ushort4){0, 0, 0, 0};
            }
        }
        #pragma unroll
        for (int u = 0; u < 8; ++u) {
            int c = __builtin_amdgcn_readfirstlane(csegv[u]);
            if (c != ccur) {
                *(float4*)(mg + ccur * 1056 + d * 32 + e0) = a;
                if ((t & 7) == 0) mg[ccur * 1056 + 1024 + d] = ks;
                a = (float4){0.f, 0.f, 0.f, 0.f};
                ks = 0.f;
                ccur = c;
            }
            float kd = bf2f(ku[u]);
            float4 v4;
            v4.x = bf2f(vu[u].x); v4.y = bf2f(vu[u].y);
            v4.z = bf2f(vu[u].z); v4.w = bf2f(vu[u].w);
            a.x = fmaf(kd, v4.x, a.x); a.y = fmaf(kd, v4.y, a.y);
            a.z = fmaf(kd, v4.z, a.z); a.w = fmaf(kd, v4.w, a.w);
            ks += kd;
        }
    }
    *(float4*)(mg + ccur * 1056 + d * 32 + e0) = a;
    if ((t & 7) == 0) mg[ccur * 1056 + 1024 + d] = ks;
    __syncthreads();

    float* pb = part + (size_t)blk * PART_STRIDE;
    for (int i = t; i < (KCLS * 1056) / 4; i += 256) {
        float4 v = *(const float4*)(mg + i * 4);
        *(float4*)(pb + i * 4) = v;
    }
}

// ---------------- reduce partials -> KV, Ks ----------------
__global__ __launch_bounds__(256) void kv_reduce(
    const float* __restrict__ part, float* __restrict__ KV, float* __restrict__ Ks)
{
    int blk = blockIdx.x;          // bh * KCLS + c
    int c = blk % KCLS;
    int bh = blk / KCLS;
    int b = bh >> 3, h = bh & 7;
    int t = threadIdx.x;
    const float* pb = part + (size_t)bh * KVWIN * PART_STRIDE + c * 1056;
    float4 acc = {0, 0, 0, 0};
    float ka = 0.f;
    #pragma unroll
    for (int s = 0; s < KVWIN; ++s) {
        float4 v = *(const float4*)(pb + (size_t)s * PART_STRIDE + t * 4);
        acc.x += v.x; acc.y += v.y; acc.z += v.z; acc.w += v.w;
        if (t < 32) ka += pb[(size_t)s * PART_STRIDE + 1024 + t];
    }
    *(float4*)(KV + ((size_t)(b * KCLS + c) * NHEAD + h) * HD * HD + t * 4) = acc;
    if (t < 32) Ks[((size_t)(b * KCLS + c) * NHEAD + h) * HD + t] = ka;
}

// ---------------- msg: 64 cluster-uniform sorted tokens per block, KV in LDS/regs ----------------
__global__ __launch_bounds__(256) void msg_kernel(
    const unsigned short* __restrict__ Q, const float* __restrict__ KV,
    const float* __restrict__ Ks, const int* __restrict__ pidxp,
    const int* __restrict__ wseg, unsigned short* __restrict__ msgb)
{
    int b = blockIdx.x / NWIN, w = blockIdx.x % NWIN;
    int c = wseg[b * NWIN + w];
    if (c < 0) return;
    __shared__ unsigned short sQ[64 * DM];          // 32 KB gathered Q tile
    __shared__ unsigned short kvb[NHEAD * HD * HD]; // 16 KB bf16 KV[c]
    __shared__ float sKs[NHEAD][HD];
    __shared__ int sTok[64];
    int t = threadIdx.x;

    if (t < 64) sTok[t] = pidxp[b * PADPOS + w * 64 + t];
    { int h = t >> 5, d = t & 31;
      sKs[h][d] = Ks[((size_t)(b * KCLS + c) * NHEAD + h) * HD + d]; }
    const float* kvsrc = KV + (size_t)(b * KCLS + c) * NHEAD * HD * HD;
    #pragma unroll
    for (int i = 0; i < 8; ++i) {
        int q = i * 256 + t;
        float4 v = ((const float4*)kvsrc)[q];
        ushort4 u; u.x = f2bf(v.x); u.y = f2bf(v.y); u.z = f2bf(v.z); u.w = f2bf(v.w);
        ((ushort4*)kvb)[q] = u;
    }
    #pragma unroll
    for (int i = 0; i < 8; ++i) {
        int q = i * 256 + t;                 // 2048 chunks of 8 bf16
        int row = q >> 5, col8 = (q & 31) * 8;
        int tok = pidxp[b * PADPOS + w * 64 + row];
        bf16x8 v;
        if (tok >= 0)
            v = *(const bf16x8*)(Q + (size_t)(b * SEQ + tok) * DM + col8);
        else
            v = (bf16x8){0,0,0,0,0,0,0,0};
        *(bf16x8*)(sQ + row * DM + col8) = v;
    }
    __syncthreads();

    int h = t >> 5, e = t & 31;
    float kvreg[32], ksreg[32];
    #pragma unroll
    for (int d = 0; d < 32; ++d)
        kvreg[d] = bf2f(kvb[h * 1024 + d * 32 + e]);
    #pragma unroll
    for (int d = 0; d < 32; ++d)
        ksreg[d] = sKs[h][d];

    for (int r = 0; r < 64; ++r) {
        float macc = 0.f, zacc = 0.f;
        #pragma unroll
        for (int d8 = 0; d8 < 4; ++d8) {
            bf16x8 qv = *(const bf16x8*)(sQ + r * DM + h * 32 + d8 * 8);
            #pragma unroll
            for (int j = 0; j < 8; ++j) {
                float qf = bf2f((unsigned short)qv[j]);
                macc = fmaf(qf, kvreg[d8 * 8 + j], macc);
                zacc = fmaf(qf, ksreg[d8 * 8 + j], zacc);
            }
        }
        int tok = sTok[r];
        if (tok >= 0)
            msgb[(size_t)(b * SEQ + tok) * DM + t] = f2bf(macc / (zacc + 1e-6f));
    }
}

extern "C" void kernel_launch(void* const* d_in, const int* in_sizes, int n_in,
                              void* d_out, int out_size, void* d_ws, size_t ws_size,
                              hipStream_t stream)
{
    const float* feat = (const float*)d_in[1];
    const float* fc   = (const float*)d_in[2];
    const float* Wq   = (const float*)d_in[3];
    const float* Wk   = (const float*)d_in[4];
    const float* Wv   = (const float*)d_in[5];
    const float* Wm   = (const float*)d_in[6];
    const float* W1   = (const float*)d_in[7];
    const float* W2   = (const float*)d_in[8];
    const float* g1   = (const float*)d_in[9];
    const float* b1   = (const float*)d_in[10];
    const float* g2   = (const float*)d_in[11];
    const float* b2   = (const float*)d_in[12];
    float* x = (float*)d_out;

    char* ws = (char*)d_ws;
    auto alloc = [&](size_t bytes) { char* p = ws; ws += (bytes + 255) & ~(size_t)255; return p; };
    int*   seg   = (int*)  alloc((size_t)M_TOK * 4);
    int*   cnt   = (int*)  alloc((size_t)BATCH * 16 * KCLS * 4);
    int*   cbase = (int*)  alloc((size_t)BATCH * 16 * KCLS * 4);
    int*   pidxp = (int*)  alloc((size_t)BATCH * PADPOS * 4);
    int*   psegp = (int*)  alloc((size_t)BATCH * PADPOS * 4);
    int*   wseg  = (int*)  alloc((size_t)BATCH * NWIN * 4);
    float* KV    = (float*)alloc((size_t)BATCH * KCLS * NHEAD * HD * HD * 4);
    float* Ks    = (float*)alloc((size_t)BATCH * KCLS * NHEAD * HD * 4);
    float* part  = (float*)alloc((size_t)BATCH * NHEAD * KVWIN * PART_STRIDE * 4);
    unsigned short* xm = (unsigned short*)alloc((size_t)M_TOK * 512 * 2);
    char* bufA = alloc((size_t)M_TOK * 512 * 2);   // Qb bf16 [M][256] then hb bf16 [M][512]
    char* bufB = alloc((size_t)M_TOK * 256 * 2);   // Kb bf16
    char* bufC = alloc((size_t)M_TOK * 256 * 2);   // Vb bf16 then msgb bf16
    unsigned short* WqkvT = (unsigned short*)alloc((size_t)NL * 768 * 256 * 2);
    unsigned short* WmT   = (unsigned short*)alloc((size_t)NL * 256 * 256 * 2);
    unsigned short* W1T   = (unsigned short*)alloc((size_t)NL * 512 * 512 * 2);
    unsigned short* W2T   = (unsigned short*)alloc((size_t)NL * 256 * 512 * 2);

    unsigned short* Qb = (unsigned short*)bufA;
    unsigned short* hb = (unsigned short*)bufA;
    unsigned short* Kb = (unsigned short*)bufB;
    unsigned short* Vb = (unsigned short*)bufC;
    unsigned short* msgb = (unsigned short*)bufC;

    for (int li = 0; li < NL; ++li) {
        transpose_bf16<<<dim3(4, 4), 256, 0, stream>>>(Wq + (size_t)li*65536, WqkvT + (size_t)li*768*256, 256, 256);
        transpose_bf16<<<dim3(4, 4), 256, 0, stream>>>(Wk + (size_t)li*65536, WqkvT + (size_t)li*768*256 + 65536, 256, 256);
        transpose_bf16<<<dim3(4, 4), 256, 0, stream>>>(Wv + (size_t)li*65536, WqkvT + (size_t)li*768*256 + 131072, 256, 256);
        transpose_bf16<<<dim3(4, 4), 256, 0, stream>>>(Wm + (size_t)li*65536, WmT + (size_t)li*65536, 256, 256);
        transpose_bf16<<<dim3(8, 8), 256, 0, stream>>>(W1 + (size_t)li*262144, W1T + (size_t)li*262144, 512, 512);
        transpose_bf16<<<dim3(8, 4), 256, 0, stream>>>(W2 + (size_t)li*131072, W2T + (size_t)li*131072, 512, 256);
    }

    init_kernel<<<8192, 256, 0, stream>>>(feat, x, xm);
    route_kernel<<<8192, 256, 0, stream>>>(feat, fc, seg);

    // deterministic padded cluster sort (once; reused by all layers)
    seg_count<<<BATCH * 16, 256, 0, stream>>>(seg, cnt);
    seg_scan<<<1, 256, 0, stream>>>(cnt, cbase, wseg, psegp);
    hipMemsetAsync(pidxp, 0xFF, (size_t)BATCH * PADPOS * 4, stream);
    seg_scatter<<<BATCH * 16, 256, 0, stream>>>(seg, cbase, pidxp);

    for (int li = 0; li < NL; ++li) {
        const unsigned short* wqkv = WqkvT + (size_t)li * 768 * 256;
        const unsigned short* wm   = WmT + (size_t)li * 65536;
        const unsigned short* w1   = W1T + (size_t)li * 262144;
        const unsigned short* w2   = W2T + (size_t)li * 131072;

        mfma_gemm<256, 512, 1><<<dim3(256, 6), 256, 0, stream>>>(xm, wqkv, Qb, Kb, Vb);

        kv_kernel<<<BATCH * NHEAD * KVWIN, 256, 0, stream>>>(Kb, Vb, pidxp, psegp, part);
        kv_reduce<<<BATCH * NHEAD * KCLS, 256, 0, stream>>>(part, KV, Ks);

        msg_kernel<<<BATCH * NWIN, 256, 0, stream>>>(Qb, KV, Ks, pidxp, wseg, msgb);

        gemm_ln<256, 1><<<512, 256, 0, stream>>>(msgb, wm, g1 + li * DM, b1 + li * DM, nullptr, xm);

        mfma_gemm<512, 512, 2><<<dim3(256, 4), 256, 0, stream>>>(xm, w1, hb, nullptr, nullptr);

        gemm_ln<512, 2><<<512, 256, 0, stream>>>(hb, w2, g2 + li * DM, b2 + li * DM, x, xm);
    }
}

// Round 9
// 997.105 us; speedup vs baseline: 1.4301x; 1.4301x over previous
//
#include <hip/hip_runtime.h>
#include <hip/hip_bf16.h>
#include <math.h>

#define DM 256
#define NHEAD 8
#define HD 32
#define NL 4
#define BATCH 8
#define SEQ 4096
#define KCLS 10
#define M_TOK (BATCH*SEQ)   // 32768

#define BM 128
#define BN 128
#define BKG 64

#define PADPOS 5120          // padded sorted positions per batch (each cluster 64-aligned)
#define NWIN (PADPOS/64)     // 80 msg windows per batch
#define KVWIN (PADPOS/512)   // 10 kv windows per batch (512 positions each)
#define PART_STRIDE (KCLS * 1056)   // per-block partial: 10 clusters x (1024 KV + 32 Ks)

using bf16x8 = __attribute__((ext_vector_type(8))) short;
using f32x4  = __attribute__((ext_vector_type(4))) float;

__device__ __forceinline__ unsigned short f2bf(float f) {
    __hip_bfloat16 b = __float2bfloat16(f);
    return __builtin_bit_cast(unsigned short, b);
}
__device__ __forceinline__ float bf2f(unsigned short u) {
    unsigned v = (unsigned)u << 16;
    return __builtin_bit_cast(float, v);
}

__device__ __forceinline__ float wave_reduce_sum(float v) {
    #pragma unroll
    for (int off = 32; off > 0; off >>= 1) v += __shfl_xor(v, off, 64);
    return v;
}

// ---------------- init: x = feat (fp32), xm[:,0:256] = bf16(feat) ----------------
__global__ __launch_bounds__(256) void init_kernel(const float* __restrict__ feat,
                                                   float* __restrict__ x,
                                                   unsigned short* __restrict__ xm) {
    int i = blockIdx.x * 256 + threadIdx.x;      // over M_TOK*64 quads
    int row = i >> 6, c4 = (i & 63) * 4;
    float4 v = *(const float4*)(feat + (size_t)row * DM + c4);
    *(float4*)(x + (size_t)row * DM + c4) = v;
    ushort4 u; u.x = f2bf(v.x); u.y = f2bf(v.y); u.z = f2bf(v.z); u.w = f2bf(v.w);
    *(ushort4*)(xm + (size_t)row * 512 + c4) = u;
}

// ---------------- routing ----------------
__global__ void route_kernel(const float* __restrict__ x, const float* __restrict__ fc,
                             int* __restrict__ seg) {
    int wid = (int)((blockIdx.x * (size_t)blockDim.x + threadIdx.x) >> 6);
    int lane = threadIdx.x & 63;
    if (wid >= M_TOK) return;
    int b = wid / SEQ;
    float4 xv = *(const float4*)(x + (size_t)wid * DM + lane * 4);
    float nb2 = xv.x*xv.x + xv.y*xv.y + xv.z*xv.z + xv.w*xv.w;
    nb2 = wave_reduce_sum(nb2);
    float nb = sqrtf(nb2);
    float best = -1e30f; int bestk = 0;
    for (int k = 0; k < KCLS; ++k) {
        float4 fv = *(const float4*)(fc + ((size_t)(b * KCLS + k)) * DM + lane * 4);
        float d = fv.x*xv.x + fv.y*xv.y + fv.z*xv.z + fv.w*xv.w;
        float n = fv.x*fv.x + fv.y*fv.y + fv.z*fv.z + fv.w*fv.w;
        d = wave_reduce_sum(d);
        n = wave_reduce_sum(n);
        float sim = d / fmaxf(sqrtf(n) * nb, 1e-8f);
        if (sim > best) { best = sim; bestk = k; }
    }
    if (lane == 0) seg[wid] = bestk;
}

// ---------------- deterministic cluster counting-sort (per batch, 64-aligned clusters) ----------------
__global__ __launch_bounds__(256) void seg_count(const int* __restrict__ seg,
                                                 int* __restrict__ cnt) {
    __shared__ int wc[4][KCLS];
    int b = blockIdx.x >> 4, chunk = blockIdx.x & 15;
    int t = threadIdx.x, w = t >> 6, lane = t & 63;
    int c = seg[b * SEQ + chunk * 256 + t];
    #pragma unroll
    for (int cc = 0; cc < KCLS; ++cc) {
        unsigned long long m = __ballot(c == cc);
        if (lane == 0) wc[w][cc] = __popcll(m);
    }
    __syncthreads();
    if (t < KCLS)
        cnt[(b * 16 + chunk) * KCLS + t] = wc[0][t] + wc[1][t] + wc[2][t] + wc[3][t];
}

__global__ __launch_bounds__(256) void seg_scan(const int* __restrict__ cnt,
                                                int* __restrict__ chunkbase,
                                                int* __restrict__ wseg,
                                                int* __restrict__ psegp) {
    __shared__ int sTot[BATCH][KCLS];
    __shared__ int sBase[BATCH][KCLS];
    int tid = threadIdx.x;
    if (tid < BATCH * KCLS) {
        int b = tid / KCLS, c = tid % KCLS;
        int run = 0;
        #pragma unroll
        for (int j = 0; j < 16; ++j) run += cnt[(b * 16 + j) * KCLS + c];
        sTot[b][c] = run;
    }
    __syncthreads();
    if (tid < BATCH) {
        int b = tid, pb = 0;
        for (int c = 0; c < KCLS; ++c) {
            sBase[b][c] = pb;
            int psz = (sTot[b][c] + 63) & ~63;
            int w0 = pb >> 6, w1 = (pb + psz) >> 6;
            for (int w = w0; w < w1; ++w) wseg[b * NWIN + w] = c;
            pb += psz;
        }
        for (int w = pb >> 6; w < NWIN; ++w) wseg[b * NWIN + w] = -1;
    }
    __syncthreads();
    for (int i = tid; i < BATCH * PADPOS; i += 256) {
        int b = i / PADPOS, pos = i % PADPOS;
        int c = KCLS - 1;
        #pragma unroll
        for (int cc = KCLS - 1; cc >= 1; --cc)
            if (pos < sBase[b][cc]) c = cc - 1;
        psegp[i] = c;
    }
    if (tid < BATCH * KCLS) {
        int b = tid / KCLS, c = tid % KCLS;
        int pre = 0;
        #pragma unroll
        for (int j = 0; j < 16; ++j) {
            chunkbase[(b * 16 + j) * KCLS + c] = sBase[b][c] + pre;
            pre += cnt[(b * 16 + j) * KCLS + c];
        }
    }
}

// scatter: pidxp[b][pos] = token; sortposG[b*SEQ+l] = b*PADPOS+pos (inverse perm)
__global__ __launch_bounds__(256) void seg_scatter(const int* __restrict__ seg,
                                                   const int* __restrict__ chunkbase,
                                                   int* __restrict__ pidxp,
                                                   int* __restrict__ sortposG) {
    __shared__ int wc[4][KCLS];
    int b = blockIdx.x >> 4, chunk = blockIdx.x & 15;
    int t = threadIdx.x, w = t >> 6, lane = t & 63;
    int l = chunk * 256 + t;
    int c = seg[b * SEQ + l];
    int rank_w = 0;
    #pragma unroll
    for (int cc = 0; cc < KCLS; ++cc) {
        unsigned long long m = __ballot(c == cc);
        if (lane == 0) wc[w][cc] = __popcll(m);
        if (cc == c) rank_w = __popcll(m & ((1ULL << lane) - 1ULL));
    }
    __syncthreads();
    int rank = rank_w;
    for (int wp = 0; wp < 4; ++wp)
        if (wp < w) rank += wc[wp][c];
    int pos = chunkbase[(b * 16 + chunk) * KCLS + c] + rank;
    pidxp[b * PADPOS + pos] = l;
    sortposG[b * SEQ + l] = b * PADPOS + pos;
}

// ---------------- zero pad rows of sorted K/V (once per launch) ----------------
__global__ __launch_bounds__(256) void zero_pads(const int* __restrict__ pidxp,
                                                 unsigned short* __restrict__ Kb,
                                                 unsigned short* __restrict__ Vb) {
    int row = blockIdx.x * 8 + (threadIdx.x >> 5);   // global padded row
    int c8 = (threadIdx.x & 31) * 8;
    if (pidxp[row] >= 0) return;
    bf16x8 z = (bf16x8){0,0,0,0,0,0,0,0};
    *(bf16x8*)(Kb + (size_t)row * DM + c8) = z;
    *(bf16x8*)(Vb + (size_t)row * DM + c8) = z;
}

// ---------------- weight transpose+convert: src [K][N] fp32 -> dst [N][K] bf16 ----------------
__global__ __launch_bounds__(256) void transpose_bf16(const float* __restrict__ src,
                                                      unsigned short* __restrict__ dst,
                                                      int K, int N) {
    __shared__ float s[64][65];
    int k0 = blockIdx.x * 64, n0 = blockIdx.y * 64;
    int t = threadIdx.x;
    int r = t >> 4, c4 = (t & 15) * 4;
    #pragma unroll
    for (int i = 0; i < 4; ++i) {
        float4 v = *(const float4*)(src + (size_t)(k0 + r + i*16) * N + n0 + c4);
        s[c4+0][r+i*16] = v.x; s[c4+1][r+i*16] = v.y;
        s[c4+2][r+i*16] = v.z; s[c4+3][r+i*16] = v.w;
    }
    __syncthreads();
    #pragma unroll
    for (int i = 0; i < 4; ++i) {
        int nr = r + i*16;
        ushort4 u;
        u.x = f2bf(s[nr][c4+0]); u.y = f2bf(s[nr][c4+1]);
        u.z = f2bf(s[nr][c4+2]); u.w = f2bf(s[nr][c4+3]);
        *(ushort4*)(dst + (size_t)(n0 + nr) * K + k0 + c4) = u;
    }
}

// ---------------- bf16 MFMA GEMM (128x128 tile): out = act( A[M,KD] * Bt[N,KD]^T ) ----------------
// MODE 1: QKV (N=768), outputs written at SORTED rows (sortpos): Ob0=Q(elu+1), Ob1=K(elu+1), Ob2=V
// MODE 2: W1 (N=512): bf16 out Ob0 [M][512], relu (original row order)
template<int KD, int AS, int MODE>
__global__ __launch_bounds__(256) void mfma_gemm(
    const unsigned short* __restrict__ A, const unsigned short* __restrict__ Bt,
    const int* __restrict__ sortpos,
    unsigned short* __restrict__ Ob0, unsigned short* __restrict__ Ob1,
    unsigned short* __restrict__ Ob2)
{
    __shared__ unsigned short As[BM * BKG];
    __shared__ unsigned short Bs[BN * BKG];
    __shared__ int sPos[BM];
    int t = threadIdx.x;
    int lane = t & 63;
    int w = t >> 6;
    int wm = w & 1, wn = w >> 1;         // 2x2 wave grid, each wave 64x64
    int bm = blockIdx.x * BM;
    int bn = blockIdx.y * BN;

    if (MODE == 1 && t < BM) sPos[t] = sortpos[bm + t];

    f32x4 acc[4][4];
    #pragma unroll
    for (int m = 0; m < 4; ++m)
        #pragma unroll
        for (int n = 0; n < 4; ++n)
            acc[m][n] = (f32x4){0.f, 0.f, 0.f, 0.f};

    for (int k0 = 0; k0 < KD; k0 += BKG) {
        #pragma unroll
        for (int i = 0; i < 4; ++i) {
            int chunk = i * 256 + t;
            int row = chunk >> 3, cc = chunk & 7;
            __builtin_amdgcn_global_load_lds(
                (const __attribute__((address_space(1))) void*)(A + (size_t)(bm + row) * AS + k0 + cc * 8),
                (__attribute__((address_space(3))) void*)((char*)As + chunk * 16), 16, 0, 0);
            __builtin_amdgcn_global_load_lds(
                (const __attribute__((address_space(1))) void*)(Bt + (size_t)(bn + row) * KD + k0 + cc * 8),
                (__attribute__((address_space(3))) void*)((char*)Bs + chunk * 16), 16, 0, 0);
        }
        asm volatile("s_waitcnt vmcnt(0)");
        __syncthreads();
        #pragma unroll
        for (int kk = 0; kk < 2; ++kk) {
            int kbyte = (kk * 32 + (lane >> 4) * 8) * 2;
            bf16x8 af[4], bfr[4];
            #pragma unroll
            for (int m = 0; m < 4; ++m)
                af[m] = *(const bf16x8*)((const char*)As + (wm*64 + m*16 + (lane & 15)) * 128 + kbyte);
            #pragma unroll
            for (int n = 0; n < 4; ++n)
                bfr[n] = *(const bf16x8*)((const char*)Bs + (wn*64 + n*16 + (lane & 15)) * 128 + kbyte);
            #pragma unroll
            for (int m = 0; m < 4; ++m)
                #pragma unroll
                for (int n = 0; n < 4; ++n)
                    acc[m][n] = __builtin_amdgcn_mfma_f32_16x16x32_bf16(af[m], bfr[n], acc[m][n], 0, 0, 0);
        }
        __syncthreads();
    }

    int lrow0 = wm * 64 + (lane >> 4) * 4;
    int lcol = wn * 64 + (lane & 15);
    if (MODE == 1) {
        unsigned short* Obuf = (bn < 256) ? Ob0 : (bn < 512) ? Ob1 : Ob2;
        const bool act = (bn < 512);
        int cc0 = (bn & 255) + lcol;
        #pragma unroll
        for (int m = 0; m < 4; ++m)
            #pragma unroll
            for (int n = 0; n < 4; ++n)
                #pragma unroll
                for (int j = 0; j < 4; ++j) {
                    float v = acc[m][n][j];
                    if (act) v = (v > 0.f) ? v + 1.f : expf(v);
                    int drow = sPos[lrow0 + m*16 + j];
                    Obuf[(size_t)drow * 256 + cc0 + n*16] = f2bf(v);
                }
    } else {
        #pragma unroll
        for (int m = 0; m < 4; ++m)
            #pragma unroll
            for (int n = 0; n < 4; ++n)
                #pragma unroll
                for (int j = 0; j < 4; ++j)
                    Ob0[(size_t)(bm + lrow0 + m*16 + j) * 512 + bn + lcol + n*16] =
                        f2bf(fmaxf(acc[m][n][j], 0.f));
    }
}

// ---------------- fused GEMM + LayerNorm (full rows per block: BM=64, BN=256) ----------------
template<int KD, int LNMODE>
__global__ __launch_bounds__(256) void gemm_ln(
    const unsigned short* __restrict__ A, const unsigned short* __restrict__ Bt,
    const float* __restrict__ g, const float* __restrict__ bb,
    float* __restrict__ x, unsigned short* __restrict__ xm)
{
    __shared__ unsigned short As[64 * BKG];
    __shared__ unsigned short Bs[256 * BKG];
    __shared__ float redS[4][64];
    __shared__ float redQ[4][64];
    int t = threadIdx.x;
    int lane = t & 63;
    int w = t >> 6;                      // wave covers cols [w*64, w*64+64)
    int li = lane & 15, lg = lane >> 4;
    int bm = blockIdx.x * 64;

    f32x4 acc[4][4];
    #pragma unroll
    for (int m = 0; m < 4; ++m)
        #pragma unroll
        for (int n = 0; n < 4; ++n)
            acc[m][n] = (f32x4){0.f, 0.f, 0.f, 0.f};

    for (int k0 = 0; k0 < KD; k0 += BKG) {
        #pragma unroll
        for (int i = 0; i < 2; ++i) {
            int chunk = i * 256 + t;
            int row = chunk >> 3, cc = chunk & 7;
            __builtin_amdgcn_global_load_lds(
                (const __attribute__((address_space(1))) void*)(A + (size_t)(bm + row) * KD + k0 + cc * 8),
                (__attribute__((address_space(3))) void*)((char*)As + chunk * 16), 16, 0, 0);
        }
        #pragma unroll
        for (int i = 0; i < 8; ++i) {
            int chunk = i * 256 + t;
            int row = chunk >> 3, cc = chunk & 7;
            __builtin_amdgcn_global_load_lds(
                (const __attribute__((address_space(1))) void*)(Bt + (size_t)row * KD + k0 + cc * 8),
                (__attribute__((address_space(3))) void*)((char*)Bs + chunk * 16), 16, 0, 0);
        }
        asm volatile("s_waitcnt vmcnt(0)");
        __syncthreads();
        #pragma unroll
        for (int kk = 0; kk < 2; ++kk) {
            int kbyte = (kk * 32 + lg * 8) * 2;
            bf16x8 af[4], bfr[4];
            #pragma unroll
            for (int m = 0; m < 4; ++m)
                af[m] = *(const bf16x8*)((const char*)As + (m*16 + li) * 128 + kbyte);
            #pragma unroll
            for (int n = 0; n < 4; ++n)
                bfr[n] = *(const bf16x8*)((const char*)Bs + (w*64 + n*16 + li) * 128 + kbyte);
            #pragma unroll
            for (int m = 0; m < 4; ++m)
                #pragma unroll
                for (int n = 0; n < 4; ++n)
                    acc[m][n] = __builtin_amdgcn_mfma_f32_16x16x32_bf16(af[m], bfr[n], acc[m][n], 0, 0, 0);
        }
        __syncthreads();
    }

    float vs[4][4], vq[4][4];
    #pragma unroll
    for (int m = 0; m < 4; ++m)
        #pragma unroll
        for (int j = 0; j < 4; ++j) {
            float s = 0.f, q = 0.f;
            #pragma unroll
            for (int n = 0; n < 4; ++n) {
                float v = acc[m][n][j];
                s += v; q += v * v;
            }
            #pragma unroll
            for (int msk = 1; msk < 16; msk <<= 1) {
                s += __shfl_xor(s, msk, 64);
                q += __shfl_xor(q, msk, 64);
            }
            vs[m][j] = s; vq[m][j] = q;
        }
    if (li == 0) {
        #pragma unroll
        for (int m = 0; m < 4; ++m)
            #pragma unroll
            for (int j = 0; j < 4; ++j) {
                redS[w][m*16 + lg*4 + j] = vs[m][j];
                redQ[w][m*16 + lg*4 + j] = vq[m][j];
            }
    }
    __syncthreads();

    float gv[4], bv[4];
    #pragma unroll
    for (int n = 0; n < 4; ++n) {
        int col = w*64 + n*16 + li;
        gv[n] = g[col]; bv[n] = bb[col];
    }
    #pragma unroll
    for (int m = 0; m < 4; ++m)
        #pragma unroll
        for (int j = 0; j < 4; ++j) {
            int r = m*16 + lg*4 + j;
            float S = redS[0][r] + redS[1][r] + redS[2][r] + redS[3][r];
            float Q = redQ[0][r] + redQ[1][r] + redQ[2][r] + redQ[3][r];
            float mu = S * (1.f / 256.f);
            float var = Q * (1.f / 256.f) - mu * mu;
            float rs = rsqrtf(var + 1e-5f);
            #pragma unroll
            for (int n = 0; n < 4; ++n) {
                int col = w*64 + n*16 + li;
                float o = gv[n] * (acc[m][n][j] - mu) * rs + bv[n];
                if (LNMODE == 1) {
                    xm[(size_t)(bm + r) * 512 + 256 + col] = f2bf(o);
                } else {
                    size_t idx = (size_t)(bm + r) * 256 + col;
                    float xv = x[idx] + o;
                    x[idx] = xv;
                    xm[(size_t)(bm + r) * 512 + col] = f2bf(xv);
                }
            }
        }
}

// ---------------- KV / Ksum partials: SEQUENTIAL walk over sorted K/V ----------------
__global__ __launch_bounds__(256) void kv_kernel(
    const unsigned short* __restrict__ Ksrt, const unsigned short* __restrict__ Vsrt,
    const int* __restrict__ psegp, float* __restrict__ part)
{
    __shared__ float mg[KCLS * 1056];
    __shared__ int sSeg[512];
    int blk = blockIdx.x;
    int s = blk % KVWIN;
    int bh = blk / KVWIN;
    int b = bh >> 3, h = bh & 7;
    int t = threadIdx.x;
    int d = t >> 3, e0 = (t & 7) * 4;

    for (int i = t; i < KCLS * 1056; i += 256) mg[i] = 0.f;
    sSeg[t] = psegp[b * PADPOS + s * 512 + t];
    sSeg[t + 256] = psegp[b * PADPOS + s * 512 + 256 + t];
    __syncthreads();

    const unsigned short* Kp = Ksrt + (size_t)(b * PADPOS + s * 512) * DM + h * HD + d;
    const unsigned short* Vp = Vsrt + (size_t)(b * PADPOS + s * 512) * DM + h * HD + e0;

    float4 a = {0.f, 0.f, 0.f, 0.f};
    float ks = 0.f;
    int ccur = __builtin_amdgcn_readfirstlane(sSeg[0]);

    for (int l0 = 0; l0 < 512; l0 += 8) {
        unsigned short ku[8]; ushort4 vu[8];
        #pragma unroll
        for (int u = 0; u < 8; ++u) {
            ku[u] = Kp[(size_t)(l0 + u) * DM];
            vu[u] = *(const ushort4*)(Vp + (size_t)(l0 + u) * DM);
        }
        #pragma unroll
        for (int u = 0; u < 8; ++u) {
            int c = __builtin_amdgcn_readfirstlane(sSeg[l0 + u]);
            if (c != ccur) {
                *(float4*)(mg + ccur * 1056 + d * 32 + e0) = a;
                if ((t & 7) == 0) mg[ccur * 1056 + 1024 + d] = ks;
                a = (float4){0.f, 0.f, 0.f, 0.f};
                ks = 0.f;
                ccur = c;
            }
            float kd = bf2f(ku[u]);
            float4 v4;
            v4.x = bf2f(vu[u].x); v4.y = bf2f(vu[u].y);
            v4.z = bf2f(vu[u].z); v4.w = bf2f(vu[u].w);
            a.x = fmaf(kd, v4.x, a.x); a.y = fmaf(kd, v4.y, a.y);
            a.z = fmaf(kd, v4.z, a.z); a.w = fmaf(kd, v4.w, a.w);
            ks += kd;
        }
    }
    *(float4*)(mg + ccur * 1056 + d * 32 + e0) = a;
    if ((t & 7) == 0) mg[ccur * 1056 + 1024 + d] = ks;
    __syncthreads();

    float* pb = part + (size_t)blk * PART_STRIDE;
    for (int i = t; i < (KCLS * 1056) / 4; i += 256) {
        float4 v = *(const float4*)(mg + i * 4);
        *(float4*)(pb + i * 4) = v;
    }
}

// ---------------- reduce partials -> KV, Ks ----------------
__global__ __launch_bounds__(256) void kv_reduce(
    const float* __restrict__ part, float* __restrict__ KV, float* __restrict__ Ks)
{
    int blk = blockIdx.x;          // bh * KCLS + c
    int c = blk % KCLS;
    int bh = blk / KCLS;
    int b = bh >> 3, h = bh & 7;
    int t = threadIdx.x;
    const float* pb = part + (size_t)bh * KVWIN * PART_STRIDE + c * 1056;
    float4 acc = {0, 0, 0, 0};
    float ka = 0.f;
    #pragma unroll
    for (int s = 0; s < KVWIN; ++s) {
        float4 v = *(const float4*)(pb + (size_t)s * PART_STRIDE + t * 4);
        acc.x += v.x; acc.y += v.y; acc.z += v.z; acc.w += v.w;
        if (t < 32) ka += pb[(size_t)s * PART_STRIDE + 1024 + t];
    }
    *(float4*)(KV + ((size_t)(b * KCLS + c) * NHEAD + h) * HD * HD + t * 4) = acc;
    if (t < 32) Ks[((size_t)(b * KCLS + c) * NHEAD + h) * HD + t] = ka;
}

// ---------------- msg: 64 cluster-uniform sorted tokens per block (sorted Q, linear reads) ----------------
__global__ __launch_bounds__(256) void msg_kernel(
    const unsigned short* __restrict__ Qs, const float* __restrict__ KV,
    const float* __restrict__ Ks, const int* __restrict__ pidxp,
    const int* __restrict__ wseg, unsigned short* __restrict__ msgb)
{
    int b = blockIdx.x / NWIN, w = blockIdx.x % NWIN;
    int c = wseg[b * NWIN + w];
    if (c < 0) return;
    __shared__ unsigned short sQ[64 * DM];          // 32 KB sorted Q tile (linear)
    __shared__ unsigned short kvb[NHEAD * HD * HD]; // 16 KB bf16 KV[c]
    __shared__ float sKs[NHEAD][HD];
    __shared__ int sTok[64];
    int t = threadIdx.x;

    if (t < 64) sTok[t] = pidxp[b * PADPOS + w * 64 + t];
    { int h = t >> 5, d = t & 31;
      sKs[h][d] = Ks[((size_t)(b * KCLS + c) * NHEAD + h) * HD + d]; }
    const float* kvsrc = KV + (size_t)(b * KCLS + c) * NHEAD * HD * HD;
    #pragma unroll
    for (int i = 0; i < 8; ++i) {
        int q = i * 256 + t;
        float4 v = ((const float4*)kvsrc)[q];
        ushort4 u; u.x = f2bf(v.x); u.y = f2bf(v.y); u.z = f2bf(v.z); u.w = f2bf(v.w);
        ((ushort4*)kvb)[q] = u;
    }
    const unsigned short* qsrc = Qs + (size_t)(b * PADPOS + w * 64) * DM;
    #pragma unroll
    for (int i = 0; i < 8; ++i) {
        int q = i * 256 + t;                 // 2048 chunks of 8 bf16, linear
        *(bf16x8*)(sQ + q * 8) = *(const bf16x8*)(qsrc + q * 8);
    }
    __syncthreads();

    int h = t >> 5, e = t & 31;
    float kvreg[32], ksreg[32];
    #pragma unroll
    for (int d = 0; d < 32; ++d)
        kvreg[d] = bf2f(kvb[h * 1024 + d * 32 + e]);
    #pragma unroll
    for (int d = 0; d < 32; ++d)
        ksreg[d] = sKs[h][d];

    for (int r = 0; r < 64; ++r) {
        float macc = 0.f, zacc = 0.f;
        #pragma unroll
        for (int d8 = 0; d8 < 4; ++d8) {
            bf16x8 qv = *(const bf16x8*)(sQ + r * DM + h * 32 + d8 * 8);
            #pragma unroll
            for (int j = 0; j < 8; ++j) {
                float qf = bf2f((unsigned short)qv[j]);
                macc = fmaf(qf, kvreg[d8 * 8 + j], macc);
                zacc = fmaf(qf, ksreg[d8 * 8 + j], zacc);
            }
        }
        int tok = sTok[r];
        if (tok >= 0)
            msgb[(size_t)(b * SEQ + tok) * DM + t] = f2bf(macc / (zacc + 1e-6f));
    }
}

extern "C" void kernel_launch(void* const* d_in, const int* in_sizes, int n_in,
                              void* d_out, int out_size, void* d_ws, size_t ws_size,
                              hipStream_t stream)
{
    const float* feat = (const float*)d_in[1];
    const float* fc   = (const float*)d_in[2];
    const float* Wq   = (const float*)d_in[3];
    const float* Wk   = (const float*)d_in[4];
    const float* Wv   = (const float*)d_in[5];
    const float* Wm   = (const float*)d_in[6];
    const float* W1   = (const float*)d_in[7];
    const float* W2   = (const float*)d_in[8];
    const float* g1   = (const float*)d_in[9];
    const float* b1   = (const float*)d_in[10];
    const float* g2   = (const float*)d_in[11];
    const float* b2   = (const float*)d_in[12];
    float* x = (float*)d_out;

    char* ws = (char*)d_ws;
    auto alloc = [&](size_t bytes) { char* p = ws; ws += (bytes + 255) & ~(size_t)255; return p; };
    int*   seg    = (int*)  alloc((size_t)M_TOK * 4);
    int*   cnt    = (int*)  alloc((size_t)BATCH * 16 * KCLS * 4);
    int*   cbase  = (int*)  alloc((size_t)BATCH * 16 * KCLS * 4);
    int*   pidxp  = (int*)  alloc((size_t)BATCH * PADPOS * 4);
    int*   psegp  = (int*)  alloc((size_t)BATCH * PADPOS * 4);
    int*   sortposG = (int*)alloc((size_t)M_TOK * 4);
    int*   wseg   = (int*)  alloc((size_t)BATCH * NWIN * 4);
    float* KV     = (float*)alloc((size_t)BATCH * KCLS * NHEAD * HD * HD * 4);
    float* Ks     = (float*)alloc((size_t)BATCH * KCLS * NHEAD * HD * 4);
    unsigned short* xm = (unsigned short*)alloc((size_t)M_TOK * 512 * 2);
    char* bufA = alloc((size_t)M_TOK * 512 * 2);   // hb bf16 [M][512] / msgb bf16 [M][256] / part (27MB)
    unsigned short* Qs   = (unsigned short*)alloc((size_t)BATCH * PADPOS * DM * 2);
    unsigned short* Ksrt = (unsigned short*)alloc((size_t)BATCH * PADPOS * DM * 2);
    unsigned short* Vsrt = (unsigned short*)alloc((size_t)BATCH * PADPOS * DM * 2);
    unsigned short* WqkvT = (unsigned short*)alloc((size_t)NL * 768 * 256 * 2);
    unsigned short* WmT   = (unsigned short*)alloc((size_t)NL * 256 * 256 * 2);
    unsigned short* W1T   = (unsigned short*)alloc((size_t)NL * 512 * 512 * 2);
    unsigned short* W2T   = (unsigned short*)alloc((size_t)NL * 256 * 512 * 2);

    unsigned short* hb   = (unsigned short*)bufA;
    unsigned short* msgb = (unsigned short*)bufA;
    float*          part = (float*)bufA;           // overlay: dead intervals verified

    for (int li = 0; li < NL; ++li) {
        transpose_bf16<<<dim3(4, 4), 256, 0, stream>>>(Wq + (size_t)li*65536, WqkvT + (size_t)li*768*256, 256, 256);
        transpose_bf16<<<dim3(4, 4), 256, 0, stream>>>(Wk + (size_t)li*65536, WqkvT + (size_t)li*768*256 + 65536, 256, 256);
        transpose_bf16<<<dim3(4, 4), 256, 0, stream>>>(Wv + (size_t)li*65536, WqkvT + (size_t)li*768*256 + 131072, 256, 256);
        transpose_bf16<<<dim3(4, 4), 256, 0, stream>>>(Wm + (size_t)li*65536, WmT + (size_t)li*65536, 256, 256);
        transpose_bf16<<<dim3(8, 8), 256, 0, stream>>>(W1 + (size_t)li*262144, W1T + (size_t)li*262144, 512, 512);
        transpose_bf16<<<dim3(8, 4), 256, 0, stream>>>(W2 + (size_t)li*131072, W2T + (size_t)li*131072, 512, 256);
    }

    init_kernel<<<8192, 256, 0, stream>>>(feat, x, xm);
    route_kernel<<<8192, 256, 0, stream>>>(feat, fc, seg);

    // deterministic padded cluster sort (once; reused by all layers)
    seg_count<<<BATCH * 16, 256, 0, stream>>>(seg, cnt);
    seg_scan<<<1, 256, 0, stream>>>(cnt, cbase, wseg, psegp);
    hipMemsetAsync(pidxp, 0xFF, (size_t)BATCH * PADPOS * 4, stream);
    seg_scatter<<<BATCH * 16, 256, 0, stream>>>(seg, cbase, pidxp, sortposG);
    zero_pads<<<BATCH * PADPOS / 8, 256, 0, stream>>>(pidxp, Ksrt, Vsrt);

    for (int li = 0; li < NL; ++li) {
        const unsigned short* wqkv = WqkvT + (size_t)li * 768 * 256;
        const unsigned short* wm   = WmT + (size_t)li * 65536;
        const unsigned short* w1   = W1T + (size_t)li * 262144;
        const unsigned short* w2   = W2T + (size_t)li * 131072;

        // QKV GEMM writes Q/K/V at sorted padded rows (elu+1 on Q,K)
        mfma_gemm<256, 512, 1><<<dim3(256, 6), 256, 0, stream>>>(xm, wqkv, sortposG, Qs, Ksrt, Vsrt);

        // KV/Ksum: sequential sorted walk, slab flush on cluster change, tree reduce
        kv_kernel<<<BATCH * NHEAD * KVWIN, 256, 0, stream>>>(Ksrt, Vsrt, psegp, part);
        kv_reduce<<<BATCH * NHEAD * KCLS, 256, 0, stream>>>(part, KV, Ks);

        // msgb (bf16, original token order) <- attention message (sorted Q, shared KV[c])
        msg_kernel<<<BATCH * NWIN, 256, 0, stream>>>(Qs, KV, Ks, pidxp, wseg, msgb);

        gemm_ln<256, 1><<<512, 256, 0, stream>>>(msgb, wm, g1 + li * DM, b1 + li * DM, nullptr, xm);

        mfma_gemm<512, 512, 2><<<dim3(256, 4), 256, 0, stream>>>(xm, w1, nullptr, hb, nullptr, nullptr);

        gemm_ln<512, 2><<<512, 256, 0, stream>>>(hb, w2, g2 + li * DM, b2 + li * DM, x, xm);
    }
}

// Round 10
// 981.310 us; speedup vs baseline: 1.4532x; 1.0161x over previous
//
#include <hip/hip_runtime.h>
#include <hip/hip_bf16.h>
#include <math.h>

#define DM 256
#define NHEAD 8
#define HD 32
#define NL 4
#define BATCH 8
#define SEQ 4096
#define KCLS 10
#define M_TOK (BATCH*SEQ)   // 32768

#define BM 128
#define BN 128
#define BKG 64

#define PADPOS 5120          // padded sorted positions per batch (each cluster 64-aligned)
#define NWIN (PADPOS/64)     // 80 msg windows per batch
#define KVWIN (PADPOS/512)   // 10 kv windows per batch (512 positions each)
#define PART_STRIDE (KCLS * 1056)   // per-window partial: 10 clusters x (1024 KV + 32 Ks)

using bf16x8 = __attribute__((ext_vector_type(8))) short;
using f32x4  = __attribute__((ext_vector_type(4))) float;

__device__ __forceinline__ unsigned short f2bf(float f) {
    __hip_bfloat16 b = __float2bfloat16(f);
    return __builtin_bit_cast(unsigned short, b);
}
__device__ __forceinline__ float bf2f(unsigned short u) {
    unsigned v = (unsigned)u << 16;
    return __builtin_bit_cast(float, v);
}

__device__ __forceinline__ float wave_reduce_sum(float v) {
    #pragma unroll
    for (int off = 32; off > 0; off >>= 1) v += __shfl_xor(v, off, 64);
    return v;
}

// ---------------- init: x = feat (fp32), xm[:,0:256] = bf16(feat) ----------------
__global__ __launch_bounds__(256) void init_kernel(const float* __restrict__ feat,
                                                   float* __restrict__ x,
                                                   unsigned short* __restrict__ xm) {
    int i = blockIdx.x * 256 + threadIdx.x;      // over M_TOK*64 quads
    int row = i >> 6, c4 = (i & 63) * 4;
    float4 v = *(const float4*)(feat + (size_t)row * DM + c4);
    *(float4*)(x + (size_t)row * DM + c4) = v;
    ushort4 u; u.x = f2bf(v.x); u.y = f2bf(v.y); u.z = f2bf(v.z); u.w = f2bf(v.w);
    *(ushort4*)(xm + (size_t)row * 512 + c4) = u;
}

// ---------------- routing ----------------
__global__ void route_kernel(const float* __restrict__ x, const float* __restrict__ fc,
                             int* __restrict__ seg) {
    int wid = (int)((blockIdx.x * (size_t)blockDim.x + threadIdx.x) >> 6);
    int lane = threadIdx.x & 63;
    if (wid >= M_TOK) return;
    int b = wid / SEQ;
    float4 xv = *(const float4*)(x + (size_t)wid * DM + lane * 4);
    float nb2 = xv.x*xv.x + xv.y*xv.y + xv.z*xv.z + xv.w*xv.w;
    nb2 = wave_reduce_sum(nb2);
    float nb = sqrtf(nb2);
    float best = -1e30f; int bestk = 0;
    for (int k = 0; k < KCLS; ++k) {
        float4 fv = *(const float4*)(fc + ((size_t)(b * KCLS + k)) * DM + lane * 4);
        float d = fv.x*xv.x + fv.y*xv.y + fv.z*xv.z + fv.w*xv.w;
        float n = fv.x*fv.x + fv.y*fv.y + fv.z*fv.z + fv.w*fv.w;
        d = wave_reduce_sum(d);
        n = wave_reduce_sum(n);
        float sim = d / fmaxf(sqrtf(n) * nb, 1e-8f);
        if (sim > best) { best = sim; bestk = k; }
    }
    if (lane == 0) seg[wid] = bestk;
}

// ---------------- deterministic cluster counting-sort (per batch, 64-aligned clusters) ----------------
__global__ __launch_bounds__(256) void seg_count(const int* __restrict__ seg,
                                                 int* __restrict__ cnt) {
    __shared__ int wc[4][KCLS];
    int b = blockIdx.x >> 4, chunk = blockIdx.x & 15;
    int t = threadIdx.x, w = t >> 6, lane = t & 63;
    int c = seg[b * SEQ + chunk * 256 + t];
    #pragma unroll
    for (int cc = 0; cc < KCLS; ++cc) {
        unsigned long long m = __ballot(c == cc);
        if (lane == 0) wc[w][cc] = __popcll(m);
    }
    __syncthreads();
    if (t < KCLS)
        cnt[(b * 16 + chunk) * KCLS + t] = wc[0][t] + wc[1][t] + wc[2][t] + wc[3][t];
}

__global__ __launch_bounds__(256) void seg_scan(const int* __restrict__ cnt,
                                                int* __restrict__ chunkbase,
                                                int* __restrict__ wseg,
                                                int* __restrict__ psegp) {
    __shared__ int sTot[BATCH][KCLS];
    __shared__ int sBase[BATCH][KCLS];
    int tid = threadIdx.x;
    if (tid < BATCH * KCLS) {
        int b = tid / KCLS, c = tid % KCLS;
        int run = 0;
        #pragma unroll
        for (int j = 0; j < 16; ++j) run += cnt[(b * 16 + j) * KCLS + c];
        sTot[b][c] = run;
    }
    __syncthreads();
    if (tid < BATCH) {
        int b = tid, pb = 0;
        for (int c = 0; c < KCLS; ++c) {
            sBase[b][c] = pb;
            int psz = (sTot[b][c] + 63) & ~63;
            int w0 = pb >> 6, w1 = (pb + psz) >> 6;
            for (int w = w0; w < w1; ++w) wseg[b * NWIN + w] = c;
            pb += psz;
        }
        for (int w = pb >> 6; w < NWIN; ++w) wseg[b * NWIN + w] = -1;
    }
    __syncthreads();
    for (int i = tid; i < BATCH * PADPOS; i += 256) {
        int b = i / PADPOS, pos = i % PADPOS;
        int c = KCLS - 1;
        #pragma unroll
        for (int cc = KCLS - 1; cc >= 1; --cc)
            if (pos < sBase[b][cc]) c = cc - 1;
        psegp[i] = c;
    }
    if (tid < BATCH * KCLS) {
        int b = tid / KCLS, c = tid % KCLS;
        int pre = 0;
        #pragma unroll
        for (int j = 0; j < 16; ++j) {
            chunkbase[(b * 16 + j) * KCLS + c] = sBase[b][c] + pre;
            pre += cnt[(b * 16 + j) * KCLS + c];
        }
    }
}

// scatter: pidxp[b][pos] = token; sortposG[b*SEQ+l] = b*PADPOS+pos (inverse perm)
__global__ __launch_bounds__(256) void seg_scatter(const int* __restrict__ seg,
                                                   const int* __restrict__ chunkbase,
                                                   int* __restrict__ pidxp,
                                                   int* __restrict__ sortposG) {
    __shared__ int wc[4][KCLS];
    int b = blockIdx.x >> 4, chunk = blockIdx.x & 15;
    int t = threadIdx.x, w = t >> 6, lane = t & 63;
    int l = chunk * 256 + t;
    int c = seg[b * SEQ + l];
    int rank_w = 0;
    #pragma unroll
    for (int cc = 0; cc < KCLS; ++cc) {
        unsigned long long m = __ballot(c == cc);
        if (lane == 0) wc[w][cc] = __popcll(m);
        if (cc == c) rank_w = __popcll(m & ((1ULL << lane) - 1ULL));
    }
    __syncthreads();
    int rank = rank_w;
    for (int wp = 0; wp < 4; ++wp)
        if (wp < w) rank += wc[wp][c];
    int pos = chunkbase[(b * 16 + chunk) * KCLS + c] + rank;
    pidxp[b * PADPOS + pos] = l;
    sortposG[b * SEQ + l] = b * PADPOS + pos;
}

// ---------------- zero pad rows of sorted K/V (once per launch) ----------------
__global__ __launch_bounds__(256) void zero_pads(const int* __restrict__ pidxp,
                                                 unsigned short* __restrict__ Kb,
                                                 unsigned short* __restrict__ Vb) {
    int row = blockIdx.x * 8 + (threadIdx.x >> 5);   // global padded row
    int c8 = (threadIdx.x & 31) * 8;
    if (pidxp[row] >= 0) return;
    bf16x8 z = (bf16x8){0,0,0,0,0,0,0,0};
    *(bf16x8*)(Kb + (size_t)row * DM + c8) = z;
    *(bf16x8*)(Vb + (size_t)row * DM + c8) = z;
}

// ---------------- weight transpose+convert: src [K][N] fp32 -> dst [N][K] bf16 ----------------
__global__ __launch_bounds__(256) void transpose_bf16(const float* __restrict__ src,
                                                      unsigned short* __restrict__ dst,
                                                      int K, int N) {
    __shared__ float s[64][65];
    int k0 = blockIdx.x * 64, n0 = blockIdx.y * 64;
    int t = threadIdx.x;
    int r = t >> 4, c4 = (t & 15) * 4;
    #pragma unroll
    for (int i = 0; i < 4; ++i) {
        float4 v = *(const float4*)(src + (size_t)(k0 + r + i*16) * N + n0 + c4);
        s[c4+0][r+i*16] = v.x; s[c4+1][r+i*16] = v.y;
        s[c4+2][r+i*16] = v.z; s[c4+3][r+i*16] = v.w;
    }
    __syncthreads();
    #pragma unroll
    for (int i = 0; i < 4; ++i) {
        int nr = r + i*16;
        ushort4 u;
        u.x = f2bf(s[nr][c4+0]); u.y = f2bf(s[nr][c4+1]);
        u.z = f2bf(s[nr][c4+2]); u.w = f2bf(s[nr][c4+3]);
        *(ushort4*)(dst + (size_t)(n0 + nr) * K + k0 + c4) = u;
    }
}

// ---------------- bf16 MFMA GEMM (128x128 tile): out = act( A[M,KD] * Bt[N,KD]^T ) ----------------
// MODE 1: QKV (N=768), outputs written at SORTED rows (sortpos): Ob0=Q(elu+1), Ob1=K(elu+1), Ob2=V
// MODE 2: W1 (N=512): bf16 out Ob0 [M][512], relu (original row order)
template<int KD, int AS, int MODE>
__global__ __launch_bounds__(256) void mfma_gemm(
    const unsigned short* __restrict__ A, const unsigned short* __restrict__ Bt,
    const int* __restrict__ sortpos,
    unsigned short* __restrict__ Ob0, unsigned short* __restrict__ Ob1,
    unsigned short* __restrict__ Ob2)
{
    __shared__ unsigned short As[BM * BKG];
    __shared__ unsigned short Bs[BN * BKG];
    __shared__ int sPos[BM];
    int t = threadIdx.x;
    int lane = t & 63;
    int w = t >> 6;
    int wm = w & 1, wn = w >> 1;         // 2x2 wave grid, each wave 64x64
    int bm = blockIdx.x * BM;
    int bn = blockIdx.y * BN;

    if (MODE == 1 && t < BM) sPos[t] = sortpos[bm + t];

    f32x4 acc[4][4];
    #pragma unroll
    for (int m = 0; m < 4; ++m)
        #pragma unroll
        for (int n = 0; n < 4; ++n)
            acc[m][n] = (f32x4){0.f, 0.f, 0.f, 0.f};

    for (int k0 = 0; k0 < KD; k0 += BKG) {
        #pragma unroll
        for (int i = 0; i < 4; ++i) {
            int chunk = i * 256 + t;
            int row = chunk >> 3, cc = chunk & 7;
            __builtin_amdgcn_global_load_lds(
                (const __attribute__((address_space(1))) void*)(A + (size_t)(bm + row) * AS + k0 + cc * 8),
                (__attribute__((address_space(3))) void*)((char*)As + chunk * 16), 16, 0, 0);
            __builtin_amdgcn_global_load_lds(
                (const __attribute__((address_space(1))) void*)(Bt + (size_t)(bn + row) * KD + k0 + cc * 8),
                (__attribute__((address_space(3))) void*)((char*)Bs + chunk * 16), 16, 0, 0);
        }
        asm volatile("s_waitcnt vmcnt(0)");
        __syncthreads();
        #pragma unroll
        for (int kk = 0; kk < 2; ++kk) {
            int kbyte = (kk * 32 + (lane >> 4) * 8) * 2;
            bf16x8 af[4], bfr[4];
            #pragma unroll
            for (int m = 0; m < 4; ++m)
                af[m] = *(const bf16x8*)((const char*)As + (wm*64 + m*16 + (lane & 15)) * 128 + kbyte);
            #pragma unroll
            for (int n = 0; n < 4; ++n)
                bfr[n] = *(const bf16x8*)((const char*)Bs + (wn*64 + n*16 + (lane & 15)) * 128 + kbyte);
            #pragma unroll
            for (int m = 0; m < 4; ++m)
                #pragma unroll
                for (int n = 0; n < 4; ++n)
                    acc[m][n] = __builtin_amdgcn_mfma_f32_16x16x32_bf16(af[m], bfr[n], acc[m][n], 0, 0, 0);
        }
        __syncthreads();
    }

    int lrow0 = wm * 64 + (lane >> 4) * 4;
    int lcol = wn * 64 + (lane & 15);
    if (MODE == 1) {
        unsigned short* Obuf = (bn < 256) ? Ob0 : (bn < 512) ? Ob1 : Ob2;
        const bool act = (bn < 512);
        int cc0 = (bn & 255) + lcol;
        #pragma unroll
        for (int m = 0; m < 4; ++m)
            #pragma unroll
            for (int n = 0; n < 4; ++n)
                #pragma unroll
                for (int j = 0; j < 4; ++j) {
                    float v = acc[m][n][j];
                    if (act) v = (v > 0.f) ? v + 1.f : expf(v);
                    int drow = sPos[lrow0 + m*16 + j];
                    Obuf[(size_t)drow * 256 + cc0 + n*16] = f2bf(v);
                }
    } else {
        #pragma unroll
        for (int m = 0; m < 4; ++m)
            #pragma unroll
            for (int n = 0; n < 4; ++n)
                #pragma unroll
                for (int j = 0; j < 4; ++j)
                    Ob0[(size_t)(bm + lrow0 + m*16 + j) * 512 + bn + lcol + n*16] =
                        f2bf(fmaxf(acc[m][n][j], 0.f));
    }
}

// ---------------- fused GEMM + LayerNorm (full rows per block: BM=64, BN=256) ----------------
template<int KD, int LNMODE>
__global__ __launch_bounds__(256) void gemm_ln(
    const unsigned short* __restrict__ A, const unsigned short* __restrict__ Bt,
    const float* __restrict__ g, const float* __restrict__ bb,
    float* __restrict__ x, unsigned short* __restrict__ xm)
{
    __shared__ unsigned short As[64 * BKG];
    __shared__ unsigned short Bs[256 * BKG];
    __shared__ float redS[4][64];
    __shared__ float redQ[4][64];
    int t = threadIdx.x;
    int lane = t & 63;
    int w = t >> 6;                      // wave covers cols [w*64, w*64+64)
    int li = lane & 15, lg = lane >> 4;
    int bm = blockIdx.x * 64;

    f32x4 acc[4][4];
    #pragma unroll
    for (int m = 0; m < 4; ++m)
        #pragma unroll
        for (int n = 0; n < 4; ++n)
            acc[m][n] = (f32x4){0.f, 0.f, 0.f, 0.f};

    for (int k0 = 0; k0 < KD; k0 += BKG) {
        #pragma unroll
        for (int i = 0; i < 2; ++i) {
            int chunk = i * 256 + t;
            int row = chunk >> 3, cc = chunk & 7;
            __builtin_amdgcn_global_load_lds(
                (const __attribute__((address_space(1))) void*)(A + (size_t)(bm + row) * KD + k0 + cc * 8),
                (__attribute__((address_space(3))) void*)((char*)As + chunk * 16), 16, 0, 0);
        }
        #pragma unroll
        for (int i = 0; i < 8; ++i) {
            int chunk = i * 256 + t;
            int row = chunk >> 3, cc = chunk & 7;
            __builtin_amdgcn_global_load_lds(
                (const __attribute__((address_space(1))) void*)(Bt + (size_t)row * KD + k0 + cc * 8),
                (__attribute__((address_space(3))) void*)((char*)Bs + chunk * 16), 16, 0, 0);
        }
        asm volatile("s_waitcnt vmcnt(0)");
        __syncthreads();
        #pragma unroll
        for (int kk = 0; kk < 2; ++kk) {
            int kbyte = (kk * 32 + lg * 8) * 2;
            bf16x8 af[4], bfr[4];
            #pragma unroll
            for (int m = 0; m < 4; ++m)
                af[m] = *(const bf16x8*)((const char*)As + (m*16 + li) * 128 + kbyte);
            #pragma unroll
            for (int n = 0; n < 4; ++n)
                bfr[n] = *(const bf16x8*)((const char*)Bs + (w*64 + n*16 + li) * 128 + kbyte);
            #pragma unroll
            for (int m = 0; m < 4; ++m)
                #pragma unroll
                for (int n = 0; n < 4; ++n)
                    acc[m][n] = __builtin_amdgcn_mfma_f32_16x16x32_bf16(af[m], bfr[n], acc[m][n], 0, 0, 0);
        }
        __syncthreads();
    }

    float vs[4][4], vq[4][4];
    #pragma unroll
    for (int m = 0; m < 4; ++m)
        #pragma unroll
        for (int j = 0; j < 4; ++j) {
            float s = 0.f, q = 0.f;
            #pragma unroll
            for (int n = 0; n < 4; ++n) {
                float v = acc[m][n][j];
                s += v; q += v * v;
            }
            #pragma unroll
            for (int msk = 1; msk < 16; msk <<= 1) {
                s += __shfl_xor(s, msk, 64);
                q += __shfl_xor(q, msk, 64);
            }
            vs[m][j] = s; vq[m][j] = q;
        }
    if (li == 0) {
        #pragma unroll
        for (int m = 0; m < 4; ++m)
            #pragma unroll
            for (int j = 0; j < 4; ++j) {
                redS[w][m*16 + lg*4 + j] = vs[m][j];
                redQ[w][m*16 + lg*4 + j] = vq[m][j];
            }
    }
    __syncthreads();

    float gv[4], bv[4];
    #pragma unroll
    for (int n = 0; n < 4; ++n) {
        int col = w*64 + n*16 + li;
        gv[n] = g[col]; bv[n] = bb[col];
    }
    #pragma unroll
    for (int m = 0; m < 4; ++m)
        #pragma unroll
        for (int j = 0; j < 4; ++j) {
            int r = m*16 + lg*4 + j;
            float S = redS[0][r] + redS[1][r] + redS[2][r] + redS[3][r];
            float Q = redQ[0][r] + redQ[1][r] + redQ[2][r] + redQ[3][r];
            float mu = S * (1.f / 256.f);
            float var = Q * (1.f / 256.f) - mu * mu;
            float rs = rsqrtf(var + 1e-5f);
            #pragma unroll
            for (int n = 0; n < 4; ++n) {
                int col = w*64 + n*16 + li;
                float o = gv[n] * (acc[m][n][j] - mu) * rs + bv[n];
                if (LNMODE == 1) {
                    xm[(size_t)(bm + r) * 512 + 256 + col] = f2bf(o);
                } else {
                    size_t idx = (size_t)(bm + r) * 256 + col;
                    float xv = x[idx] + o;
                    x[idx] = xv;
                    xm[(size_t)(bm + r) * 512 + col] = f2bf(xv);
                }
            }
        }
}

// ---------------- KV / Ksum partials: sequential sorted walk, DIRECT global flush ----------------
__global__ __launch_bounds__(256) void kv_kernel(
    const unsigned short* __restrict__ Ksrt, const unsigned short* __restrict__ Vsrt,
    const int* __restrict__ psegp, float* __restrict__ part)
{
    __shared__ int sSeg[512];
    int blk = blockIdx.x;
    int s = blk % KVWIN;
    int bh = blk / KVWIN;
    int b = bh >> 3, h = bh & 7;
    int t = threadIdx.x;
    int d = t >> 3, e0 = (t & 7) * 4;

    sSeg[t] = psegp[b * PADPOS + s * 512 + t];
    sSeg[t + 256] = psegp[b * PADPOS + s * 512 + 256 + t];
    __syncthreads();

    const unsigned short* Kp = Ksrt + (size_t)(b * PADPOS + s * 512) * DM + h * HD + d;
    const unsigned short* Vp = Vsrt + (size_t)(b * PADPOS + s * 512) * DM + h * HD + e0;
    float* pb = part + (size_t)blk * PART_STRIDE;

    float4 a = {0.f, 0.f, 0.f, 0.f};
    float ks = 0.f;
    int ccur = __builtin_amdgcn_readfirstlane(sSeg[0]);

    for (int l0 = 0; l0 < 512; l0 += 8) {
        unsigned short ku[8]; ushort4 vu[8];
        #pragma unroll
        for (int u = 0; u < 8; ++u) {
            ku[u] = Kp[(size_t)(l0 + u) * DM];
            vu[u] = *(const ushort4*)(Vp + (size_t)(l0 + u) * DM);
        }
        #pragma unroll
        for (int u = 0; u < 8; ++u) {
            int c = __builtin_amdgcn_readfirstlane(sSeg[l0 + u]);
            if (c != ccur) {
                *(float4*)(pb + ccur * 1056 + d * 32 + e0) = a;
                if ((t & 7) == 0) pb[ccur * 1056 + 1024 + d] = ks;
                a = (float4){0.f, 0.f, 0.f, 0.f};
                ks = 0.f;
                ccur = c;
            }
            float kd = bf2f(ku[u]);
            float4 v4;
            v4.x = bf2f(vu[u].x); v4.y = bf2f(vu[u].y);
            v4.z = bf2f(vu[u].z); v4.w = bf2f(vu[u].w);
            a.x = fmaf(kd, v4.x, a.x); a.y = fmaf(kd, v4.y, a.y);
            a.z = fmaf(kd, v4.z, a.z); a.w = fmaf(kd, v4.w, a.w);
            ks += kd;
        }
    }
    *(float4*)(pb + ccur * 1056 + d * 32 + e0) = a;
    if ((t & 7) == 0) pb[ccur * 1056 + 1024 + d] = ks;
}

// ---------------- reduce partials -> KV, Ks (window range-check via psegp) ----------------
__global__ __launch_bounds__(256) void kv_reduce(
    const float* __restrict__ part, const int* __restrict__ psegp,
    float* __restrict__ KV, float* __restrict__ Ks)
{
    int blk = blockIdx.x;          // bh * KCLS + c
    int c = blk % KCLS;
    int bh = blk / KCLS;
    int b = bh >> 3, h = bh & 7;
    int t = threadIdx.x;
    const float* pb = part + (size_t)bh * KVWIN * PART_STRIDE + c * 1056;
    float4 acc = {0, 0, 0, 0};
    float ka = 0.f;
    #pragma unroll
    for (int s = 0; s < KVWIN; ++s) {
        int cf = psegp[b * PADPOS + s * 512];
        int cl = psegp[b * PADPOS + s * 512 + 511];
        if (c < cf || c > cl) continue;       // window never flushed cluster c
        float4 v = *(const float4*)(pb + (size_t)s * PART_STRIDE + t * 4);
        acc.x += v.x; acc.y += v.y; acc.z += v.z; acc.w += v.w;
        if (t < 32) ka += pb[(size_t)s * PART_STRIDE + 1024 + t];
    }
    *(float4*)(KV + ((size_t)(b * KCLS + c) * NHEAD + h) * HD * HD + t * 4) = acc;
    if (t < 32) Ks[((size_t)(b * KCLS + c) * NHEAD + h) * HD + t] = ka;
}

// ---------------- msg: 64 cluster-uniform sorted tokens per block (sorted Q, linear reads) ----------------
__global__ __launch_bounds__(256) void msg_kernel(
    const unsigned short* __restrict__ Qs, const float* __restrict__ KV,
    const float* __restrict__ Ks, const int* __restrict__ pidxp,
    const int* __restrict__ wseg, unsigned short* __restrict__ msgb)
{
    int b = blockIdx.x / NWIN, w = blockIdx.x % NWIN;
    int c = wseg[b * NWIN + w];
    if (c < 0) return;
    __shared__ unsigned short sQ[64 * DM];          // 32 KB sorted Q tile (linear)
    __shared__ unsigned short kvb[NHEAD * HD * HD]; // 16 KB bf16 KV[c]
    __shared__ float sKs[NHEAD][HD];
    __shared__ int sTok[64];
    int t = threadIdx.x;

    if (t < 64) sTok[t] = pidxp[b * PADPOS + w * 64 + t];
    { int h = t >> 5, d = t & 31;
      sKs[h][d] = Ks[((size_t)(b * KCLS + c) * NHEAD + h) * HD + d]; }
    const float* kvsrc = KV + (size_t)(b * KCLS + c) * NHEAD * HD * HD;
    #pragma unroll
    for (int i = 0; i < 8; ++i) {
        int q = i * 256 + t;
        float4 v = ((const float4*)kvsrc)[q];
        ushort4 u; u.x = f2bf(v.x); u.y = f2bf(v.y); u.z = f2bf(v.z); u.w = f2bf(v.w);
        ((ushort4*)kvb)[q] = u;
    }
    const unsigned short* qsrc = Qs + (size_t)(b * PADPOS + w * 64) * DM;
    #pragma unroll
    for (int i = 0; i < 8; ++i) {
        int q = i * 256 + t;                 // 2048 chunks of 8 bf16, linear
        *(bf16x8*)(sQ + q * 8) = *(const bf16x8*)(qsrc + q * 8);
    }
    __syncthreads();

    int h = t >> 5, e = t & 31;
    float kvreg[32], ksreg[32];
    #pragma unroll
    for (int d = 0; d < 32; ++d)
        kvreg[d] = bf2f(kvb[h * 1024 + d * 32 + e]);
    #pragma unroll
    for (int d = 0; d < 32; ++d)
        ksreg[d] = sKs[h][d];

    for (int r = 0; r < 64; ++r) {
        float macc = 0.f, zacc = 0.f;
        #pragma unroll
        for (int d8 = 0; d8 < 4; ++d8) {
            bf16x8 qv = *(const bf16x8*)(sQ + r * DM + h * 32 + d8 * 8);
            #pragma unroll
            for (int j = 0; j < 8; ++j) {
                float qf = bf2f((unsigned short)qv[j]);
                macc = fmaf(qf, kvreg[d8 * 8 + j], macc);
                zacc = fmaf(qf, ksreg[d8 * 8 + j], zacc);
            }
        }
        int tok = sTok[r];
        if (tok >= 0)
            msgb[(size_t)(b * SEQ + tok) * DM + t] = f2bf(macc / (zacc + 1e-6f));
    }
}

extern "C" void kernel_launch(void* const* d_in, const int* in_sizes, int n_in,
                              void* d_out, int out_size, void* d_ws, size_t ws_size,
                              hipStream_t stream)
{
    const float* feat = (const float*)d_in[1];
    const float* fc   = (const float*)d_in[2];
    const float* Wq   = (const float*)d_in[3];
    const float* Wk   = (const float*)d_in[4];
    const float* Wv   = (const float*)d_in[5];
    const float* Wm   = (const float*)d_in[6];
    const float* W1   = (const float*)d_in[7];
    const float* W2   = (const float*)d_in[8];
    const float* g1   = (const float*)d_in[9];
    const float* b1   = (const float*)d_in[10];
    const float* g2   = (const float*)d_in[11];
    const float* b2   = (const float*)d_in[12];
    float* x = (float*)d_out;

    char* ws = (char*)d_ws;
    auto alloc = [&](size_t bytes) { char* p = ws; ws += (bytes + 255) & ~(size_t)255; return p; };
    int*   seg    = (int*)  alloc((size_t)M_TOK * 4);
    int*   cnt    = (int*)  alloc((size_t)BATCH * 16 * KCLS * 4);
    int*   cbase  = (int*)  alloc((size_t)BATCH * 16 * KCLS * 4);
    int*   pidxp  = (int*)  alloc((size_t)BATCH * PADPOS * 4);
    int*   psegp  = (int*)  alloc((size_t)BATCH * PADPOS * 4);
    int*   sortposG = (int*)alloc((size_t)M_TOK * 4);
    int*   wseg   = (int*)  alloc((size_t)BATCH * NWIN * 4);
    float* KV     = (float*)alloc((size_t)BATCH * KCLS * NHEAD * HD * HD * 4);
    float* Ks     = (float*)alloc((size_t)BATCH * KCLS * NHEAD * HD * 4);
    unsigned short* xm = (unsigned short*)alloc((size_t)M_TOK * 512 * 2);
    char* bufA = alloc((size_t)M_TOK * 512 * 2);   // hb bf16 [M][512] / msgb bf16 [M][256] / part (27MB)
    unsigned short* Qs   = (unsigned short*)alloc((size_t)BATCH * PADPOS * DM * 2);
    unsigned short* Ksrt = (unsigned short*)alloc((size_t)BATCH * PADPOS * DM * 2);
    unsigned short* Vsrt = (unsigned short*)alloc((size_t)BATCH * PADPOS * DM * 2);
    unsigned short* WqkvT = (unsigned short*)alloc((size_t)NL * 768 * 256 * 2);
    unsigned short* WmT   = (unsigned short*)alloc((size_t)NL * 256 * 256 * 2);
    unsigned short* W1T   = (unsigned short*)alloc((size_t)NL * 512 * 512 * 2);
    unsigned short* W2T   = (unsigned short*)alloc((size_t)NL * 256 * 512 * 2);

    unsigned short* hb   = (unsigned short*)bufA;
    unsigned short* msgb = (unsigned short*)bufA;
    float*          part = (float*)bufA;           // overlay: dead intervals verified

    for (int li = 0; li < NL; ++li) {
        transpose_bf16<<<dim3(4, 4), 256, 0, stream>>>(Wq + (size_t)li*65536, WqkvT + (size_t)li*768*256, 256, 256);
        transpose_bf16<<<dim3(4, 4), 256, 0, stream>>>(Wk + (size_t)li*65536, WqkvT + (size_t)li*768*256 + 65536, 256, 256);
        transpose_bf16<<<dim3(4, 4), 256, 0, stream>>>(Wv + (size_t)li*65536, WqkvT + (size_t)li*768*256 + 131072, 256, 256);
        transpose_bf16<<<dim3(4, 4), 256, 0, stream>>>(Wm + (size_t)li*65536, WmT + (size_t)li*65536, 256, 256);
        transpose_bf16<<<dim3(8, 8), 256, 0, stream>>>(W1 + (size_t)li*262144, W1T + (size_t)li*262144, 512, 512);
        transpose_bf16<<<dim3(8, 4), 256, 0, stream>>>(W2 + (size_t)li*131072, W2T + (size_t)li*131072, 512, 256);
    }

    init_kernel<<<8192, 256, 0, stream>>>(feat, x, xm);
    route_kernel<<<8192, 256, 0, stream>>>(feat, fc, seg);

    // deterministic padded cluster sort (once; reused by all layers)
    seg_count<<<BATCH * 16, 256, 0, stream>>>(seg, cnt);
    seg_scan<<<1, 256, 0, stream>>>(cnt, cbase, wseg, psegp);
    hipMemsetAsync(pidxp, 0xFF, (size_t)BATCH * PADPOS * 4, stream);
    seg_scatter<<<BATCH * 16, 256, 0, stream>>>(seg, cbase, pidxp, sortposG);
    zero_pads<<<BATCH * PADPOS / 8, 256, 0, stream>>>(pidxp, Ksrt, Vsrt);

    for (int li = 0; li < NL; ++li) {
        const unsigned short* wqkv = WqkvT + (size_t)li * 768 * 256;
        const unsigned short* wm   = WmT + (size_t)li * 65536;
        const unsigned short* w1   = W1T + (size_t)li * 262144;
        const unsigned short* w2   = W2T + (size_t)li * 131072;

        // QKV GEMM writes Q/K/V at sorted padded rows (elu+1 on Q,K)
        mfma_gemm<256, 512, 1><<<dim3(256, 6), 256, 0, stream>>>(xm, wqkv, sortposG, Qs, Ksrt, Vsrt);

        // KV/Ksum: sequential sorted walk, direct global flush, range-checked reduce
        kv_kernel<<<BATCH * NHEAD * KVWIN, 256, 0, stream>>>(Ksrt, Vsrt, psegp, part);
        kv_reduce<<<BATCH * NHEAD * KCLS, 256, 0, stream>>>(part, psegp, KV, Ks);

        // msgb (bf16, original token order) <- attention message (sorted Q, shared KV[c])
        msg_kernel<<<BATCH * NWIN, 256, 0, stream>>>(Qs, KV, Ks, pidxp, wseg, msgb);

        gemm_ln<256, 1><<<512, 256, 0, stream>>>(msgb, wm, g1 + li * DM, b1 + li * DM, nullptr, xm);

        mfma_gemm<512, 512, 2><<<dim3(256, 4), 256, 0, stream>>>(xm, w1, nullptr, hb, nullptr, nullptr);

        gemm_ln<512, 2><<<512, 256, 0, stream>>>(hb, w2, g2 + li * DM, b2 + li * DM, x, xm);
    }
}

// Round 11
// 971.909 us; speedup vs baseline: 1.4672x; 1.0097x over previous
//
#include <hip/hip_runtime.h>
#include <hip/hip_bf16.h>
#include <math.h>

#define DM 256
#define NHEAD 8
#define HD 32
#define NL 4
#define BATCH 8
#define SEQ 4096
#define KCLS 10
#define M_TOK (BATCH*SEQ)   // 32768

#define BM 128
#define BN 128
#define BKG 64

#define PADPOS 5120          // padded sorted positions per batch (each cluster 64-aligned)
#define NWIN (PADPOS/64)     // 80 msg windows per batch
#define KVWIN (PADPOS/512)   // 10 kv windows per batch (512 positions each)
#define PART_STRIDE (KCLS * 1056)   // per-window partial: 10 clusters x (1024 KV + 32 Ks)

using bf16x8 = __attribute__((ext_vector_type(8))) short;
using f32x4  = __attribute__((ext_vector_type(4))) float;

__device__ __forceinline__ unsigned short f2bf(float f) {
    __hip_bfloat16 b = __float2bfloat16(f);
    return __builtin_bit_cast(unsigned short, b);
}
__device__ __forceinline__ float bf2f(unsigned short u) {
    unsigned v = (unsigned)u << 16;
    return __builtin_bit_cast(float, v);
}

__device__ __forceinline__ float wave_reduce_sum(float v) {
    #pragma unroll
    for (int off = 32; off > 0; off >>= 1) v += __shfl_xor(v, off, 64);
    return v;
}

// ---------------- init: x = feat (fp32), xm[:,0:256] = bf16(feat) ----------------
__global__ __launch_bounds__(256) void init_kernel(const float* __restrict__ feat,
                                                   float* __restrict__ x,
                                                   unsigned short* __restrict__ xm) {
    int i = blockIdx.x * 256 + threadIdx.x;      // over M_TOK*64 quads
    int row = i >> 6, c4 = (i & 63) * 4;
    float4 v = *(const float4*)(feat + (size_t)row * DM + c4);
    *(float4*)(x + (size_t)row * DM + c4) = v;
    ushort4 u; u.x = f2bf(v.x); u.y = f2bf(v.y); u.z = f2bf(v.z); u.w = f2bf(v.w);
    *(ushort4*)(xm + (size_t)row * 512 + c4) = u;
}

// ---------------- routing ----------------
__global__ void route_kernel(const float* __restrict__ x, const float* __restrict__ fc,
                             int* __restrict__ seg) {
    int wid = (int)((blockIdx.x * (size_t)blockDim.x + threadIdx.x) >> 6);
    int lane = threadIdx.x & 63;
    if (wid >= M_TOK) return;
    int b = wid / SEQ;
    float4 xv = *(const float4*)(x + (size_t)wid * DM + lane * 4);
    float nb2 = xv.x*xv.x + xv.y*xv.y + xv.z*xv.z + xv.w*xv.w;
    nb2 = wave_reduce_sum(nb2);
    float nb = sqrtf(nb2);
    float best = -1e30f; int bestk = 0;
    for (int k = 0; k < KCLS; ++k) {
        float4 fv = *(const float4*)(fc + ((size_t)(b * KCLS + k)) * DM + lane * 4);
        float d = fv.x*xv.x + fv.y*xv.y + fv.z*xv.z + fv.w*xv.w;
        float n = fv.x*fv.x + fv.y*fv.y + fv.z*fv.z + fv.w*fv.w;
        d = wave_reduce_sum(d);
        n = wave_reduce_sum(n);
        float sim = d / fmaxf(sqrtf(n) * nb, 1e-8f);
        if (sim > best) { best = sim; bestk = k; }
    }
    if (lane == 0) seg[wid] = bestk;
}

// ---------------- deterministic cluster counting-sort (per batch, 64-aligned clusters) ----------------
__global__ __launch_bounds__(256) void seg_count(const int* __restrict__ seg,
                                                 int* __restrict__ cnt) {
    __shared__ int wc[4][KCLS];
    int b = blockIdx.x >> 4, chunk = blockIdx.x & 15;
    int t = threadIdx.x, w = t >> 6, lane = t & 63;
    int c = seg[b * SEQ + chunk * 256 + t];
    #pragma unroll
    for (int cc = 0; cc < KCLS; ++cc) {
        unsigned long long m = __ballot(c == cc);
        if (lane == 0) wc[w][cc] = __popcll(m);
    }
    __syncthreads();
    if (t < KCLS)
        cnt[(b * 16 + chunk) * KCLS + t] = wc[0][t] + wc[1][t] + wc[2][t] + wc[3][t];
}

__global__ __launch_bounds__(256) void seg_scan(const int* __restrict__ cnt,
                                                int* __restrict__ chunkbase,
                                                int* __restrict__ wseg,
                                                int* __restrict__ psegp) {
    __shared__ int sTot[BATCH][KCLS];
    __shared__ int sBase[BATCH][KCLS];
    int tid = threadIdx.x;
    if (tid < BATCH * KCLS) {
        int b = tid / KCLS, c = tid % KCLS;
        int run = 0;
        #pragma unroll
        for (int j = 0; j < 16; ++j) run += cnt[(b * 16 + j) * KCLS + c];
        sTot[b][c] = run;
    }
    __syncthreads();
    if (tid < BATCH) {
        int b = tid, pb = 0;
        for (int c = 0; c < KCLS; ++c) {
            sBase[b][c] = pb;
            int psz = (sTot[b][c] + 63) & ~63;
            int w0 = pb >> 6, w1 = (pb + psz) >> 6;
            for (int w = w0; w < w1; ++w) wseg[b * NWIN + w] = c;
            pb += psz;
        }
        for (int w = pb >> 6; w < NWIN; ++w) wseg[b * NWIN + w] = -1;
    }
    __syncthreads();
    for (int i = tid; i < BATCH * PADPOS; i += 256) {
        int b = i / PADPOS, pos = i % PADPOS;
        int c = KCLS - 1;
        #pragma unroll
        for (int cc = KCLS - 1; cc >= 1; --cc)
            if (pos < sBase[b][cc]) c = cc - 1;
        psegp[i] = c;
    }
    if (tid < BATCH * KCLS) {
        int b = tid / KCLS, c = tid % KCLS;
        int pre = 0;
        #pragma unroll
        for (int j = 0; j < 16; ++j) {
            chunkbase[(b * 16 + j) * KCLS + c] = sBase[b][c] + pre;
            pre += cnt[(b * 16 + j) * KCLS + c];
        }
    }
}

// scatter: pidxp[b][pos] = token; sortposG[b*SEQ+l] = b*PADPOS+pos (inverse perm)
__global__ __launch_bounds__(256) void seg_scatter(const int* __restrict__ seg,
                                                   const int* __restrict__ chunkbase,
                                                   int* __restrict__ pidxp,
                                                   int* __restrict__ sortposG) {
    __shared__ int wc[4][KCLS];
    int b = blockIdx.x >> 4, chunk = blockIdx.x & 15;
    int t = threadIdx.x, w = t >> 6, lane = t & 63;
    int l = chunk * 256 + t;
    int c = seg[b * SEQ + l];
    int rank_w = 0;
    #pragma unroll
    for (int cc = 0; cc < KCLS; ++cc) {
        unsigned long long m = __ballot(c == cc);
        if (lane == 0) wc[w][cc] = __popcll(m);
        if (cc == c) rank_w = __popcll(m & ((1ULL << lane) - 1ULL));
    }
    __syncthreads();
    int rank = rank_w;
    for (int wp = 0; wp < 4; ++wp)
        if (wp < w) rank += wc[wp][c];
    int pos = chunkbase[(b * 16 + chunk) * KCLS + c] + rank;
    pidxp[b * PADPOS + pos] = l;
    sortposG[b * SEQ + l] = b * PADPOS + pos;
}

// ---------------- zero pad rows of sorted K/V (once per launch) ----------------
__global__ __launch_bounds__(256) void zero_pads(const int* __restrict__ pidxp,
                                                 unsigned short* __restrict__ Kb,
                                                 unsigned short* __restrict__ Vb) {
    int row = blockIdx.x * 8 + (threadIdx.x >> 5);   // global padded row
    int c8 = (threadIdx.x & 31) * 8;
    if (pidxp[row] >= 0) return;
    bf16x8 z = (bf16x8){0,0,0,0,0,0,0,0};
    *(bf16x8*)(Kb + (size_t)row * DM + c8) = z;
    *(bf16x8*)(Vb + (size_t)row * DM + c8) = z;
}

// ---------------- weight transpose+convert: src [K][N] fp32 -> dst [N][K] bf16 ----------------
__global__ __launch_bounds__(256) void transpose_bf16(const float* __restrict__ src,
                                                      unsigned short* __restrict__ dst,
                                                      int K, int N) {
    __shared__ float s[64][65];
    int k0 = blockIdx.x * 64, n0 = blockIdx.y * 64;
    int t = threadIdx.x;
    int r = t >> 4, c4 = (t & 15) * 4;
    #pragma unroll
    for (int i = 0; i < 4; ++i) {
        float4 v = *(const float4*)(src + (size_t)(k0 + r + i*16) * N + n0 + c4);
        s[c4+0][r+i*16] = v.x; s[c4+1][r+i*16] = v.y;
        s[c4+2][r+i*16] = v.z; s[c4+3][r+i*16] = v.w;
    }
    __syncthreads();
    #pragma unroll
    for (int i = 0; i < 4; ++i) {
        int nr = r + i*16;
        ushort4 u;
        u.x = f2bf(s[nr][c4+0]); u.y = f2bf(s[nr][c4+1]);
        u.z = f2bf(s[nr][c4+2]); u.w = f2bf(s[nr][c4+3]);
        *(ushort4*)(dst + (size_t)(n0 + nr) * K + k0 + c4) = u;
    }
}

// ---------------- bf16 MFMA GEMM (128x128 tile): out = act( A[M,KD] * Bt[N,KD]^T ) ----------------
// MODE 1: QKV (N=768), outputs written at SORTED rows (sortpos): Ob0=Q(elu+1), Ob1=K(elu+1), Ob2=V
// MODE 2: W1 (N=512): bf16 out Ob0 [M][512], relu (original row order)
template<int KD, int AS, int MODE>
__global__ __launch_bounds__(256) void mfma_gemm(
    const unsigned short* __restrict__ A, const unsigned short* __restrict__ Bt,
    const int* __restrict__ sortpos,
    unsigned short* __restrict__ Ob0, unsigned short* __restrict__ Ob1,
    unsigned short* __restrict__ Ob2)
{
    __shared__ unsigned short As[BM * BKG];
    __shared__ unsigned short Bs[BN * BKG];
    __shared__ int sPos[BM];
    int t = threadIdx.x;
    int lane = t & 63;
    int w = t >> 6;
    int wm = w & 1, wn = w >> 1;         // 2x2 wave grid, each wave 64x64
    int bm = blockIdx.x * BM;
    int bn = blockIdx.y * BN;

    if (MODE == 1 && t < BM) sPos[t] = sortpos[bm + t];

    f32x4 acc[4][4];
    #pragma unroll
    for (int m = 0; m < 4; ++m)
        #pragma unroll
        for (int n = 0; n < 4; ++n)
            acc[m][n] = (f32x4){0.f, 0.f, 0.f, 0.f};

    for (int k0 = 0; k0 < KD; k0 += BKG) {
        #pragma unroll
        for (int i = 0; i < 4; ++i) {
            int chunk = i * 256 + t;
            int row = chunk >> 3, cc = chunk & 7;
            __builtin_amdgcn_global_load_lds(
                (const __attribute__((address_space(1))) void*)(A + (size_t)(bm + row) * AS + k0 + cc * 8),
                (__attribute__((address_space(3))) void*)((char*)As + chunk * 16), 16, 0, 0);
            __builtin_amdgcn_global_load_lds(
                (const __attribute__((address_space(1))) void*)(Bt + (size_t)(bn + row) * KD + k0 + cc * 8),
                (__attribute__((address_space(3))) void*)((char*)Bs + chunk * 16), 16, 0, 0);
        }
        asm volatile("s_waitcnt vmcnt(0)");
        __syncthreads();
        #pragma unroll
        for (int kk = 0; kk < 2; ++kk) {
            int kbyte = (kk * 32 + (lane >> 4) * 8) * 2;
            bf16x8 af[4], bfr[4];
            #pragma unroll
            for (int m = 0; m < 4; ++m)
                af[m] = *(const bf16x8*)((const char*)As + (wm*64 + m*16 + (lane & 15)) * 128 + kbyte);
            #pragma unroll
            for (int n = 0; n < 4; ++n)
                bfr[n] = *(const bf16x8*)((const char*)Bs + (wn*64 + n*16 + (lane & 15)) * 128 + kbyte);
            #pragma unroll
            for (int m = 0; m < 4; ++m)
                #pragma unroll
                for (int n = 0; n < 4; ++n)
                    acc[m][n] = __builtin_amdgcn_mfma_f32_16x16x32_bf16(af[m], bfr[n], acc[m][n], 0, 0, 0);
        }
        __syncthreads();
    }

    int lrow0 = wm * 64 + (lane >> 4) * 4;
    int lcol = wn * 64 + (lane & 15);
    if (MODE == 1) {
        unsigned short* Obuf = (bn < 256) ? Ob0 : (bn < 512) ? Ob1 : Ob2;
        const bool act = (bn < 512);
        int cc0 = (bn & 255) + lcol;
        #pragma unroll
        for (int m = 0; m < 4; ++m)
            #pragma unroll
            for (int n = 0; n < 4; ++n)
                #pragma unroll
                for (int j = 0; j < 4; ++j) {
                    float v = acc[m][n][j];
                    if (act) v = (v > 0.f) ? v + 1.f : expf(v);
                    int drow = sPos[lrow0 + m*16 + j];
                    Obuf[(size_t)drow * 256 + cc0 + n*16] = f2bf(v);
                }
    } else {
        #pragma unroll
        for (int m = 0; m < 4; ++m)
            #pragma unroll
            for (int n = 0; n < 4; ++n)
                #pragma unroll
                for (int j = 0; j < 4; ++j)
                    Ob0[(size_t)(bm + lrow0 + m*16 + j) * 512 + bn + lcol + n*16] =
                        f2bf(fmaxf(acc[m][n][j], 0.f));
    }
}

// ---------------- fused GEMM + LayerNorm (full rows per block: BM=64, BN=256) ----------------
template<int KD, int LNMODE>
__global__ __launch_bounds__(256) void gemm_ln(
    const unsigned short* __restrict__ A, const unsigned short* __restrict__ Bt,
    const float* __restrict__ g, const float* __restrict__ bb,
    float* __restrict__ x, unsigned short* __restrict__ xm)
{
    __shared__ unsigned short As[64 * BKG];
    __shared__ unsigned short Bs[256 * BKG];
    __shared__ float redS[4][64];
    __shared__ float redQ[4][64];
    int t = threadIdx.x;
    int lane = t & 63;
    int w = t >> 6;                      // wave covers cols [w*64, w*64+64)
    int li = lane & 15, lg = lane >> 4;
    int bm = blockIdx.x * 64;

    f32x4 acc[4][4];
    #pragma unroll
    for (int m = 0; m < 4; ++m)
        #pragma unroll
        for (int n = 0; n < 4; ++n)
            acc[m][n] = (f32x4){0.f, 0.f, 0.f, 0.f};

    for (int k0 = 0; k0 < KD; k0 += BKG) {
        #pragma unroll
        for (int i = 0; i < 2; ++i) {
            int chunk = i * 256 + t;
            int row = chunk >> 3, cc = chunk & 7;
            __builtin_amdgcn_global_load_lds(
                (const __attribute__((address_space(1))) void*)(A + (size_t)(bm + row) * KD + k0 + cc * 8),
                (__attribute__((address_space(3))) void*)((char*)As + chunk * 16), 16, 0, 0);
        }
        #pragma unroll
        for (int i = 0; i < 8; ++i) {
            int chunk = i * 256 + t;
            int row = chunk >> 3, cc = chunk & 7;
            __builtin_amdgcn_global_load_lds(
                (const __attribute__((address_space(1))) void*)(Bt + (size_t)row * KD + k0 + cc * 8),
                (__attribute__((address_space(3))) void*)((char*)Bs + chunk * 16), 16, 0, 0);
        }
        asm volatile("s_waitcnt vmcnt(0)");
        __syncthreads();
        #pragma unroll
        for (int kk = 0; kk < 2; ++kk) {
            int kbyte = (kk * 32 + lg * 8) * 2;
            bf16x8 af[4], bfr[4];
            #pragma unroll
            for (int m = 0; m < 4; ++m)
                af[m] = *(const bf16x8*)((const char*)As + (m*16 + li) * 128 + kbyte);
            #pragma unroll
            for (int n = 0; n < 4; ++n)
                bfr[n] = *(const bf16x8*)((const char*)Bs + (w*64 + n*16 + li) * 128 + kbyte);
            #pragma unroll
            for (int m = 0; m < 4; ++m)
                #pragma unroll
                for (int n = 0; n < 4; ++n)
                    acc[m][n] = __builtin_amdgcn_mfma_f32_16x16x32_bf16(af[m], bfr[n], acc[m][n], 0, 0, 0);
        }
        __syncthreads();
    }

    float vs[4][4], vq[4][4];
    #pragma unroll
    for (int m = 0; m < 4; ++m)
        #pragma unroll
        for (int j = 0; j < 4; ++j) {
            float s = 0.f, q = 0.f;
            #pragma unroll
            for (int n = 0; n < 4; ++n) {
                float v = acc[m][n][j];
                s += v; q += v * v;
            }
            #pragma unroll
            for (int msk = 1; msk < 16; msk <<= 1) {
                s += __shfl_xor(s, msk, 64);
                q += __shfl_xor(q, msk, 64);
            }
            vs[m][j] = s; vq[m][j] = q;
        }
    if (li == 0) {
        #pragma unroll
        for (int m = 0; m < 4; ++m)
            #pragma unroll
            for (int j = 0; j < 4; ++j) {
                redS[w][m*16 + lg*4 + j] = vs[m][j];
                redQ[w][m*16 + lg*4 + j] = vq[m][j];
            }
    }
    __syncthreads();

    float gv[4], bv[4];
    #pragma unroll
    for (int n = 0; n < 4; ++n) {
        int col = w*64 + n*16 + li;
        gv[n] = g[col]; bv[n] = bb[col];
    }
    #pragma unroll
    for (int m = 0; m < 4; ++m)
        #pragma unroll
        for (int j = 0; j < 4; ++j) {
            int r = m*16 + lg*4 + j;
            float S = redS[0][r] + redS[1][r] + redS[2][r] + redS[3][r];
            float Q = redQ[0][r] + redQ[1][r] + redQ[2][r] + redQ[3][r];
            float mu = S * (1.f / 256.f);
            float var = Q * (1.f / 256.f) - mu * mu;
            float rs = rsqrtf(var + 1e-5f);
            #pragma unroll
            for (int n = 0; n < 4; ++n) {
                int col = w*64 + n*16 + li;
                float o = gv[n] * (acc[m][n][j] - mu) * rs + bv[n];
                if (LNMODE == 1) {
                    xm[(size_t)(bm + r) * 512 + 256 + col] = f2bf(o);
                } else {
                    size_t idx = (size_t)(bm + r) * 256 + col;
                    float xv = x[idx] + o;
                    x[idx] = xv;
                    xm[(size_t)(bm + r) * 512 + col] = f2bf(xv);
                }
            }
        }
}

// ---------------- KV / Ksum partials: LDS-staged sequential walk, direct global flush ----------------
__global__ __launch_bounds__(256) void kv_kernel(
    const unsigned short* __restrict__ Ksrt, const unsigned short* __restrict__ Vsrt,
    const int* __restrict__ psegp, float* __restrict__ part)
{
    __shared__ unsigned short sK[128 * HD];   // 8 KB
    __shared__ unsigned short sV[128 * HD];   // 8 KB
    __shared__ int sSeg[512];
    int blk = blockIdx.x;
    int s = blk % KVWIN;
    int bh = blk / KVWIN;
    int b = bh >> 3, h = bh & 7;
    int t = threadIdx.x;
    int d = t >> 3, e0 = (t & 7) * 4;

    sSeg[t] = psegp[b * PADPOS + s * 512 + t];
    sSeg[t + 256] = psegp[b * PADPOS + s * 512 + 256 + t];

    const size_t rowbase = (size_t)(b * PADPOS + s * 512);
    float* pb = part + (size_t)blk * PART_STRIDE;

    float4 a = {0.f, 0.f, 0.f, 0.f};
    float ks = 0.f;
    int ccur = -1;

    for (int chunk = 0; chunk < 4; ++chunk) {
        __syncthreads();   // protect LDS reuse (also covers initial sSeg stores)
        // stage 128 rows x 64B of K and V with wide coalesced loads
        #pragma unroll
        for (int rep = 0; rep < 2; ++rep) {
            int idx = rep * 256 + t;             // 512 chunks of 16B per slab
            int row = idx >> 2, off8 = (idx & 3) * 8;
            size_t gsrc = (rowbase + chunk * 128 + row) * DM + h * HD + off8;
            *(bf16x8*)(sK + row * HD + off8) = *(const bf16x8*)(Ksrt + gsrc);
            *(bf16x8*)(sV + row * HD + off8) = *(const bf16x8*)(Vsrt + gsrc);
        }
        __syncthreads();
        if (chunk == 0) ccur = __builtin_amdgcn_readfirstlane(sSeg[0]);

        for (int l = 0; l < 128; ++l) {
            int c = __builtin_amdgcn_readfirstlane(sSeg[chunk * 128 + l]);
            if (c != ccur) {
                *(float4*)(pb + ccur * 1056 + d * 32 + e0) = a;
                if ((t & 7) == 0) pb[ccur * 1056 + 1024 + d] = ks;
                a = (float4){0.f, 0.f, 0.f, 0.f};
                ks = 0.f;
                ccur = c;
            }
            float kd = bf2f(sK[l * HD + d]);
            ushort4 vu = *(const ushort4*)(sV + l * HD + e0);
            float4 v4;
            v4.x = bf2f(vu.x); v4.y = bf2f(vu.y);
            v4.z = bf2f(vu.z); v4.w = bf2f(vu.w);
            a.x = fmaf(kd, v4.x, a.x); a.y = fmaf(kd, v4.y, a.y);
            a.z = fmaf(kd, v4.z, a.z); a.w = fmaf(kd, v4.w, a.w);
            ks += kd;
        }
    }
    *(float4*)(pb + ccur * 1056 + d * 32 + e0) = a;
    if ((t & 7) == 0) pb[ccur * 1056 + 1024 + d] = ks;
}

// ---------------- reduce partials -> KV, Ks (window range-check via psegp) ----------------
__global__ __launch_bounds__(256) void kv_reduce(
    const float* __restrict__ part, const int* __restrict__ psegp,
    float* __restrict__ KV, float* __restrict__ Ks)
{
    int blk = blockIdx.x;          // bh * KCLS + c
    int c = blk % KCLS;
    int bh = blk / KCLS;
    int b = bh >> 3, h = bh & 7;
    int t = threadIdx.x;
    const float* pb = part + (size_t)bh * KVWIN * PART_STRIDE + c * 1056;
    float4 acc = {0, 0, 0, 0};
    float ka = 0.f;
    #pragma unroll
    for (int s = 0; s < KVWIN; ++s) {
        int cf = psegp[b * PADPOS + s * 512];
        int cl = psegp[b * PADPOS + s * 512 + 511];
        if (c < cf || c > cl) continue;       // window never flushed cluster c
        float4 v = *(const float4*)(pb + (size_t)s * PART_STRIDE + t * 4);
        acc.x += v.x; acc.y += v.y; acc.z += v.z; acc.w += v.w;
        if (t < 32) ka += pb[(size_t)s * PART_STRIDE + 1024 + t];
    }
    *(float4*)(KV + ((size_t)(b * KCLS + c) * NHEAD + h) * HD * HD + t * 4) = acc;
    if (t < 32) Ks[((size_t)(b * KCLS + c) * NHEAD + h) * HD + t] = ka;
}

// ---------------- msg: 64 cluster-uniform sorted tokens per block (sorted Q, linear reads) ----------------
__global__ __launch_bounds__(256) void msg_kernel(
    const unsigned short* __restrict__ Qs, const float* __restrict__ KV,
    const float* __restrict__ Ks, const int* __restrict__ pidxp,
    const int* __restrict__ wseg, unsigned short* __restrict__ msgb)
{
    int b = blockIdx.x / NWIN, w = blockIdx.x % NWIN;
    int c = wseg[b * NWIN + w];
    if (c < 0) return;
    __shared__ unsigned short sQ[64 * DM];          // 32 KB sorted Q tile (linear)
    __shared__ unsigned short kvb[NHEAD * HD * HD]; // 16 KB bf16 KV[c]
    __shared__ float sKs[NHEAD][HD];
    __shared__ int sTok[64];
    int t = threadIdx.x;

    if (t < 64) sTok[t] = pidxp[b * PADPOS + w * 64 + t];
    { int h = t >> 5, d = t & 31;
      sKs[h][d] = Ks[((size_t)(b * KCLS + c) * NHEAD + h) * HD + d]; }
    const float* kvsrc = KV + (size_t)(b * KCLS + c) * NHEAD * HD * HD;
    #pragma unroll
    for (int i = 0; i < 8; ++i) {
        int q = i * 256 + t;
        float4 v = ((const float4*)kvsrc)[q];
        ushort4 u; u.x = f2bf(v.x); u.y = f2bf(v.y); u.z = f2bf(v.z); u.w = f2bf(v.w);
        ((ushort4*)kvb)[q] = u;
    }
    const unsigned short* qsrc = Qs + (size_t)(b * PADPOS + w * 64) * DM;
    #pragma unroll
    for (int i = 0; i < 8; ++i) {
        int q = i * 256 + t;                 // 2048 chunks of 8 bf16, linear
        *(bf16x8*)(sQ + q * 8) = *(const bf16x8*)(qsrc + q * 8);
    }
    __syncthreads();

    int h = t >> 5, e = t & 31;
    float kvreg[32], ksreg[32];
    #pragma unroll
    for (int d = 0; d < 32; ++d)
        kvreg[d] = bf2f(kvb[h * 1024 + d * 32 + e]);
    #pragma unroll
    for (int d = 0; d < 32; ++d)
        ksreg[d] = sKs[h][d];

    for (int r = 0; r < 64; ++r) {
        float macc = 0.f, zacc = 0.f;
        #pragma unroll
        for (int d8 = 0; d8 < 4; ++d8) {
            bf16x8 qv = *(const bf16x8*)(sQ + r * DM + h * 32 + d8 * 8);
            #pragma unroll
            for (int j = 0; j < 8; ++j) {
                float qf = bf2f((unsigned short)qv[j]);
                macc = fmaf(qf, kvreg[d8 * 8 + j], macc);
                zacc = fmaf(qf, ksreg[d8 * 8 + j], zacc);
            }
        }
        int tok = sTok[r];
        if (tok >= 0)
            msgb[(size_t)(b * SEQ + tok) * DM + t] = f2bf(macc / (zacc + 1e-6f));
    }
}

extern "C" void kernel_launch(void* const* d_in, const int* in_sizes, int n_in,
                              void* d_out, int out_size, void* d_ws, size_t ws_size,
                              hipStream_t stream)
{
    const float* feat = (const float*)d_in[1];
    const float* fc   = (const float*)d_in[2];
    const float* Wq   = (const float*)d_in[3];
    const float* Wk   = (const float*)d_in[4];
    const float* Wv   = (const float*)d_in[5];
    const float* Wm   = (const float*)d_in[6];
    const float* W1   = (const float*)d_in[7];
    const float* W2   = (const float*)d_in[8];
    const float* g1   = (const float*)d_in[9];
    const float* b1   = (const float*)d_in[10];
    const float* g2   = (const float*)d_in[11];
    const float* b2   = (const float*)d_in[12];
    float* x = (float*)d_out;

    char* ws = (char*)d_ws;
    auto alloc = [&](size_t bytes) { char* p = ws; ws += (bytes + 255) & ~(size_t)255; return p; };
    int*   seg    = (int*)  alloc((size_t)M_TOK * 4);
    int*   cnt    = (int*)  alloc((size_t)BATCH * 16 * KCLS * 4);
    int*   cbase  = (int*)  alloc((size_t)BATCH * 16 * KCLS * 4);
    int*   pidxp  = (int*)  alloc((size_t)BATCH * PADPOS * 4);
    int*   psegp  = (int*)  alloc((size_t)BATCH * PADPOS * 4);
    int*   sortposG = (int*)alloc((size_t)M_TOK * 4);
    int*   wseg   = (int*)  alloc((size_t)BATCH * NWIN * 4);
    float* KV     = (float*)alloc((size_t)BATCH * KCLS * NHEAD * HD * HD * 4);
    float* Ks     = (float*)alloc((size_t)BATCH * KCLS * NHEAD * HD * 4);
    unsigned short* xm = (unsigned short*)alloc((size_t)M_TOK * 512 * 2);
    char* bufA = alloc((size_t)M_TOK * 512 * 2);   // hb bf16 [M][512] / msgb bf16 [M][256] / part (27MB)
    unsigned short* Qs   = (unsigned short*)alloc((size_t)BATCH * PADPOS * DM * 2);
    unsigned short* Ksrt = (unsigned short*)alloc((size_t)BATCH * PADPOS * DM * 2);
    unsigned short* Vsrt = (unsigned short*)alloc((size_t)BATCH * PADPOS * DM * 2);
    unsigned short* WqkvT = (unsigned short*)alloc((size_t)NL * 768 * 256 * 2);
    unsigned short* WmT   = (unsigned short*)alloc((size_t)NL * 256 * 256 * 2);
    unsigned short* W1T   = (unsigned short*)alloc((size_t)NL * 512 * 512 * 2);
    unsigned short* W2T   = (unsigned short*)alloc((size_t)NL * 256 * 512 * 2);

    unsigned short* hb   = (unsigned short*)bufA;
    unsigned short* msgb = (unsigned short*)bufA;
    float*          part = (float*)bufA;           // overlay: dead intervals verified

    for (int li = 0; li < NL; ++li) {
        transpose_bf16<<<dim3(4, 4), 256, 0, stream>>>(Wq + (size_t)li*65536, WqkvT + (size_t)li*768*256, 256, 256);
        transpose_bf16<<<dim3(4, 4), 256, 0, stream>>>(Wk + (size_t)li*65536, WqkvT + (size_t)li*768*256 + 65536, 256, 256);
        transpose_bf16<<<dim3(4, 4), 256, 0, stream>>>(Wv + (size_t)li*65536, WqkvT + (size_t)li*768*256 + 131072, 256, 256);
        transpose_bf16<<<dim3(4, 4), 256, 0, stream>>>(Wm + (size_t)li*65536, WmT + (size_t)li*65536, 256, 256);
        transpose_bf16<<<dim3(8, 8), 256, 0, stream>>>(W1 + (size_t)li*262144, W1T + (size_t)li*262144, 512, 512);
        transpose_bf16<<<dim3(8, 4), 256, 0, stream>>>(W2 + (size_t)li*131072, W2T + (size_t)li*131072, 512, 256);
    }

    init_kernel<<<8192, 256, 0, stream>>>(feat, x, xm);
    route_kernel<<<8192, 256, 0, stream>>>(feat, fc, seg);

    // deterministic padded cluster sort (once; reused by all layers)
    seg_count<<<BATCH * 16, 256, 0, stream>>>(seg, cnt);
    seg_scan<<<1, 256, 0, stream>>>(cnt, cbase, wseg, psegp);
    hipMemsetAsync(pidxp, 0xFF, (size_t)BATCH * PADPOS * 4, stream);
    seg_scatter<<<BATCH * 16, 256, 0, stream>>>(seg, cbase, pidxp, sortposG);
    zero_pads<<<BATCH * PADPOS / 8, 256, 0, stream>>>(pidxp, Ksrt, Vsrt);

    for (int li = 0; li < NL; ++li) {
        const unsigned short* wqkv = WqkvT + (size_t)li * 768 * 256;
        const unsigned short* wm   = WmT + (size_t)li * 65536;
        const unsigned short* w1   = W1T + (size_t)li * 262144;
        const unsigned short* w2   = W2T + (size_t)li * 131072;

        // QKV GEMM writes Q/K/V at sorted padded rows (elu+1 on Q,K)
        mfma_gemm<256, 512, 1><<<dim3(256, 6), 256, 0, stream>>>(xm, wqkv, sortposG, Qs, Ksrt, Vsrt);

        // KV/Ksum: LDS-staged sequential walk, direct global flush, range-checked reduce
        kv_kernel<<<BATCH * NHEAD * KVWIN, 256, 0, stream>>>(Ksrt, Vsrt, psegp, part);
        kv_reduce<<<BATCH * NHEAD * KCLS, 256, 0, stream>>>(part, psegp, KV, Ks);

        // msgb (bf16, original token order) <- attention message (sorted Q, shared KV[c])
        msg_kernel<<<BATCH * NWIN, 256, 0, stream>>>(Qs, KV, Ks, pidxp, wseg, msgb);

        gemm_ln<256, 1><<<512, 256, 0, stream>>>(msgb, wm, g1 + li * DM, b1 + li * DM, nullptr, xm);

        mfma_gemm<512, 512, 2><<<dim3(256, 4), 256, 0, stream>>>(xm, w1, nullptr, hb, nullptr, nullptr);

        gemm_ln<512, 2><<<512, 256, 0, stream>>>(hb, w2, g2 + li * DM, b2 + li * DM, x, xm);
    }
}

// Round 12
// 900.414 us; speedup vs baseline: 1.5837x; 1.0794x over previous
//
#include <hip/hip_runtime.h>
#include <hip/hip_bf16.h>
#include <math.h>

#define DM 256
#define NHEAD 8
#define HD 32
#define NL 4
#define BATCH 8
#define SEQ 4096
#define KCLS 10
#define M_TOK (BATCH*SEQ)   // 32768

#define BM 128
#define BN 128
#define BKG 64

#define PADPOS 5120          // padded sorted positions per batch (each cluster 64-aligned)
#define NWIN (PADPOS/64)     // 80 msg windows per batch
#define KVWIN (PADPOS/512)   // 10 kv windows per batch (512 positions each)
#define PART_STRIDE (KCLS * 1056)   // per-window partial: 10 clusters x (1024 KV + 32 Ks)

using bf16x8 = __attribute__((ext_vector_type(8))) short;
using f32x4  = __attribute__((ext_vector_type(4))) float;

__device__ __forceinline__ unsigned short f2bf(float f) {
    __hip_bfloat16 b = __float2bfloat16(f);
    return __builtin_bit_cast(unsigned short, b);
}
__device__ __forceinline__ float bf2f(unsigned short u) {
    unsigned v = (unsigned)u << 16;
    return __builtin_bit_cast(float, v);
}

__device__ __forceinline__ float wave_reduce_sum(float v) {
    #pragma unroll
    for (int off = 32; off > 0; off >>= 1) v += __shfl_xor(v, off, 64);
    return v;
}

// ---------------- init: x = feat (fp32), xm[:,0:256] = bf16(feat) ----------------
__global__ __launch_bounds__(256) void init_kernel(const float* __restrict__ feat,
                                                   float* __restrict__ x,
                                                   unsigned short* __restrict__ xm) {
    int i = blockIdx.x * 256 + threadIdx.x;      // over M_TOK*64 quads
    int row = i >> 6, c4 = (i & 63) * 4;
    float4 v = *(const float4*)(feat + (size_t)row * DM + c4);
    *(float4*)(x + (size_t)row * DM + c4) = v;
    ushort4 u; u.x = f2bf(v.x); u.y = f2bf(v.y); u.z = f2bf(v.z); u.w = f2bf(v.w);
    *(ushort4*)(xm + (size_t)row * 512 + c4) = u;
}

// ---------------- routing ----------------
__global__ void route_kernel(const float* __restrict__ x, const float* __restrict__ fc,
                             int* __restrict__ seg) {
    int wid = (int)((blockIdx.x * (size_t)blockDim.x + threadIdx.x) >> 6);
    int lane = threadIdx.x & 63;
    if (wid >= M_TOK) return;
    int b = wid / SEQ;
    float4 xv = *(const float4*)(x + (size_t)wid * DM + lane * 4);
    float nb2 = xv.x*xv.x + xv.y*xv.y + xv.z*xv.z + xv.w*xv.w;
    nb2 = wave_reduce_sum(nb2);
    float nb = sqrtf(nb2);
    float best = -1e30f; int bestk = 0;
    for (int k = 0; k < KCLS; ++k) {
        float4 fv = *(const float4*)(fc + ((size_t)(b * KCLS + k)) * DM + lane * 4);
        float d = fv.x*xv.x + fv.y*xv.y + fv.z*xv.z + fv.w*xv.w;
        float n = fv.x*fv.x + fv.y*fv.y + fv.z*fv.z + fv.w*fv.w;
        d = wave_reduce_sum(d);
        n = wave_reduce_sum(n);
        float sim = d / fmaxf(sqrtf(n) * nb, 1e-8f);
        if (sim > best) { best = sim; bestk = k; }
    }
    if (lane == 0) seg[wid] = bestk;
}

// ---------------- deterministic cluster counting-sort (per batch, 64-aligned clusters) ----------------
__global__ __launch_bounds__(256) void seg_count(const int* __restrict__ seg,
                                                 int* __restrict__ cnt) {
    __shared__ int wc[4][KCLS];
    int b = blockIdx.x >> 4, chunk = blockIdx.x & 15;
    int t = threadIdx.x, w = t >> 6, lane = t & 63;
    int c = seg[b * SEQ + chunk * 256 + t];
    #pragma unroll
    for (int cc = 0; cc < KCLS; ++cc) {
        unsigned long long m = __ballot(c == cc);
        if (lane == 0) wc[w][cc] = __popcll(m);
    }
    __syncthreads();
    if (t < KCLS)
        cnt[(b * 16 + chunk) * KCLS + t] = wc[0][t] + wc[1][t] + wc[2][t] + wc[3][t];
}

__global__ __launch_bounds__(256) void seg_scan(const int* __restrict__ cnt,
                                                int* __restrict__ chunkbase,
                                                int* __restrict__ wseg,
                                                int* __restrict__ psegp) {
    __shared__ int sTot[BATCH][KCLS];
    __shared__ int sBase[BATCH][KCLS];
    int tid = threadIdx.x;
    if (tid < BATCH * KCLS) {
        int b = tid / KCLS, c = tid % KCLS;
        int run = 0;
        #pragma unroll
        for (int j = 0; j < 16; ++j) run += cnt[(b * 16 + j) * KCLS + c];
        sTot[b][c] = run;
    }
    __syncthreads();
    if (tid < BATCH) {
        int b = tid, pb = 0;
        for (int c = 0; c < KCLS; ++c) {
            sBase[b][c] = pb;
            int psz = (sTot[b][c] + 63) & ~63;
            int w0 = pb >> 6, w1 = (pb + psz) >> 6;
            for (int w = w0; w < w1; ++w) wseg[b * NWIN + w] = c;
            pb += psz;
        }
        for (int w = pb >> 6; w < NWIN; ++w) wseg[b * NWIN + w] = -1;
    }
    __syncthreads();
    for (int i = tid; i < BATCH * PADPOS; i += 256) {
        int b = i / PADPOS, pos = i % PADPOS;
        int c = KCLS - 1;
        #pragma unroll
        for (int cc = KCLS - 1; cc >= 1; --cc)
            if (pos < sBase[b][cc]) c = cc - 1;
        psegp[i] = c;
    }
    if (tid < BATCH * KCLS) {
        int b = tid / KCLS, c = tid % KCLS;
        int pre = 0;
        #pragma unroll
        for (int j = 0; j < 16; ++j) {
            chunkbase[(b * 16 + j) * KCLS + c] = sBase[b][c] + pre;
            pre += cnt[(b * 16 + j) * KCLS + c];
        }
    }
}

// scatter: pidxp[b][pos] = token; sortposG[b*SEQ+l] = b*PADPOS+pos (inverse perm)
__global__ __launch_bounds__(256) void seg_scatter(const int* __restrict__ seg,
                                                   const int* __restrict__ chunkbase,
                                                   int* __restrict__ pidxp,
                                                   int* __restrict__ sortposG) {
    __shared__ int wc[4][KCLS];
    int b = blockIdx.x >> 4, chunk = blockIdx.x & 15;
    int t = threadIdx.x, w = t >> 6, lane = t & 63;
    int l = chunk * 256 + t;
    int c = seg[b * SEQ + l];
    int rank_w = 0;
    #pragma unroll
    for (int cc = 0; cc < KCLS; ++cc) {
        unsigned long long m = __ballot(c == cc);
        if (lane == 0) wc[w][cc] = __popcll(m);
        if (cc == c) rank_w = __popcll(m & ((1ULL << lane) - 1ULL));
    }
    __syncthreads();
    int rank = rank_w;
    for (int wp = 0; wp < 4; ++wp)
        if (wp < w) rank += wc[wp][c];
    int pos = chunkbase[(b * 16 + chunk) * KCLS + c] + rank;
    pidxp[b * PADPOS + pos] = l;
    sortposG[b * SEQ + l] = b * PADPOS + pos;
}

// ---------------- zero pad rows of sorted K/V (once per launch) ----------------
__global__ __launch_bounds__(256) void zero_pads(const int* __restrict__ pidxp,
                                                 unsigned short* __restrict__ Kb,
                                                 unsigned short* __restrict__ Vb) {
    int row = blockIdx.x * 8 + (threadIdx.x >> 5);   // global padded row
    int c8 = (threadIdx.x & 31) * 8;
    if (pidxp[row] >= 0) return;
    bf16x8 z = (bf16x8){0,0,0,0,0,0,0,0};
    *(bf16x8*)(Kb + (size_t)row * DM + c8) = z;
    *(bf16x8*)(Vb + (size_t)row * DM + c8) = z;
}

// ---------------- weight transpose+convert: src [K][N] fp32 -> dst [N][K] bf16 ----------------
__global__ __launch_bounds__(256) void transpose_bf16(const float* __restrict__ src,
                                                      unsigned short* __restrict__ dst,
                                                      int K, int N) {
    __shared__ float s[64][65];
    int k0 = blockIdx.x * 64, n0 = blockIdx.y * 64;
    int t = threadIdx.x;
    int r = t >> 4, c4 = (t & 15) * 4;
    #pragma unroll
    for (int i = 0; i < 4; ++i) {
        float4 v = *(const float4*)(src + (size_t)(k0 + r + i*16) * N + n0 + c4);
        s[c4+0][r+i*16] = v.x; s[c4+1][r+i*16] = v.y;
        s[c4+2][r+i*16] = v.z; s[c4+3][r+i*16] = v.w;
    }
    __syncthreads();
    #pragma unroll
    for (int i = 0; i < 4; ++i) {
        int nr = r + i*16;
        ushort4 u;
        u.x = f2bf(s[nr][c4+0]); u.y = f2bf(s[nr][c4+1]);
        u.z = f2bf(s[nr][c4+2]); u.w = f2bf(s[nr][c4+3]);
        *(ushort4*)(dst + (size_t)(n0 + nr) * K + k0 + c4) = u;
    }
}

// ---------------- bf16 MFMA GEMM (128x128 tile): out = act( A[M,KD] * Bt[N,KD]^T ) ----------------
// MODE 1: QKV (N=768), outputs written at SORTED rows (sortpos): Ob0=Q(elu+1), Ob1=K(elu+1), Ob2=V
// MODE 2: W1 (N=512): bf16 out Ob0 [M][512], relu (original row order)
template<int KD, int AS, int MODE>
__global__ __launch_bounds__(256) void mfma_gemm(
    const unsigned short* __restrict__ A, const unsigned short* __restrict__ Bt,
    const int* __restrict__ sortpos,
    unsigned short* __restrict__ Ob0, unsigned short* __restrict__ Ob1,
    unsigned short* __restrict__ Ob2)
{
    __shared__ unsigned short As[BM * BKG];
    __shared__ unsigned short Bs[BN * BKG];
    __shared__ int sPos[BM];
    int t = threadIdx.x;
    int lane = t & 63;
    int w = t >> 6;
    int wm = w & 1, wn = w >> 1;         // 2x2 wave grid, each wave 64x64
    int bm = blockIdx.x * BM;
    int bn = blockIdx.y * BN;

    if (MODE == 1 && t < BM) sPos[t] = sortpos[bm + t];

    f32x4 acc[4][4];
    #pragma unroll
    for (int m = 0; m < 4; ++m)
        #pragma unroll
        for (int n = 0; n < 4; ++n)
            acc[m][n] = (f32x4){0.f, 0.f, 0.f, 0.f};

    for (int k0 = 0; k0 < KD; k0 += BKG) {
        #pragma unroll
        for (int i = 0; i < 4; ++i) {
            int chunk = i * 256 + t;
            int row = chunk >> 3, cc = chunk & 7;
            __builtin_amdgcn_global_load_lds(
                (const __attribute__((address_space(1))) void*)(A + (size_t)(bm + row) * AS + k0 + cc * 8),
                (__attribute__((address_space(3))) void*)((char*)As + chunk * 16), 16, 0, 0);
            __builtin_amdgcn_global_load_lds(
                (const __attribute__((address_space(1))) void*)(Bt + (size_t)(bn + row) * KD + k0 + cc * 8),
                (__attribute__((address_space(3))) void*)((char*)Bs + chunk * 16), 16, 0, 0);
        }
        asm volatile("s_waitcnt vmcnt(0)");
        __syncthreads();
        #pragma unroll
        for (int kk = 0; kk < 2; ++kk) {
            int kbyte = (kk * 32 + (lane >> 4) * 8) * 2;
            bf16x8 af[4], bfr[4];
            #pragma unroll
            for (int m = 0; m < 4; ++m)
                af[m] = *(const bf16x8*)((const char*)As + (wm*64 + m*16 + (lane & 15)) * 128 + kbyte);
            #pragma unroll
            for (int n = 0; n < 4; ++n)
                bfr[n] = *(const bf16x8*)((const char*)Bs + (wn*64 + n*16 + (lane & 15)) * 128 + kbyte);
            #pragma unroll
            for (int m = 0; m < 4; ++m)
                #pragma unroll
                for (int n = 0; n < 4; ++n)
                    acc[m][n] = __builtin_amdgcn_mfma_f32_16x16x32_bf16(af[m], bfr[n], acc[m][n], 0, 0, 0);
        }
        __syncthreads();
    }

    int lrow0 = wm * 64 + (lane >> 4) * 4;
    int lcol = wn * 64 + (lane & 15);
    if (MODE == 1) {
        unsigned short* Obuf = (bn < 256) ? Ob0 : (bn < 512) ? Ob1 : Ob2;
        const bool act = (bn < 512);
        int cc0 = (bn & 255) + lcol;
        #pragma unroll
        for (int m = 0; m < 4; ++m)
            #pragma unroll
            for (int n = 0; n < 4; ++n)
                #pragma unroll
                for (int j = 0; j < 4; ++j) {
                    float v = acc[m][n][j];
                    if (act) v = (v > 0.f) ? v + 1.f : expf(v);
                    int drow = sPos[lrow0 + m*16 + j];
                    Obuf[(size_t)drow * 256 + cc0 + n*16] = f2bf(v);
                }
    } else {
        #pragma unroll
        for (int m = 0; m < 4; ++m)
            #pragma unroll
            for (int n = 0; n < 4; ++n)
                #pragma unroll
                for (int j = 0; j < 4; ++j)
                    Ob0[(size_t)(bm + lrow0 + m*16 + j) * 512 + bn + lcol + n*16] =
                        f2bf(fmaxf(acc[m][n][j], 0.f));
    }
}

// ---------------- fused GEMM + LayerNorm (full rows per block: BM=64, BN=256) ----------------
template<int KD, int LNMODE>
__global__ __launch_bounds__(256) void gemm_ln(
    const unsigned short* __restrict__ A, const unsigned short* __restrict__ Bt,
    const float* __restrict__ g, const float* __restrict__ bb,
    float* __restrict__ x, unsigned short* __restrict__ xm)
{
    __shared__ unsigned short As[64 * BKG];
    __shared__ unsigned short Bs[256 * BKG];
    __shared__ float redS[4][64];
    __shared__ float redQ[4][64];
    int t = threadIdx.x;
    int lane = t & 63;
    int w = t >> 6;                      // wave covers cols [w*64, w*64+64)
    int li = lane & 15, lg = lane >> 4;
    int bm = blockIdx.x * 64;

    f32x4 acc[4][4];
    #pragma unroll
    for (int m = 0; m < 4; ++m)
        #pragma unroll
        for (int n = 0; n < 4; ++n)
            acc[m][n] = (f32x4){0.f, 0.f, 0.f, 0.f};

    for (int k0 = 0; k0 < KD; k0 += BKG) {
        #pragma unroll
        for (int i = 0; i < 2; ++i) {
            int chunk = i * 256 + t;
            int row = chunk >> 3, cc = chunk & 7;
            __builtin_amdgcn_global_load_lds(
                (const __attribute__((address_space(1))) void*)(A + (size_t)(bm + row) * KD + k0 + cc * 8),
                (__attribute__((address_space(3))) void*)((char*)As + chunk * 16), 16, 0, 0);
        }
        #pragma unroll
        for (int i = 0; i < 8; ++i) {
            int chunk = i * 256 + t;
            int row = chunk >> 3, cc = chunk & 7;
            __builtin_amdgcn_global_load_lds(
                (const __attribute__((address_space(1))) void*)(Bt + (size_t)row * KD + k0 + cc * 8),
                (__attribute__((address_space(3))) void*)((char*)Bs + chunk * 16), 16, 0, 0);
        }
        asm volatile("s_waitcnt vmcnt(0)");
        __syncthreads();
        #pragma unroll
        for (int kk = 0; kk < 2; ++kk) {
            int kbyte = (kk * 32 + lg * 8) * 2;
            bf16x8 af[4], bfr[4];
            #pragma unroll
            for (int m = 0; m < 4; ++m)
                af[m] = *(const bf16x8*)((const char*)As + (m*16 + li) * 128 + kbyte);
            #pragma unroll
            for (int n = 0; n < 4; ++n)
                bfr[n] = *(const bf16x8*)((const char*)Bs + (w*64 + n*16 + li) * 128 + kbyte);
            #pragma unroll
            for (int m = 0; m < 4; ++m)
                #pragma unroll
                for (int n = 0; n < 4; ++n)
                    acc[m][n] = __builtin_amdgcn_mfma_f32_16x16x32_bf16(af[m], bfr[n], acc[m][n], 0, 0, 0);
        }
        __syncthreads();
    }

    float vs[4][4], vq[4][4];
    #pragma unroll
    for (int m = 0; m < 4; ++m)
        #pragma unroll
        for (int j = 0; j < 4; ++j) {
            float s = 0.f, q = 0.f;
            #pragma unroll
            for (int n = 0; n < 4; ++n) {
                float v = acc[m][n][j];
                s += v; q += v * v;
            }
            #pragma unroll
            for (int msk = 1; msk < 16; msk <<= 1) {
                s += __shfl_xor(s, msk, 64);
                q += __shfl_xor(q, msk, 64);
            }
            vs[m][j] = s; vq[m][j] = q;
        }
    if (li == 0) {
        #pragma unroll
        for (int m = 0; m < 4; ++m)
            #pragma unroll
            for (int j = 0; j < 4; ++j) {
                redS[w][m*16 + lg*4 + j] = vs[m][j];
                redQ[w][m*16 + lg*4 + j] = vq[m][j];
            }
    }
    __syncthreads();

    float gv[4], bv[4];
    #pragma unroll
    for (int n = 0; n < 4; ++n) {
        int col = w*64 + n*16 + li;
        gv[n] = g[col]; bv[n] = bb[col];
    }
    #pragma unroll
    for (int m = 0; m < 4; ++m)
        #pragma unroll
        for (int j = 0; j < 4; ++j) {
            int r = m*16 + lg*4 + j;
            float S = redS[0][r] + redS[1][r] + redS[2][r] + redS[3][r];
            float Q = redQ[0][r] + redQ[1][r] + redQ[2][r] + redQ[3][r];
            float mu = S * (1.f / 256.f);
            float var = Q * (1.f / 256.f) - mu * mu;
            float rs = rsqrtf(var + 1e-5f);
            #pragma unroll
            for (int n = 0; n < 4; ++n) {
                int col = w*64 + n*16 + li;
                float o = gv[n] * (acc[m][n][j] - mu) * rs + bv[n];
                if (LNMODE == 1) {
                    xm[(size_t)(bm + r) * 512 + 256 + col] = f2bf(o);
                } else {
                    size_t idx = (size_t)(bm + r) * 256 + col;
                    float xv = x[idx] + o;
                    x[idx] = xv;
                    xm[(size_t)(bm + r) * 512 + col] = f2bf(xv);
                }
            }
        }
}

// ---------------- KV / Ksum partials: LDS-staged, per-64-group cluster check ----------------
__global__ __launch_bounds__(256) void kv_kernel(
    const unsigned short* __restrict__ Ksrt, const unsigned short* __restrict__ Vsrt,
    const int* __restrict__ psegp, float* __restrict__ part)
{
    __shared__ unsigned short sK[128 * HD];   // 8 KB
    __shared__ unsigned short sV[128 * HD];   // 8 KB
    __shared__ int sSeg[8];                   // cluster id per 64-token group
    int blk = blockIdx.x;
    int s = blk % KVWIN;
    int bh = blk / KVWIN;
    int b = bh >> 3, h = bh & 7;
    int t = threadIdx.x;
    int d = t >> 3, e0 = (t & 7) * 4;

    if (t < 8) sSeg[t] = psegp[b * PADPOS + s * 512 + t * 64];

    const size_t rowbase = (size_t)(b * PADPOS + s * 512);
    float* pb = part + (size_t)blk * PART_STRIDE;

    float4 a = {0.f, 0.f, 0.f, 0.f};
    float ks = 0.f;
    int ccur = -1;

    for (int chunk = 0; chunk < 4; ++chunk) {
        __syncthreads();   // protect LDS reuse (also covers initial sSeg stores)
        // stage 128 rows x 64B of K and V with wide coalesced loads
        #pragma unroll
        for (int rep = 0; rep < 2; ++rep) {
            int idx = rep * 256 + t;             // 512 chunks of 16B per slab
            int row = idx >> 2, off8 = (idx & 3) * 8;
            size_t gsrc = (rowbase + chunk * 128 + row) * DM + h * HD + off8;
            *(bf16x8*)(sK + row * HD + off8) = *(const bf16x8*)(Ksrt + gsrc);
            *(bf16x8*)(sV + row * HD + off8) = *(const bf16x8*)(Vsrt + gsrc);
        }
        __syncthreads();

        #pragma unroll
        for (int g = 0; g < 2; ++g) {
            int c = __builtin_amdgcn_readfirstlane(sSeg[chunk * 2 + g]);
            if (c != ccur) {
                if (ccur >= 0) {
                    *(float4*)(pb + ccur * 1056 + d * 32 + e0) = a;
                    if ((t & 7) == 0) pb[ccur * 1056 + 1024 + d] = ks;
                    a = (float4){0.f, 0.f, 0.f, 0.f};
                    ks = 0.f;
                }
                ccur = c;
            }
            // branch-free 64-token accumulate (cluster-uniform by construction)
            #pragma unroll 8
            for (int l = 0; l < 64; ++l) {
                int lr = g * 64 + l;
                float kd = bf2f(sK[lr * HD + d]);
                ushort4 vu = *(const ushort4*)(sV + lr * HD + e0);
                a.x = fmaf(kd, bf2f(vu.x), a.x);
                a.y = fmaf(kd, bf2f(vu.y), a.y);
                a.z = fmaf(kd, bf2f(vu.z), a.z);
                a.w = fmaf(kd, bf2f(vu.w), a.w);
                ks += kd;
            }
        }
    }
    *(float4*)(pb + ccur * 1056 + d * 32 + e0) = a;
    if ((t & 7) == 0) pb[ccur * 1056 + 1024 + d] = ks;
}

// ---------------- reduce partials -> KV, Ks (window range-check via psegp) ----------------
__global__ __launch_bounds__(256) void kv_reduce(
    const float* __restrict__ part, const int* __restrict__ psegp,
    float* __restrict__ KV, float* __restrict__ Ks)
{
    int blk = blockIdx.x;          // bh * KCLS + c
    int c = blk % KCLS;
    int bh = blk / KCLS;
    int b = bh >> 3, h = bh & 7;
    int t = threadIdx.x;
    const float* pb = part + (size_t)bh * KVWIN * PART_STRIDE + c * 1056;
    float4 acc = {0, 0, 0, 0};
    float ka = 0.f;
    #pragma unroll
    for (int s = 0; s < KVWIN; ++s) {
        int cf = psegp[b * PADPOS + s * 512];
        int cl = psegp[b * PADPOS + s * 512 + 511];
        if (c < cf || c > cl) continue;       // window never flushed cluster c
        float4 v = *(const float4*)(pb + (size_t)s * PART_STRIDE + t * 4);
        acc.x += v.x; acc.y += v.y; acc.z += v.z; acc.w += v.w;
        if (t < 32) ka += pb[(size_t)s * PART_STRIDE + 1024 + t];
    }
    *(float4*)(KV + ((size_t)(b * KCLS + c) * NHEAD + h) * HD * HD + t * 4) = acc;
    if (t < 32) Ks[((size_t)(b * KCLS + c) * NHEAD + h) * HD + t] = ka;
}

// ---------------- msg: 64 cluster-uniform sorted tokens per block (sorted Q, linear reads) ----------------
__global__ __launch_bounds__(256) void msg_kernel(
    const unsigned short* __restrict__ Qs, const float* __restrict__ KV,
    const float* __restrict__ Ks, const int* __restrict__ pidxp,
    const int* __restrict__ wseg, unsigned short* __restrict__ msgb)
{
    int b = blockIdx.x / NWIN, w = blockIdx.x % NWIN;
    int c = wseg[b * NWIN + w];
    if (c < 0) return;
    __shared__ unsigned short sQ[64 * DM];          // 32 KB sorted Q tile (linear)
    __shared__ unsigned short kvb[NHEAD * HD * HD]; // 16 KB bf16 KV[c]
    __shared__ float sKs[NHEAD][HD];
    __shared__ int sTok[64];
    int t = threadIdx.x;

    if (t < 64) sTok[t] = pidxp[b * PADPOS + w * 64 + t];
    { int h = t >> 5, d = t & 31;
      sKs[h][d] = Ks[((size_t)(b * KCLS + c) * NHEAD + h) * HD + d]; }
    const float* kvsrc = KV + (size_t)(b * KCLS + c) * NHEAD * HD * HD;
    #pragma unroll
    for (int i = 0; i < 8; ++i) {
        int q = i * 256 + t;
        float4 v = ((const float4*)kvsrc)[q];
        ushort4 u; u.x = f2bf(v.x); u.y = f2bf(v.y); u.z = f2bf(v.z); u.w = f2bf(v.w);
        ((ushort4*)kvb)[q] = u;
    }
    const unsigned short* qsrc = Qs + (size_t)(b * PADPOS + w * 64) * DM;
    #pragma unroll
    for (int i = 0; i < 8; ++i) {
        int q = i * 256 + t;                 // 2048 chunks of 8 bf16, linear
        *(bf16x8*)(sQ + q * 8) = *(const bf16x8*)(qsrc + q * 8);
    }
    __syncthreads();

    int h = t >> 5, e = t & 31;
    float kvreg[32], ksreg[32];
    #pragma unroll
    for (int d = 0; d < 32; ++d)
        kvreg[d] = bf2f(kvb[h * 1024 + d * 32 + e]);
    #pragma unroll
    for (int d = 0; d < 32; ++d)
        ksreg[d] = sKs[h][d];

    for (int r = 0; r < 64; ++r) {
        float macc = 0.f, zacc = 0.f;
        #pragma unroll
        for (int d8 = 0; d8 < 4; ++d8) {
            bf16x8 qv = *(const bf16x8*)(sQ + r * DM + h * 32 + d8 * 8);
            #pragma unroll
            for (int j = 0; j < 8; ++j) {
                float qf = bf2f((unsigned short)qv[j]);
                macc = fmaf(qf, kvreg[d8 * 8 + j], macc);
                zacc = fmaf(qf, ksreg[d8 * 8 + j], zacc);
            }
        }
        int tok = sTok[r];
        if (tok >= 0)
            msgb[(size_t)(b * SEQ + tok) * DM + t] = f2bf(macc / (zacc + 1e-6f));
    }
}

extern "C" void kernel_launch(void* const* d_in, const int* in_sizes, int n_in,
                              void* d_out, int out_size, void* d_ws, size_t ws_size,
                              hipStream_t stream)
{
    const float* feat = (const float*)d_in[1];
    const float* fc   = (const float*)d_in[2];
    const float* Wq   = (const float*)d_in[3];
    const float* Wk   = (const float*)d_in[4];
    const float* Wv   = (const float*)d_in[5];
    const float* Wm   = (const float*)d_in[6];
    const float* W1   = (const float*)d_in[7];
    const float* W2   = (const float*)d_in[8];
    const float* g1   = (const float*)d_in[9];
    const float* b1   = (const float*)d_in[10];
    const float* g2   = (const float*)d_in[11];
    const float* b2   = (const float*)d_in[12];
    float* x = (float*)d_out;

    char* ws = (char*)d_ws;
    auto alloc = [&](size_t bytes) { char* p = ws; ws += (bytes + 255) & ~(size_t)255; return p; };
    int*   seg    = (int*)  alloc((size_t)M_TOK * 4);
    int*   cnt    = (int*)  alloc((size_t)BATCH * 16 * KCLS * 4);
    int*   cbase  = (int*)  alloc((size_t)BATCH * 16 * KCLS * 4);
    int*   pidxp  = (int*)  alloc((size_t)BATCH * PADPOS * 4);
    int*   psegp  = (int*)  alloc((size_t)BATCH * PADPOS * 4);
    int*   sortposG = (int*)alloc((size_t)M_TOK * 4);
    int*   wseg   = (int*)  alloc((size_t)BATCH * NWIN * 4);
    float* KV     = (float*)alloc((size_t)BATCH * KCLS * NHEAD * HD * HD * 4);
    float* Ks     = (float*)alloc((size_t)BATCH * KCLS * NHEAD * HD * 4);
    unsigned short* xm = (unsigned short*)alloc((size_t)M_TOK * 512 * 2);
    char* bufA = alloc((size_t)M_TOK * 512 * 2);   // hb bf16 [M][512] / msgb bf16 [M][256] / part (27MB)
    unsigned short* Qs   = (unsigned short*)alloc((size_t)BATCH * PADPOS * DM * 2);
    unsigned short* Ksrt = (unsigned short*)alloc((size_t)BATCH * PADPOS * DM * 2);
    unsigned short* Vsrt = (unsigned short*)alloc((size_t)BATCH * PADPOS * DM * 2);
    unsigned short* WqkvT = (unsigned short*)alloc((size_t)NL * 768 * 256 * 2);
    unsigned short* WmT   = (unsigned short*)alloc((size_t)NL * 256 * 256 * 2);
    unsigned short* W1T   = (unsigned short*)alloc((size_t)NL * 512 * 512 * 2);
    unsigned short* W2T   = (unsigned short*)alloc((size_t)NL * 256 * 512 * 2);

    unsigned short* hb   = (unsigned short*)bufA;
    unsigned short* msgb = (unsigned short*)bufA;
    float*          part = (float*)bufA;           // overlay: dead intervals verified

    for (int li = 0; li < NL; ++li) {
        transpose_bf16<<<dim3(4, 4), 256, 0, stream>>>(Wq + (size_t)li*65536, WqkvT + (size_t)li*768*256, 256, 256);
        transpose_bf16<<<dim3(4, 4), 256, 0, stream>>>(Wk + (size_t)li*65536, WqkvT + (size_t)li*768*256 + 65536, 256, 256);
        transpose_bf16<<<dim3(4, 4), 256, 0, stream>>>(Wv + (size_t)li*65536, WqkvT + (size_t)li*768*256 + 131072, 256, 256);
        transpose_bf16<<<dim3(4, 4), 256, 0, stream>>>(Wm + (size_t)li*65536, WmT + (size_t)li*65536, 256, 256);
        transpose_bf16<<<dim3(8, 8), 256, 0, stream>>>(W1 + (size_t)li*262144, W1T + (size_t)li*262144, 512, 512);
        transpose_bf16<<<dim3(8, 4), 256, 0, stream>>>(W2 + (size_t)li*131072, W2T + (size_t)li*131072, 512, 256);
    }

    init_kernel<<<8192, 256, 0, stream>>>(feat, x, xm);
    route_kernel<<<8192, 256, 0, stream>>>(feat, fc, seg);

    // deterministic padded cluster sort (once; reused by all layers)
    seg_count<<<BATCH * 16, 256, 0, stream>>>(seg, cnt);
    seg_scan<<<1, 256, 0, stream>>>(cnt, cbase, wseg, psegp);
    hipMemsetAsync(pidxp, 0xFF, (size_t)BATCH * PADPOS * 4, stream);
    seg_scatter<<<BATCH * 16, 256, 0, stream>>>(seg, cbase, pidxp, sortposG);
    zero_pads<<<BATCH * PADPOS / 8, 256, 0, stream>>>(pidxp, Ksrt, Vsrt);

    for (int li = 0; li < NL; ++li) {
        const unsigned short* wqkv = WqkvT + (size_t)li * 768 * 256;
        const unsigned short* wm   = WmT + (size_t)li * 65536;
        const unsigned short* w1   = W1T + (size_t)li * 262144;
        const unsigned short* w2   = W2T + (size_t)li * 131072;

        // QKV GEMM writes Q/K/V at sorted padded rows (elu+1 on Q,K)
        mfma_gemm<256, 512, 1><<<dim3(256, 6), 256, 0, stream>>>(xm, wqkv, sortposG, Qs, Ksrt, Vsrt);

        // KV/Ksum: LDS-staged walk, per-64-group check, direct flush, range-checked reduce
        kv_kernel<<<BATCH * NHEAD * KVWIN, 256, 0, stream>>>(Ksrt, Vsrt, psegp, part);
        kv_reduce<<<BATCH * NHEAD * KCLS, 256, 0, stream>>>(part, psegp, KV, Ks);

        // msgb (bf16, original token order) <- attention message (sorted Q, shared KV[c])
        msg_kernel<<<BATCH * NWIN, 256, 0, stream>>>(Qs, KV, Ks, pidxp, wseg, msgb);

        gemm_ln<256, 1><<<512, 256, 0, stream>>>(msgb, wm, g1 + li * DM, b1 + li * DM, nullptr, xm);

        mfma_gemm<512, 512, 2><<<dim3(256, 4), 256, 0, stream>>>(xm, w1, nullptr, hb, nullptr, nullptr);

        gemm_ln<512, 2><<<512, 256, 0, stream>>>(hb, w2, g2 + li * DM, b2 + li * DM, x, xm);
    }
}

// Round 13
// 852.685 us; speedup vs baseline: 1.6724x; 1.0560x over previous
//
#include <hip/hip_runtime.h>
#include <hip/hip_bf16.h>
#include <math.h>

#define DM 256
#define NHEAD 8
#define HD 32
#define NL 4
#define BATCH 8
#define SEQ 4096
#define KCLS 10
#define M_TOK (BATCH*SEQ)   // 32768

#define BKG 64

#define PADPOS 5120          // padded sorted positions per batch (each cluster 64-aligned)
#define NWIN (PADPOS/64)     // 80 msg windows per batch
#define KVWIN (PADPOS/512)   // 10 kv windows per batch (512 positions each)
#define PART_STRIDE (KCLS * 1056)   // per-window partial: 10 clusters x (1024 KV + 32 Ks)

using bf16x8 = __attribute__((ext_vector_type(8))) short;
using f32x4  = __attribute__((ext_vector_type(4))) float;

__device__ __forceinline__ unsigned short f2bf(float f) {
    __hip_bfloat16 b = __float2bfloat16(f);
    return __builtin_bit_cast(unsigned short, b);
}
__device__ __forceinline__ float bf2f(unsigned short u) {
    unsigned v = (unsigned)u << 16;
    return __builtin_bit_cast(float, v);
}

__device__ __forceinline__ float wave_reduce_sum(float v) {
    #pragma unroll
    for (int off = 32; off > 0; off >>= 1) v += __shfl_xor(v, off, 64);
    return v;
}

// ---------------- fc norms: fcn[b*KCLS+k] = ||fc[b,k]|| (bitwise-identical reduce) ----------------
__global__ __launch_bounds__(64) void fcn_kernel(const float* __restrict__ fc,
                                                 float* __restrict__ fcn) {
    int bk = blockIdx.x;
    int lane = threadIdx.x;
    float4 fv = *(const float4*)(fc + (size_t)bk * DM + lane * 4);
    float n = fv.x*fv.x + fv.y*fv.y + fv.z*fv.z + fv.w*fv.w;
    n = wave_reduce_sum(n);
    if (lane == 0) fcn[bk] = sqrtf(n);
}

// ---------------- fused init + routing: x = feat, xm[:,0:256] = bf16(feat), seg = argmax ----------------
__global__ void route_kernel(const float* __restrict__ feat, const float* __restrict__ fc,
                             const float* __restrict__ fcn,
                             float* __restrict__ x, unsigned short* __restrict__ xm,
                             int* __restrict__ seg) {
    int wid = (int)((blockIdx.x * (size_t)blockDim.x + threadIdx.x) >> 6);
    int lane = threadIdx.x & 63;
    if (wid >= M_TOK) return;
    int b = wid / SEQ;
    float4 xv = *(const float4*)(feat + (size_t)wid * DM + lane * 4);
    *(float4*)(x + (size_t)wid * DM + lane * 4) = xv;
    ushort4 u; u.x = f2bf(xv.x); u.y = f2bf(xv.y); u.z = f2bf(xv.z); u.w = f2bf(xv.w);
    *(ushort4*)(xm + (size_t)wid * 512 + lane * 4) = u;
    float nb2 = xv.x*xv.x + xv.y*xv.y + xv.z*xv.z + xv.w*xv.w;
    nb2 = wave_reduce_sum(nb2);
    float nb = sqrtf(nb2);
    float best = -1e30f; int bestk = 0;
    for (int k = 0; k < KCLS; ++k) {
        float4 fv = *(const float4*)(fc + ((size_t)(b * KCLS + k)) * DM + lane * 4);
        float d = fv.x*xv.x + fv.y*xv.y + fv.z*xv.z + fv.w*xv.w;
        d = wave_reduce_sum(d);
        float sim = d / fmaxf(fcn[b * KCLS + k] * nb, 1e-8f);
        if (sim > best) { best = sim; bestk = k; }
    }
    if (lane == 0) seg[wid] = bestk;
}

// ---------------- deterministic cluster counting-sort (per batch, 64-aligned clusters) ----------------
__global__ __launch_bounds__(256) void seg_count(const int* __restrict__ seg,
                                                 int* __restrict__ cnt) {
    __shared__ int wc[4][KCLS];
    int b = blockIdx.x >> 4, chunk = blockIdx.x & 15;
    int t = threadIdx.x, w = t >> 6, lane = t & 63;
    int c = seg[b * SEQ + chunk * 256 + t];
    #pragma unroll
    for (int cc = 0; cc < KCLS; ++cc) {
        unsigned long long m = __ballot(c == cc);
        if (lane == 0) wc[w][cc] = __popcll(m);
    }
    __syncthreads();
    if (t < KCLS)
        cnt[(b * 16 + chunk) * KCLS + t] = wc[0][t] + wc[1][t] + wc[2][t] + wc[3][t];
}

__global__ __launch_bounds__(256) void seg_scan(const int* __restrict__ cnt,
                                                int* __restrict__ chunkbase,
                                                int* __restrict__ wseg,
                                                int* __restrict__ psegp) {
    __shared__ int sTot[BATCH][KCLS];
    __shared__ int sBase[BATCH][KCLS];
    int tid = threadIdx.x;
    if (tid < BATCH * KCLS) {
        int b = tid / KCLS, c = tid % KCLS;
        int run = 0;
        #pragma unroll
        for (int j = 0; j < 16; ++j) run += cnt[(b * 16 + j) * KCLS + c];
        sTot[b][c] = run;
    }
    __syncthreads();
    if (tid < BATCH) {
        int b = tid, pb = 0;
        for (int c = 0; c < KCLS; ++c) {
            sBase[b][c] = pb;
            int psz = (sTot[b][c] + 63) & ~63;
            int w0 = pb >> 6, w1 = (pb + psz) >> 6;
            for (int w = w0; w < w1; ++w) wseg[b * NWIN + w] = c;
            pb += psz;
        }
        for (int w = pb >> 6; w < NWIN; ++w) wseg[b * NWIN + w] = -1;
    }
    __syncthreads();
    for (int i = tid; i < BATCH * PADPOS; i += 256) {
        int b = i / PADPOS, pos = i % PADPOS;
        int c = KCLS - 1;
        #pragma unroll
        for (int cc = KCLS - 1; cc >= 1; --cc)
            if (pos < sBase[b][cc]) c = cc - 1;
        psegp[i] = c;
    }
    if (tid < BATCH * KCLS) {
        int b = tid / KCLS, c = tid % KCLS;
        int pre = 0;
        #pragma unroll
        for (int j = 0; j < 16; ++j) {
            chunkbase[(b * 16 + j) * KCLS + c] = sBase[b][c] + pre;
            pre += cnt[(b * 16 + j) * KCLS + c];
        }
    }
}

// scatter: pidxp[b][pos] = token; sortposG[b*SEQ+l] = b*PADPOS+pos (inverse perm)
__global__ __launch_bounds__(256) void seg_scatter(const int* __restrict__ seg,
                                                   const int* __restrict__ chunkbase,
                                                   int* __restrict__ pidxp,
                                                   int* __restrict__ sortposG) {
    __shared__ int wc[4][KCLS];
    int b = blockIdx.x >> 4, chunk = blockIdx.x & 15;
    int t = threadIdx.x, w = t >> 6, lane = t & 63;
    int l = chunk * 256 + t;
    int c = seg[b * SEQ + l];
    int rank_w = 0;
    #pragma unroll
    for (int cc = 0; cc < KCLS; ++cc) {
        unsigned long long m = __ballot(c == cc);
        if (lane == 0) wc[w][cc] = __popcll(m);
        if (cc == c) rank_w = __popcll(m & ((1ULL << lane) - 1ULL));
    }
    __syncthreads();
    int rank = rank_w;
    for (int wp = 0; wp < 4; ++wp)
        if (wp < w) rank += wc[wp][c];
    int pos = chunkbase[(b * 16 + chunk) * KCLS + c] + rank;
    pidxp[b * PADPOS + pos] = l;
    sortposG[b * SEQ + l] = b * PADPOS + pos;
}

// ---------------- zero pad rows of sorted K/V (once per launch) ----------------
__global__ __launch_bounds__(256) void zero_pads(const int* __restrict__ pidxp,
                                                 unsigned short* __restrict__ Kb,
                                                 unsigned short* __restrict__ Vb) {
    int row = blockIdx.x * 8 + (threadIdx.x >> 5);   // global padded row
    int c8 = (threadIdx.x & 31) * 8;
    if (pidxp[row] >= 0) return;
    bf16x8 z = (bf16x8){0,0,0,0,0,0,0,0};
    *(bf16x8*)(Kb + (size_t)row * DM + c8) = z;
    *(bf16x8*)(Vb + (size_t)row * DM + c8) = z;
}

// ---------------- weight transpose+convert: src [K][N] fp32 -> dst [N][K] bf16 ----------------
__global__ __launch_bounds__(256) void transpose_bf16(const float* __restrict__ src,
                                                      unsigned short* __restrict__ dst,
                                                      int K, int N) {
    __shared__ float s[64][65];
    int k0 = blockIdx.x * 64, n0 = blockIdx.y * 64;
    int t = threadIdx.x;
    int r = t >> 4, c4 = (t & 15) * 4;
    #pragma unroll
    for (int i = 0; i < 4; ++i) {
        float4 v = *(const float4*)(src + (size_t)(k0 + r + i*16) * N + n0 + c4);
        s[c4+0][r+i*16] = v.x; s[c4+1][r+i*16] = v.y;
        s[c4+2][r+i*16] = v.z; s[c4+3][r+i*16] = v.w;
    }
    __syncthreads();
    #pragma unroll
    for (int i = 0; i < 4; ++i) {
        int nr = r + i*16;
        ushort4 u;
        u.x = f2bf(s[nr][c4+0]); u.y = f2bf(s[nr][c4+1]);
        u.z = f2bf(s[nr][c4+2]); u.w = f2bf(s[nr][c4+3]);
        *(ushort4*)(dst + (size_t)(n0 + nr) * K + k0 + c4) = u;
    }
}

// ---------------- bf16 MFMA GEMM (128x256 tile, 8 waves): out = act( A[M,KD] * Bt[N,KD]^T ) ----------------
// MODE 1: QKV (N=768, BN=256 -> block-uniform out): rows written at SORTED positions (sortpos)
// MODE 2: W1 (N=512): bf16 out Ob0 [M][512], relu (original row order)
template<int KD, int AS, int MODE>
__global__ __launch_bounds__(512, 4) void mfma_gemm(
    const unsigned short* __restrict__ A, const unsigned short* __restrict__ Bt,
    const int* __restrict__ sortpos,
    unsigned short* __restrict__ Ob0, unsigned short* __restrict__ Ob1,
    unsigned short* __restrict__ Ob2)
{
    __shared__ unsigned short As[128 * BKG];   // 16 KB
    __shared__ unsigned short Bs[256 * BKG];   // 32 KB
    __shared__ int sPos[128];
    int t = threadIdx.x;
    int lane = t & 63;
    int w = t >> 6;                      // 8 waves: wm = w&1 (M 64-half), wn = w>>1 (N 64-quarter)
    int wm = w & 1, wn = w >> 1;
    int bm = blockIdx.x * 128;
    int bn = blockIdx.y * 256;

    if (MODE == 1 && t < 128) sPos[t] = sortpos[bm + t];

    f32x4 acc[4][4];
    #pragma unroll
    for (int m = 0; m < 4; ++m)
        #pragma unroll
        for (int n = 0; n < 4; ++n)
            acc[m][n] = (f32x4){0.f, 0.f, 0.f, 0.f};

    for (int k0 = 0; k0 < KD; k0 += BKG) {
        #pragma unroll
        for (int i = 0; i < 2; ++i) {
            int chunk = i * 512 + t;
            int row = chunk >> 3, cc = chunk & 7;
            __builtin_amdgcn_global_load_lds(
                (const __attribute__((address_space(1))) void*)(A + (size_t)(bm + row) * AS + k0 + cc * 8),
                (__attribute__((address_space(3))) void*)((char*)As + chunk * 16), 16, 0, 0);
        }
        #pragma unroll
        for (int i = 0; i < 4; ++i) {
            int chunk = i * 512 + t;
            int row = chunk >> 3, cc = chunk & 7;
            __builtin_amdgcn_global_load_lds(
                (const __attribute__((address_space(1))) void*)(Bt + (size_t)(bn + row) * KD + k0 + cc * 8),
                (__attribute__((address_space(3))) void*)((char*)Bs + chunk * 16), 16, 0, 0);
        }
        asm volatile("s_waitcnt vmcnt(0)");
        __syncthreads();
        #pragma unroll
        for (int kk = 0; kk < 2; ++kk) {
            int kbyte = (kk * 32 + (lane >> 4) * 8) * 2;
            bf16x8 af[4], bfr[4];
            #pragma unroll
            for (int m = 0; m < 4; ++m)
                af[m] = *(const bf16x8*)((const char*)As + (wm*64 + m*16 + (lane & 15)) * 128 + kbyte);
            #pragma unroll
            for (int n = 0; n < 4; ++n)
                bfr[n] = *(const bf16x8*)((const char*)Bs + (wn*64 + n*16 + (lane & 15)) * 128 + kbyte);
            #pragma unroll
            for (int m = 0; m < 4; ++m)
                #pragma unroll
                for (int n = 0; n < 4; ++n)
                    acc[m][n] = __builtin_amdgcn_mfma_f32_16x16x32_bf16(af[m], bfr[n], acc[m][n], 0, 0, 0);
        }
        __syncthreads();
    }

    int lrow0 = wm * 64 + (lane >> 4) * 4;
    int lcol = wn * 64 + (lane & 15);
    if (MODE == 1) {
        unsigned short* Obuf = (bn < 256) ? Ob0 : (bn < 512) ? Ob1 : Ob2;
        const bool act = (bn < 512);
        #pragma unroll
        for (int m = 0; m < 4; ++m)
            #pragma unroll
            for (int n = 0; n < 4; ++n)
                #pragma unroll
                for (int j = 0; j < 4; ++j) {
                    float v = acc[m][n][j];
                    if (act) v = (v > 0.f) ? v + 1.f : expf(v);
                    int drow = sPos[lrow0 + m*16 + j];
                    Obuf[(size_t)drow * 256 + lcol + n*16] = f2bf(v);
                }
    } else {
        #pragma unroll
        for (int m = 0; m < 4; ++m)
            #pragma unroll
            for (int n = 0; n < 4; ++n)
                #pragma unroll
                for (int j = 0; j < 4; ++j)
                    Ob0[(size_t)(bm + lrow0 + m*16 + j) * 512 + bn + lcol + n*16] =
                        f2bf(fmaxf(acc[m][n][j], 0.f));
    }
}

// ---------------- fused GEMM + LayerNorm (full rows per block: BM=64, BN=256) ----------------
template<int KD, int LNMODE>
__global__ __launch_bounds__(256) void gemm_ln(
    const unsigned short* __restrict__ A, const unsigned short* __restrict__ Bt,
    const float* __restrict__ g, const float* __restrict__ bb,
    float* __restrict__ x, unsigned short* __restrict__ xm)
{
    __shared__ unsigned short As[64 * BKG];
    __shared__ unsigned short Bs[256 * BKG];
    __shared__ float redS[4][64];
    __shared__ float redQ[4][64];
    int t = threadIdx.x;
    int lane = t & 63;
    int w = t >> 6;                      // wave covers cols [w*64, w*64+64)
    int li = lane & 15, lg = lane >> 4;
    int bm = blockIdx.x * 64;

    f32x4 acc[4][4];
    #pragma unroll
    for (int m = 0; m < 4; ++m)
        #pragma unroll
        for (int n = 0; n < 4; ++n)
            acc[m][n] = (f32x4){0.f, 0.f, 0.f, 0.f};

    for (int k0 = 0; k0 < KD; k0 += BKG) {
        #pragma unroll
        for (int i = 0; i < 2; ++i) {
            int chunk = i * 256 + t;
            int row = chunk >> 3, cc = chunk & 7;
            __builtin_amdgcn_global_load_lds(
                (const __attribute__((address_space(1))) void*)(A + (size_t)(bm + row) * KD + k0 + cc * 8),
                (__attribute__((address_space(3))) void*)((char*)As + chunk * 16), 16, 0, 0);
        }
        #pragma unroll
        for (int i = 0; i < 8; ++i) {
            int chunk = i * 256 + t;
            int row = chunk >> 3, cc = chunk & 7;
            __builtin_amdgcn_global_load_lds(
                (const __attribute__((address_space(1))) void*)(Bt + (size_t)row * KD + k0 + cc * 8),
                (__attribute__((address_space(3))) void*)((char*)Bs + chunk * 16), 16, 0, 0);
        }
        asm volatile("s_waitcnt vmcnt(0)");
        __syncthreads();
        #pragma unroll
        for (int kk = 0; kk < 2; ++kk) {
            int kbyte = (kk * 32 + lg * 8) * 2;
            bf16x8 af[4], bfr[4];
            #pragma unroll
            for (int m = 0; m < 4; ++m)
                af[m] = *(const bf16x8*)((const char*)As + (m*16 + li) * 128 + kbyte);
            #pragma unroll
            for (int n = 0; n < 4; ++n)
                bfr[n] = *(const bf16x8*)((const char*)Bs + (w*64 + n*16 + li) * 128 + kbyte);
            #pragma unroll
            for (int m = 0; m < 4; ++m)
                #pragma unroll
                for (int n = 0; n < 4; ++n)
                    acc[m][n] = __builtin_amdgcn_mfma_f32_16x16x32_bf16(af[m], bfr[n], acc[m][n], 0, 0, 0);
        }
        __syncthreads();
    }

    float vs[4][4], vq[4][4];
    #pragma unroll
    for (int m = 0; m < 4; ++m)
        #pragma unroll
        for (int j = 0; j < 4; ++j) {
            float s = 0.f, q = 0.f;
            #pragma unroll
            for (int n = 0; n < 4; ++n) {
                float v = acc[m][n][j];
                s += v; q += v * v;
            }
            #pragma unroll
            for (int msk = 1; msk < 16; msk <<= 1) {
                s += __shfl_xor(s, msk, 64);
                q += __shfl_xor(q, msk, 64);
            }
            vs[m][j] = s; vq[m][j] = q;
        }
    if (li == 0) {
        #pragma unroll
        for (int m = 0; m < 4; ++m)
            #pragma unroll
            for (int j = 0; j < 4; ++j) {
                redS[w][m*16 + lg*4 + j] = vs[m][j];
                redQ[w][m*16 + lg*4 + j] = vq[m][j];
            }
    }
    __syncthreads();

    float gv[4], bv[4];
    #pragma unroll
    for (int n = 0; n < 4; ++n) {
        int col = w*64 + n*16 + li;
        gv[n] = g[col]; bv[n] = bb[col];
    }
    #pragma unroll
    for (int m = 0; m < 4; ++m)
        #pragma unroll
        for (int j = 0; j < 4; ++j) {
            int r = m*16 + lg*4 + j;
            float S = redS[0][r] + redS[1][r] + redS[2][r] + redS[3][r];
            float Q = redQ[0][r] + redQ[1][r] + redQ[2][r] + redQ[3][r];
            float mu = S * (1.f / 256.f);
            float var = Q * (1.f / 256.f) - mu * mu;
            float rs = rsqrtf(var + 1e-5f);
            #pragma unroll
            for (int n = 0; n < 4; ++n) {
                int col = w*64 + n*16 + li;
                float o = gv[n] * (acc[m][n][j] - mu) * rs + bv[n];
                if (LNMODE == 1) {
                    xm[(size_t)(bm + r) * 512 + 256 + col] = f2bf(o);
                } else {
                    size_t idx = (size_t)(bm + r) * 256 + col;
                    float xv = x[idx] + o;
                    x[idx] = xv;
                    xm[(size_t)(bm + r) * 512 + col] = f2bf(xv);
                }
            }
        }
}

// ---------------- KV / Ksum partials: LDS-staged, per-64-group cluster check ----------------
__global__ __launch_bounds__(256) void kv_kernel(
    const unsigned short* __restrict__ Ksrt, const unsigned short* __restrict__ Vsrt,
    const int* __restrict__ psegp, float* __restrict__ part)
{
    __shared__ unsigned short sK[128 * HD];   // 8 KB
    __shared__ unsigned short sV[128 * HD];   // 8 KB
    __shared__ int sSeg[8];                   // cluster id per 64-token group
    int blk = blockIdx.x;
    int s = blk % KVWIN;
    int bh = blk / KVWIN;
    int b = bh >> 3, h = bh & 7;
    int t = threadIdx.x;
    int d = t >> 3, e0 = (t & 7) * 4;

    if (t < 8) sSeg[t] = psegp[b * PADPOS + s * 512 + t * 64];

    const size_t rowbase = (size_t)(b * PADPOS + s * 512);
    float* pb = part + (size_t)blk * PART_STRIDE;

    float4 a = {0.f, 0.f, 0.f, 0.f};
    float ks = 0.f;
    int ccur = -1;

    for (int chunk = 0; chunk < 4; ++chunk) {
        __syncthreads();   // protect LDS reuse (also covers initial sSeg stores)
        #pragma unroll
        for (int rep = 0; rep < 2; ++rep) {
            int idx = rep * 256 + t;             // 512 chunks of 16B per slab
            int row = idx >> 2, off8 = (idx & 3) * 8;
            size_t gsrc = (rowbase + chunk * 128 + row) * DM + h * HD + off8;
            *(bf16x8*)(sK + row * HD + off8) = *(const bf16x8*)(Ksrt + gsrc);
            *(bf16x8*)(sV + row * HD + off8) = *(const bf16x8*)(Vsrt + gsrc);
        }
        __syncthreads();

        #pragma unroll
        for (int g = 0; g < 2; ++g) {
            int c = __builtin_amdgcn_readfirstlane(sSeg[chunk * 2 + g]);
            if (c != ccur) {
                if (ccur >= 0) {
                    *(float4*)(pb + ccur * 1056 + d * 32 + e0) = a;
                    if ((t & 7) == 0) pb[ccur * 1056 + 1024 + d] = ks;
                    a = (float4){0.f, 0.f, 0.f, 0.f};
                    ks = 0.f;
                }
                ccur = c;
            }
            #pragma unroll 8
            for (int l = 0; l < 64; ++l) {
                int lr = g * 64 + l;
                float kd = bf2f(sK[lr * HD + d]);
                ushort4 vu = *(const ushort4*)(sV + lr * HD + e0);
                a.x = fmaf(kd, bf2f(vu.x), a.x);
                a.y = fmaf(kd, bf2f(vu.y), a.y);
                a.z = fmaf(kd, bf2f(vu.z), a.z);
                a.w = fmaf(kd, bf2f(vu.w), a.w);
                ks += kd;
            }
        }
    }
    *(float4*)(pb + ccur * 1056 + d * 32 + e0) = a;
    if ((t & 7) == 0) pb[ccur * 1056 + 1024 + d] = ks;
}

// ---------------- reduce partials -> KV, Ks (window range-check via psegp) ----------------
__global__ __launch_bounds__(256) void kv_reduce(
    const float* __restrict__ part, const int* __restrict__ psegp,
    float* __restrict__ KV, float* __restrict__ Ks)
{
    int blk = blockIdx.x;          // bh * KCLS + c
    int c = blk % KCLS;
    int bh = blk / KCLS;
    int b = bh >> 3, h = bh & 7;
    int t = threadIdx.x;
    const float* pb = part + (size_t)bh * KVWIN * PART_STRIDE + c * 1056;
    float4 acc = {0, 0, 0, 0};
    float ka = 0.f;
    #pragma unroll
    for (int s = 0; s < KVWIN; ++s) {
        int cf = psegp[b * PADPOS + s * 512];
        int cl = psegp[b * PADPOS + s * 512 + 511];
        if (c < cf || c > cl) continue;       // window never flushed cluster c
        float4 v = *(const float4*)(pb + (size_t)s * PART_STRIDE + t * 4);
        acc.x += v.x; acc.y += v.y; acc.z += v.z; acc.w += v.w;
        if (t < 32) ka += pb[(size_t)s * PART_STRIDE + 1024 + t];
    }
    *(float4*)(KV + ((size_t)(b * KCLS + c) * NHEAD + h) * HD * HD + t * 4) = acc;
    if (t < 32) Ks[((size_t)(b * KCLS + c) * NHEAD + h) * HD + t] = ka;
}

// ---------------- msg: 64 cluster-uniform sorted tokens per block (sorted Q, linear reads) ----------------
__global__ __launch_bounds__(256) void msg_kernel(
    const unsigned short* __restrict__ Qs, const float* __restrict__ KV,
    const float* __restrict__ Ks, const int* __restrict__ pidxp,
    const int* __restrict__ wseg, unsigned short* __restrict__ msgb)
{
    int b = blockIdx.x / NWIN, w = blockIdx.x % NWIN;
    int c = wseg[b * NWIN + w];
    if (c < 0) return;
    __shared__ unsigned short sQ[64 * DM];          // 32 KB sorted Q tile (linear)
    __shared__ unsigned short kvb[NHEAD * HD * HD]; // 16 KB bf16 KV[c]
    __shared__ float sKs[NHEAD][HD];
    __shared__ int sTok[64];
    int t = threadIdx.x;

    if (t < 64) sTok[t] = pidxp[b * PADPOS + w * 64 + t];
    { int h = t >> 5, d = t & 31;
      sKs[h][d] = Ks[((size_t)(b * KCLS + c) * NHEAD + h) * HD + d]; }
    const float* kvsrc = KV + (size_t)(b * KCLS + c) * NHEAD * HD * HD;
    #pragma unroll
    for (int i = 0; i < 8; ++i) {
        int q = i * 256 + t;
        float4 v = ((const float4*)kvsrc)[q];
        ushort4 u; u.x = f2bf(v.x); u.y = f2bf(v.y); u.z = f2bf(v.z); u.w = f2bf(v.w);
        ((ushort4*)kvb)[q] = u;
    }
    const unsigned short* qsrc = Qs + (size_t)(b * PADPOS + w * 64) * DM;
    #pragma unroll
    for (int i = 0; i < 8; ++i) {
        int q = i * 256 + t;                 // 2048 chunks of 8 bf16, linear
        *(bf16x8*)(sQ + q * 8) = *(const bf16x8*)(qsrc + q * 8);
    }
    __syncthreads();

    int h = t >> 5, e = t & 31;
    float kvreg[32], ksreg[32];
    #pragma unroll
    for (int d = 0; d < 32; ++d)
        kvreg[d] = bf2f(kvb[h * 1024 + d * 32 + e]);
    #pragma unroll
    for (int d = 0; d < 32; ++d)
        ksreg[d] = sKs[h][d];

    for (int r = 0; r < 64; ++r) {
        float macc = 0.f, zacc = 0.f;
        #pragma unroll
        for (int d8 = 0; d8 < 4; ++d8) {
            bf16x8 qv = *(const bf16x8*)(sQ + r * DM + h * 32 + d8 * 8);
            #pragma unroll
            for (int j = 0; j < 8; ++j) {
                float qf = bf2f((unsigned short)qv[j]);
                macc = fmaf(qf, kvreg[d8 * 8 + j], macc);
                zacc = fmaf(qf, ksreg[d8 * 8 + j], zacc);
            }
        }
        int tok = sTok[r];
        if (tok >= 0)
            msgb[(size_t)(b * SEQ + tok) * DM + t] = f2bf(macc / (zacc + 1e-6f));
    }
}

extern "C" void kernel_launch(void* const* d_in, const int* in_sizes, int n_in,
                              void* d_out, int out_size, void* d_ws, size_t ws_size,
                              hipStream_t stream)
{
    const float* feat = (const float*)d_in[1];
    const float* fc   = (const float*)d_in[2];
    const float* Wq   = (const float*)d_in[3];
    const float* Wk   = (const float*)d_in[4];
    const float* Wv   = (const float*)d_in[5];
    const float* Wm   = (const float*)d_in[6];
    const float* W1   = (const float*)d_in[7];
    const float* W2   = (const float*)d_in[8];
    const float* g1   = (const float*)d_in[9];
    const float* b1   = (const float*)d_in[10];
    const float* g2   = (const float*)d_in[11];
    const float* b2   = (const float*)d_in[12];
    float* x = (float*)d_out;

    char* ws = (char*)d_ws;
    auto alloc = [&](size_t bytes) { char* p = ws; ws += (bytes + 255) & ~(size_t)255; return p; };
    int*   seg    = (int*)  alloc((size_t)M_TOK * 4);
    int*   cnt    = (int*)  alloc((size_t)BATCH * 16 * KCLS * 4);
    int*   cbase  = (int*)  alloc((size_t)BATCH * 16 * KCLS * 4);
    int*   pidxp  = (int*)  alloc((size_t)BATCH * PADPOS * 4);
    int*   psegp  = (int*)  alloc((size_t)BATCH * PADPOS * 4);
    int*   sortposG = (int*)alloc((size_t)M_TOK * 4);
    int*   wseg   = (int*)  alloc((size_t)BATCH * NWIN * 4);
    float* fcn    = (float*)alloc((size_t)BATCH * KCLS * 4);
    float* KV     = (float*)alloc((size_t)BATCH * KCLS * NHEAD * HD * HD * 4);
    float* Ks     = (float*)alloc((size_t)BATCH * KCLS * NHEAD * HD * 4);
    unsigned short* xm = (unsigned short*)alloc((size_t)M_TOK * 512 * 2);
    char* bufA = alloc((size_t)M_TOK * 512 * 2);   // hb bf16 [M][512] / msgb bf16 [M][256] / part (27MB)
    unsigned short* Qs   = (unsigned short*)alloc((size_t)BATCH * PADPOS * DM * 2);
    unsigned short* Ksrt = (unsigned short*)alloc((size_t)BATCH * PADPOS * DM * 2);
    unsigned short* Vsrt = (unsigned short*)alloc((size_t)BATCH * PADPOS * DM * 2);
    unsigned short* WqkvT = (unsigned short*)alloc((size_t)NL * 768 * 256 * 2);
    unsigned short* WmT   = (unsigned short*)alloc((size_t)NL * 256 * 256 * 2);
    unsigned short* W1T   = (unsigned short*)alloc((size_t)NL * 512 * 512 * 2);
    unsigned short* W2T   = (unsigned short*)alloc((size_t)NL * 256 * 512 * 2);

    unsigned short* hb   = (unsigned short*)bufA;
    unsigned short* msgb = (unsigned short*)bufA;
    float*          part = (float*)bufA;           // overlay: dead intervals verified

    for (int li = 0; li < NL; ++li) {
        transpose_bf16<<<dim3(4, 4), 256, 0, stream>>>(Wq + (size_t)li*65536, WqkvT + (size_t)li*768*256, 256, 256);
        transpose_bf16<<<dim3(4, 4), 256, 0, stream>>>(Wk + (size_t)li*65536, WqkvT + (size_t)li*768*256 + 65536, 256, 256);
        transpose_bf16<<<dim3(4, 4), 256, 0, stream>>>(Wv + (size_t)li*65536, WqkvT + (size_t)li*768*256 + 131072, 256, 256);
        transpose_bf16<<<dim3(4, 4), 256, 0, stream>>>(Wm + (size_t)li*65536, WmT + (size_t)li*65536, 256, 256);
        transpose_bf16<<<dim3(8, 8), 256, 0, stream>>>(W1 + (size_t)li*262144, W1T + (size_t)li*262144, 512, 512);
        transpose_bf16<<<dim3(8, 4), 256, 0, stream>>>(W2 + (size_t)li*131072, W2T + (size_t)li*131072, 512, 256);
    }

    // fc norms (bitwise-identical reduce), then fused init+route
    fcn_kernel<<<BATCH * KCLS, 64, 0, stream>>>(fc, fcn);
    route_kernel<<<8192, 256, 0, stream>>>(feat, fc, fcn, x, xm, seg);

    // deterministic padded cluster sort (once; reused by all layers)
    seg_count<<<BATCH * 16, 256, 0, stream>>>(seg, cnt);
    seg_scan<<<1, 256, 0, stream>>>(cnt, cbase, wseg, psegp);
    hipMemsetAsync(pidxp, 0xFF, (size_t)BATCH * PADPOS * 4, stream);
    seg_scatter<<<BATCH * 16, 256, 0, stream>>>(seg, cbase, pidxp, sortposG);
    zero_pads<<<BATCH * PADPOS / 8, 256, 0, stream>>>(pidxp, Ksrt, Vsrt);

    for (int li = 0; li < NL; ++li) {
        const unsigned short* wqkv = WqkvT + (size_t)li * 768 * 256;
        const unsigned short* wm   = WmT + (size_t)li * 65536;
        const unsigned short* w1   = W1T + (size_t)li * 262144;
        const unsigned short* w2   = W2T + (size_t)li * 131072;

        // QKV GEMM writes Q/K/V at sorted padded rows (elu+1 on Q,K)
        mfma_gemm<256, 512, 1><<<dim3(256, 3), 512, 0, stream>>>(xm, wqkv, sortposG, Qs, Ksrt, Vsrt);

        // KV/Ksum: LDS-staged walk, per-64-group check, direct flush, range-checked reduce
        kv_kernel<<<BATCH * NHEAD * KVWIN, 256, 0, stream>>>(Ksrt, Vsrt, psegp, part);
        kv_reduce<<<BATCH * NHEAD * KCLS, 256, 0, stream>>>(part, psegp, KV, Ks);

        // msgb (bf16, original token order) <- attention message (sorted Q, shared KV[c])
        msg_kernel<<<BATCH * NWIN, 256, 0, stream>>>(Qs, KV, Ks, pidxp, wseg, msgb);

        gemm_ln<256, 1><<<512, 256, 0, stream>>>(msgb, wm, g1 + li * DM, b1 + li * DM, nullptr, xm);

        mfma_gemm<512, 512, 2><<<dim3(256, 2), 512, 0, stream>>>(xm, w1, nullptr, hb, nullptr, nullptr);

        gemm_ln<512, 2><<<512, 256, 0, stream>>>(hb, w2, g2 + li * DM, b2 + li * DM, x, xm);
    }
}

// Round 14
// 781.852 us; speedup vs baseline: 1.8239x; 1.0906x over previous
//
#include <hip/hip_runtime.h>
#include <hip/hip_bf16.h>
#include <math.h>

#define DM 256
#define NHEAD 8
#define HD 32
#define NL 4
#define BATCH 8
#define SEQ 4096
#define KCLS 10
#define M_TOK (BATCH*SEQ)   // 32768

#define BKG 64

#define PADPOS 5120          // padded sorted positions per batch (each cluster 64-aligned)
#define NWIN (PADPOS/64)     // 80 msg windows per batch
#define KVWIN (PADPOS/512)   // 10 kv windows per batch (512 positions each)
#define PART_STRIDE (KCLS * 1056)   // per-window partial: 10 clusters x (1024 KV + 32 Ks)

using bf16x8 = __attribute__((ext_vector_type(8))) short;
using f32x4  = __attribute__((ext_vector_type(4))) float;

__device__ __forceinline__ unsigned short f2bf(float f) {
    __hip_bfloat16 b = __float2bfloat16(f);
    return __builtin_bit_cast(unsigned short, b);
}
__device__ __forceinline__ float bf2f(unsigned short u) {
    unsigned v = (unsigned)u << 16;
    return __builtin_bit_cast(float, v);
}

__device__ __forceinline__ float wave_reduce_sum(float v) {
    #pragma unroll
    for (int off = 32; off > 0; off >>= 1) v += __shfl_xor(v, off, 64);
    return v;
}

// ---------------- fc norms: fcn[b*KCLS+k] = ||fc[b,k]|| (bitwise-identical reduce) ----------------
__global__ __launch_bounds__(64) void fcn_kernel(const float* __restrict__ fc,
                                                 float* __restrict__ fcn) {
    int bk = blockIdx.x;
    int lane = threadIdx.x;
    float4 fv = *(const float4*)(fc + (size_t)bk * DM + lane * 4);
    float n = fv.x*fv.x + fv.y*fv.y + fv.z*fv.z + fv.w*fv.w;
    n = wave_reduce_sum(n);
    if (lane == 0) fcn[bk] = sqrtf(n);
}

// ---------------- fused init + routing: x = feat, xm[:,0:256] = bf16(feat), seg = argmax ----------------
__global__ void route_kernel(const float* __restrict__ feat, const float* __restrict__ fc,
                             const float* __restrict__ fcn,
                             float* __restrict__ x, unsigned short* __restrict__ xm,
                             int* __restrict__ seg) {
    int wid = (int)((blockIdx.x * (size_t)blockDim.x + threadIdx.x) >> 6);
    int lane = threadIdx.x & 63;
    if (wid >= M_TOK) return;
    int b = wid / SEQ;
    float4 xv = *(const float4*)(feat + (size_t)wid * DM + lane * 4);
    *(float4*)(x + (size_t)wid * DM + lane * 4) = xv;
    ushort4 u; u.x = f2bf(xv.x); u.y = f2bf(xv.y); u.z = f2bf(xv.z); u.w = f2bf(xv.w);
    *(ushort4*)(xm + (size_t)wid * 512 + lane * 4) = u;
    float nb2 = xv.x*xv.x + xv.y*xv.y + xv.z*xv.z + xv.w*xv.w;
    nb2 = wave_reduce_sum(nb2);
    float nb = sqrtf(nb2);
    float best = -1e30f; int bestk = 0;
    for (int k = 0; k < KCLS; ++k) {
        float4 fv = *(const float4*)(fc + ((size_t)(b * KCLS + k)) * DM + lane * 4);
        float d = fv.x*xv.x + fv.y*xv.y + fv.z*xv.z + fv.w*xv.w;
        d = wave_reduce_sum(d);
        float sim = d / fmaxf(fcn[b * KCLS + k] * nb, 1e-8f);
        if (sim > best) { best = sim; bestk = k; }
    }
    if (lane == 0) seg[wid] = bestk;
}

// ---------------- deterministic cluster counting-sort (per batch, 64-aligned clusters) ----------------
__global__ __launch_bounds__(256) void seg_count(const int* __restrict__ seg,
                                                 int* __restrict__ cnt) {
    __shared__ int wc[4][KCLS];
    int b = blockIdx.x >> 4, chunk = blockIdx.x & 15;
    int t = threadIdx.x, w = t >> 6, lane = t & 63;
    int c = seg[b * SEQ + chunk * 256 + t];
    #pragma unroll
    for (int cc = 0; cc < KCLS; ++cc) {
        unsigned long long m = __ballot(c == cc);
        if (lane == 0) wc[w][cc] = __popcll(m);
    }
    __syncthreads();
    if (t < KCLS)
        cnt[(b * 16 + chunk) * KCLS + t] = wc[0][t] + wc[1][t] + wc[2][t] + wc[3][t];
}

__global__ __launch_bounds__(256) void seg_scan(const int* __restrict__ cnt,
                                                int* __restrict__ chunkbase,
                                                int* __restrict__ wseg,
                                                int* __restrict__ psegp) {
    __shared__ int sTot[BATCH][KCLS];
    __shared__ int sBase[BATCH][KCLS];
    int tid = threadIdx.x;
    if (tid < BATCH * KCLS) {
        int b = tid / KCLS, c = tid % KCLS;
        int run = 0;
        #pragma unroll
        for (int j = 0; j < 16; ++j) run += cnt[(b * 16 + j) * KCLS + c];
        sTot[b][c] = run;
    }
    __syncthreads();
    if (tid < BATCH) {
        int b = tid, pb = 0;
        for (int c = 0; c < KCLS; ++c) {
            sBase[b][c] = pb;
            int psz = (sTot[b][c] + 63) & ~63;
            int w0 = pb >> 6, w1 = (pb + psz) >> 6;
            for (int w = w0; w < w1; ++w) wseg[b * NWIN + w] = c;
            pb += psz;
        }
        for (int w = pb >> 6; w < NWIN; ++w) wseg[b * NWIN + w] = -1;
    }
    __syncthreads();
    for (int i = tid; i < BATCH * PADPOS; i += 256) {
        int b = i / PADPOS, pos = i % PADPOS;
        int c = KCLS - 1;
        #pragma unroll
        for (int cc = KCLS - 1; cc >= 1; --cc)
            if (pos < sBase[b][cc]) c = cc - 1;
        psegp[i] = c;
    }
    if (tid < BATCH * KCLS) {
        int b = tid / KCLS, c = tid % KCLS;
        int pre = 0;
        #pragma unroll
        for (int j = 0; j < 16; ++j) {
            chunkbase[(b * 16 + j) * KCLS + c] = sBase[b][c] + pre;
            pre += cnt[(b * 16 + j) * KCLS + c];
        }
    }
}

// scatter: pidxp[b][pos] = token; sortposG[b*SEQ+l] = b*PADPOS+pos (inverse perm)
__global__ __launch_bounds__(256) void seg_scatter(const int* __restrict__ seg,
                                                   const int* __restrict__ chunkbase,
                                                   int* __restrict__ pidxp,
                                                   int* __restrict__ sortposG) {
    __shared__ int wc[4][KCLS];
    int b = blockIdx.x >> 4, chunk = blockIdx.x & 15;
    int t = threadIdx.x, w = t >> 6, lane = t & 63;
    int l = chunk * 256 + t;
    int c = seg[b * SEQ + l];
    int rank_w = 0;
    #pragma unroll
    for (int cc = 0; cc < KCLS; ++cc) {
        unsigned long long m = __ballot(c == cc);
        if (lane == 0) wc[w][cc] = __popcll(m);
        if (cc == c) rank_w = __popcll(m & ((1ULL << lane) - 1ULL));
    }
    __syncthreads();
    int rank = rank_w;
    for (int wp = 0; wp < 4; ++wp)
        if (wp < w) rank += wc[wp][c];
    int pos = chunkbase[(b * 16 + chunk) * KCLS + c] + rank;
    pidxp[b * PADPOS + pos] = l;
    sortposG[b * SEQ + l] = b * PADPOS + pos;
}

// ---------------- zero pad rows of sorted K/V (once per launch) ----------------
__global__ __launch_bounds__(256) void zero_pads(const int* __restrict__ pidxp,
                                                 unsigned short* __restrict__ Kb,
                                                 unsigned short* __restrict__ Vb) {
    int row = blockIdx.x * 8 + (threadIdx.x >> 5);   // global padded row
    int c8 = (threadIdx.x & 31) * 8;
    if (pidxp[row] >= 0) return;
    bf16x8 z = (bf16x8){0,0,0,0,0,0,0,0};
    *(bf16x8*)(Kb + (size_t)row * DM + c8) = z;
    *(bf16x8*)(Vb + (size_t)row * DM + c8) = z;
}

// ---------------- weight transpose+convert: src [K][N] fp32 -> dst [N][K] bf16 ----------------
__global__ __launch_bounds__(256) void transpose_bf16(const float* __restrict__ src,
                                                      unsigned short* __restrict__ dst,
                                                      int K, int N) {
    __shared__ float s[64][65];
    int k0 = blockIdx.x * 64, n0 = blockIdx.y * 64;
    int t = threadIdx.x;
    int r = t >> 4, c4 = (t & 15) * 4;
    #pragma unroll
    for (int i = 0; i < 4; ++i) {
        float4 v = *(const float4*)(src + (size_t)(k0 + r + i*16) * N + n0 + c4);
        s[c4+0][r+i*16] = v.x; s[c4+1][r+i*16] = v.y;
        s[c4+2][r+i*16] = v.z; s[c4+3][r+i*16] = v.w;
    }
    __syncthreads();
    #pragma unroll
    for (int i = 0; i < 4; ++i) {
        int nr = r + i*16;
        ushort4 u;
        u.x = f2bf(s[nr][c4+0]); u.y = f2bf(s[nr][c4+1]);
        u.z = f2bf(s[nr][c4+2]); u.w = f2bf(s[nr][c4+3]);
        *(ushort4*)(dst + (size_t)(n0 + nr) * K + k0 + c4) = u;
    }
}

// ---------------- bf16 MFMA GEMM (128x256 tile, 8 waves): out = act( A[M,KD] * Bt[N,KD]^T ) ----------------
// MODE 1: QKV (N=768, BN=256 -> block-uniform out): rows written at SORTED positions (sortpos)
// MODE 2: W1 (N=512): bf16 out Ob0 [M][512], relu (original row order)
template<int KD, int AS, int MODE>
__global__ __launch_bounds__(512, 4) void mfma_gemm(
    const unsigned short* __restrict__ A, const unsigned short* __restrict__ Bt,
    const int* __restrict__ sortpos,
    unsigned short* __restrict__ Ob0, unsigned short* __restrict__ Ob1,
    unsigned short* __restrict__ Ob2)
{
    __shared__ unsigned short As[128 * BKG];   // 16 KB
    __shared__ unsigned short Bs[256 * BKG];   // 32 KB
    __shared__ int sPos[128];
    int t = threadIdx.x;
    int lane = t & 63;
    int w = t >> 6;                      // 8 waves: wm = w&1 (M 64-half), wn = w>>1 (N 64-quarter)
    int wm = w & 1, wn = w >> 1;
    int bm = blockIdx.x * 128;
    int bn = blockIdx.y * 256;

    if (MODE == 1 && t < 128) sPos[t] = sortpos[bm + t];

    f32x4 acc[4][4];
    #pragma unroll
    for (int m = 0; m < 4; ++m)
        #pragma unroll
        for (int n = 0; n < 4; ++n)
            acc[m][n] = (f32x4){0.f, 0.f, 0.f, 0.f};

    for (int k0 = 0; k0 < KD; k0 += BKG) {
        #pragma unroll
        for (int i = 0; i < 2; ++i) {
            int chunk = i * 512 + t;
            int row = chunk >> 3, cc = chunk & 7;
            __builtin_amdgcn_global_load_lds(
                (const __attribute__((address_space(1))) void*)(A + (size_t)(bm + row) * AS + k0 + cc * 8),
                (__attribute__((address_space(3))) void*)((char*)As + chunk * 16), 16, 0, 0);
        }
        #pragma unroll
        for (int i = 0; i < 4; ++i) {
            int chunk = i * 512 + t;
            int row = chunk >> 3, cc = chunk & 7;
            __builtin_amdgcn_global_load_lds(
                (const __attribute__((address_space(1))) void*)(Bt + (size_t)(bn + row) * KD + k0 + cc * 8),
                (__attribute__((address_space(3))) void*)((char*)Bs + chunk * 16), 16, 0, 0);
        }
        asm volatile("s_waitcnt vmcnt(0)");
        __syncthreads();
        #pragma unroll
        for (int kk = 0; kk < 2; ++kk) {
            int kbyte = (kk * 32 + (lane >> 4) * 8) * 2;
            bf16x8 af[4], bfr[4];
            #pragma unroll
            for (int m = 0; m < 4; ++m)
                af[m] = *(const bf16x8*)((const char*)As + (wm*64 + m*16 + (lane & 15)) * 128 + kbyte);
            #pragma unroll
            for (int n = 0; n < 4; ++n)
                bfr[n] = *(const bf16x8*)((const char*)Bs + (wn*64 + n*16 + (lane & 15)) * 128 + kbyte);
            #pragma unroll
            for (int m = 0; m < 4; ++m)
                #pragma unroll
                for (int n = 0; n < 4; ++n)
                    acc[m][n] = __builtin_amdgcn_mfma_f32_16x16x32_bf16(af[m], bfr[n], acc[m][n], 0, 0, 0);
        }
        __syncthreads();
    }

    int lrow0 = wm * 64 + (lane >> 4) * 4;
    int lcol = wn * 64 + (lane & 15);
    if (MODE == 1) {
        unsigned short* Obuf = (bn < 256) ? Ob0 : (bn < 512) ? Ob1 : Ob2;
        const bool act = (bn < 512);
        #pragma unroll
        for (int m = 0; m < 4; ++m)
            #pragma unroll
            for (int n = 0; n < 4; ++n)
                #pragma unroll
                for (int j = 0; j < 4; ++j) {
                    float v = acc[m][n][j];
                    if (act) v = (v > 0.f) ? v + 1.f : expf(v);
                    int drow = sPos[lrow0 + m*16 + j];
                    Obuf[(size_t)drow * 256 + lcol + n*16] = f2bf(v);
                }
    } else {
        #pragma unroll
        for (int m = 0; m < 4; ++m)
            #pragma unroll
            for (int n = 0; n < 4; ++n)
                #pragma unroll
                for (int j = 0; j < 4; ++j)
                    Ob0[(size_t)(bm + lrow0 + m*16 + j) * 512 + bn + lcol + n*16] =
                        f2bf(fmaxf(acc[m][n][j], 0.f));
    }
}

// ---------------- fused GEMM + LayerNorm (full rows per block: BM=64, BN=256) ----------------
template<int KD, int LNMODE>
__global__ __launch_bounds__(256) void gemm_ln(
    const unsigned short* __restrict__ A, const unsigned short* __restrict__ Bt,
    const float* __restrict__ g, const float* __restrict__ bb,
    float* __restrict__ x, unsigned short* __restrict__ xm)
{
    __shared__ unsigned short As[64 * BKG];
    __shared__ unsigned short Bs[256 * BKG];
    __shared__ float redS[4][64];
    __shared__ float redQ[4][64];
    int t = threadIdx.x;
    int lane = t & 63;
    int w = t >> 6;                      // wave covers cols [w*64, w*64+64)
    int li = lane & 15, lg = lane >> 4;
    int bm = blockIdx.x * 64;

    f32x4 acc[4][4];
    #pragma unroll
    for (int m = 0; m < 4; ++m)
        #pragma unroll
        for (int n = 0; n < 4; ++n)
            acc[m][n] = (f32x4){0.f, 0.f, 0.f, 0.f};

    for (int k0 = 0; k0 < KD; k0 += BKG) {
        #pragma unroll
        for (int i = 0; i < 2; ++i) {
            int chunk = i * 256 + t;
            int row = chunk >> 3, cc = chunk & 7;
            __builtin_amdgcn_global_load_lds(
                (const __attribute__((address_space(1))) void*)(A + (size_t)(bm + row) * KD + k0 + cc * 8),
                (__attribute__((address_space(3))) void*)((char*)As + chunk * 16), 16, 0, 0);
        }
        #pragma unroll
        for (int i = 0; i < 8; ++i) {
            int chunk = i * 256 + t;
            int row = chunk >> 3, cc = chunk & 7;
            __builtin_amdgcn_global_load_lds(
                (const __attribute__((address_space(1))) void*)(Bt + (size_t)row * KD + k0 + cc * 8),
                (__attribute__((address_space(3))) void*)((char*)Bs + chunk * 16), 16, 0, 0);
        }
        asm volatile("s_waitcnt vmcnt(0)");
        __syncthreads();
        #pragma unroll
        for (int kk = 0; kk < 2; ++kk) {
            int kbyte = (kk * 32 + lg * 8) * 2;
            bf16x8 af[4], bfr[4];
            #pragma unroll
            for (int m = 0; m < 4; ++m)
                af[m] = *(const bf16x8*)((const char*)As + (m*16 + li) * 128 + kbyte);
            #pragma unroll
            for (int n = 0; n < 4; ++n)
                bfr[n] = *(const bf16x8*)((const char*)Bs + (w*64 + n*16 + li) * 128 + kbyte);
            #pragma unroll
            for (int m = 0; m < 4; ++m)
                #pragma unroll
                for (int n = 0; n < 4; ++n)
                    acc[m][n] = __builtin_amdgcn_mfma_f32_16x16x32_bf16(af[m], bfr[n], acc[m][n], 0, 0, 0);
        }
        __syncthreads();
    }

    float vs[4][4], vq[4][4];
    #pragma unroll
    for (int m = 0; m < 4; ++m)
        #pragma unroll
        for (int j = 0; j < 4; ++j) {
            float s = 0.f, q = 0.f;
            #pragma unroll
            for (int n = 0; n < 4; ++n) {
                float v = acc[m][n][j];
                s += v; q += v * v;
            }
            #pragma unroll
            for (int msk = 1; msk < 16; msk <<= 1) {
                s += __shfl_xor(s, msk, 64);
                q += __shfl_xor(q, msk, 64);
            }
            vs[m][j] = s; vq[m][j] = q;
        }
    if (li == 0) {
        #pragma unroll
        for (int m = 0; m < 4; ++m)
            #pragma unroll
            for (int j = 0; j < 4; ++j) {
                redS[w][m*16 + lg*4 + j] = vs[m][j];
                redQ[w][m*16 + lg*4 + j] = vq[m][j];
            }
    }
    __syncthreads();

    float gv[4], bv[4];
    #pragma unroll
    for (int n = 0; n < 4; ++n) {
        int col = w*64 + n*16 + li;
        gv[n] = g[col]; bv[n] = bb[col];
    }
    #pragma unroll
    for (int m = 0; m < 4; ++m)
        #pragma unroll
        for (int j = 0; j < 4; ++j) {
            int r = m*16 + lg*4 + j;
            float S = redS[0][r] + redS[1][r] + redS[2][r] + redS[3][r];
            float Q = redQ[0][r] + redQ[1][r] + redQ[2][r] + redQ[3][r];
            float mu = S * (1.f / 256.f);
            float var = Q * (1.f / 256.f) - mu * mu;
            float rs = rsqrtf(var + 1e-5f);
            #pragma unroll
            for (int n = 0; n < 4; ++n) {
                int col = w*64 + n*16 + li;
                float o = gv[n] * (acc[m][n][j] - mu) * rs + bv[n];
                if (LNMODE == 1) {
                    xm[(size_t)(bm + r) * 512 + 256 + col] = f2bf(o);
                } else {
                    size_t idx = (size_t)(bm + r) * 256 + col;
                    float xv = x[idx] + o;
                    x[idx] = xv;
                    xm[(size_t)(bm + r) * 512 + col] = f2bf(xv);
                }
            }
        }
}

// ---------------- KV / Ksum partials: LDS-staged, per-64-group cluster check ----------------
__global__ __launch_bounds__(256) void kv_kernel(
    const unsigned short* __restrict__ Ksrt, const unsigned short* __restrict__ Vsrt,
    const int* __restrict__ psegp, float* __restrict__ part)
{
    __shared__ unsigned short sK[128 * HD];   // 8 KB
    __shared__ unsigned short sV[128 * HD];   // 8 KB
    __shared__ int sSeg[8];                   // cluster id per 64-token group
    int blk = blockIdx.x;
    int s = blk % KVWIN;
    int bh = blk / KVWIN;
    int b = bh >> 3, h = bh & 7;
    int t = threadIdx.x;
    int d = t >> 3, e0 = (t & 7) * 4;

    if (t < 8) sSeg[t] = psegp[b * PADPOS + s * 512 + t * 64];

    const size_t rowbase = (size_t)(b * PADPOS + s * 512);
    float* pb = part + (size_t)blk * PART_STRIDE;

    float4 a = {0.f, 0.f, 0.f, 0.f};
    float ks = 0.f;
    int ccur = -1;

    for (int chunk = 0; chunk < 4; ++chunk) {
        __syncthreads();   // protect LDS reuse (also covers initial sSeg stores)
        #pragma unroll
        for (int rep = 0; rep < 2; ++rep) {
            int idx = rep * 256 + t;             // 512 chunks of 16B per slab
            int row = idx >> 2, off8 = (idx & 3) * 8;
            size_t gsrc = (rowbase + chunk * 128 + row) * DM + h * HD + off8;
            *(bf16x8*)(sK + row * HD + off8) = *(const bf16x8*)(Ksrt + gsrc);
            *(bf16x8*)(sV + row * HD + off8) = *(const bf16x8*)(Vsrt + gsrc);
        }
        __syncthreads();

        #pragma unroll
        for (int g = 0; g < 2; ++g) {
            int c = __builtin_amdgcn_readfirstlane(sSeg[chunk * 2 + g]);
            if (c != ccur) {
                if (ccur >= 0) {
                    *(float4*)(pb + ccur * 1056 + d * 32 + e0) = a;
                    if ((t & 7) == 0) pb[ccur * 1056 + 1024 + d] = ks;
                    a = (float4){0.f, 0.f, 0.f, 0.f};
                    ks = 0.f;
                }
                ccur = c;
            }
            #pragma unroll 8
            for (int l = 0; l < 64; ++l) {
                int lr = g * 64 + l;
                float kd = bf2f(sK[lr * HD + d]);
                ushort4 vu = *(const ushort4*)(sV + lr * HD + e0);
                a.x = fmaf(kd, bf2f(vu.x), a.x);
                a.y = fmaf(kd, bf2f(vu.y), a.y);
                a.z = fmaf(kd, bf2f(vu.z), a.z);
                a.w = fmaf(kd, bf2f(vu.w), a.w);
                ks += kd;
            }
        }
    }
    *(float4*)(pb + ccur * 1056 + d * 32 + e0) = a;
    if ((t & 7) == 0) pb[ccur * 1056 + 1024 + d] = ks;
}

// ---------------- reduce partials -> KV, Ks (window range-check via psegp) ----------------
__global__ __launch_bounds__(256) void kv_reduce(
    const float* __restrict__ part, const int* __restrict__ psegp,
    float* __restrict__ KV, float* __restrict__ Ks)
{
    int blk = blockIdx.x;          // bh * KCLS + c
    int c = blk % KCLS;
    int bh = blk / KCLS;
    int b = bh >> 3, h = bh & 7;
    int t = threadIdx.x;
    const float* pb = part + (size_t)bh * KVWIN * PART_STRIDE + c * 1056;
    float4 acc = {0, 0, 0, 0};
    float ka = 0.f;
    #pragma unroll
    for (int s = 0; s < KVWIN; ++s) {
        int cf = psegp[b * PADPOS + s * 512];
        int cl = psegp[b * PADPOS + s * 512 + 511];
        if (c < cf || c > cl) continue;       // window never flushed cluster c
        float4 v = *(const float4*)(pb + (size_t)s * PART_STRIDE + t * 4);
        acc.x += v.x; acc.y += v.y; acc.z += v.z; acc.w += v.w;
        if (t < 32) ka += pb[(size_t)s * PART_STRIDE + 1024 + t];
    }
    *(float4*)(KV + ((size_t)(b * KCLS + c) * NHEAD + h) * HD * HD + t * 4) = acc;
    if (t < 32) Ks[((size_t)(b * KCLS + c) * NHEAD + h) * HD + t] = ka;
}

// ---------------- msg via MFMA: per window, per head C[64][32] = Qh[64][32] @ KVc_h[32][32] ----------------
__global__ __launch_bounds__(256) void msg_kernel(
    const unsigned short* __restrict__ Qs, const float* __restrict__ KV,
    const float* __restrict__ Ks, const int* __restrict__ pidxp,
    const int* __restrict__ wseg, unsigned short* __restrict__ msgb)
{
    int b = blockIdx.x / NWIN, w = blockIdx.x % NWIN;
    int c = wseg[b * NWIN + w];
    if (c < 0) return;
    __shared__ unsigned short sQ[64 * DM];          // 32 KB sorted Q tile (linear, A operand)
    __shared__ unsigned short kvT[NHEAD * HD * HD]; // 16 KB [h][e][d] = KV[h][d][e] (Bt operand)
    __shared__ float sKs[NHEAD * HD];               // 1 KB
    __shared__ float zl[64 * NHEAD];                // 2 KB  Z[r][h]
    __shared__ int sTok[64];
    int t = threadIdx.x;
    int wv = t >> 6, lane = t & 63;

    if (t < 64) sTok[t] = pidxp[b * PADPOS + w * 64 + t];
    { int h = t >> 5, d = t & 31;
      sKs[h * HD + d] = Ks[((size_t)(b * KCLS + c) * NHEAD + h) * HD + d]; }
    const float* kvsrc = KV + (size_t)(b * KCLS + c) * NHEAD * HD * HD;
    #pragma unroll
    for (int i = 0; i < 8; ++i) {
        int q = i * 256 + t;
        float4 v = ((const float4*)kvsrc)[q];
        int g = q * 4;
        int h = g >> 10, rem = g & 1023;
        int d = rem >> 5, e = rem & 31;          // 4 consecutive e
        kvT[h * 1024 + (e + 0) * 32 + d] = f2bf(v.x);
        kvT[h * 1024 + (e + 1) * 32 + d] = f2bf(v.y);
        kvT[h * 1024 + (e + 2) * 32 + d] = f2bf(v.z);
        kvT[h * 1024 + (e + 3) * 32 + d] = f2bf(v.w);
    }
    const unsigned short* qsrc = Qs + (size_t)(b * PADPOS + w * 64) * DM;
    #pragma unroll
    for (int i = 0; i < 8; ++i) {
        int q = i * 256 + t;                 // 2048 chunks of 8 bf16, linear
        *(bf16x8*)(sQ + q * 8) = *(const bf16x8*)(qsrc + q * 8);
    }
    __syncthreads();

    // Z[r][h] = sum_d Q[r][h*32+d] * Ks[h][d]   (512 jobs / 256 threads)
    #pragma unroll
    for (int i = 0; i < 2; ++i) {
        int idx = i * 256 + t;
        int r = idx >> 3, h = idx & 7;
        float z = 0.f;
        #pragma unroll
        for (int d8 = 0; d8 < 4; ++d8) {
            bf16x8 qv = *(const bf16x8*)(sQ + r * DM + h * 32 + d8 * 8);
            #pragma unroll
            for (int j = 0; j < 8; ++j)
                z = fmaf(bf2f((unsigned short)qv[j]), sKs[h * HD + d8 * 8 + j], z);
        }
        zl[r * NHEAD + h] = z;
    }
    __syncthreads();

    int li = lane & 15, lg = lane >> 4;
    #pragma unroll
    for (int hh = 0; hh < 2; ++hh) {
        int h = wv * 2 + hh;
        f32x4 acc[4][2];
        #pragma unroll
        for (int m = 0; m < 4; ++m)
            #pragma unroll
            for (int n = 0; n < 2; ++n)
                acc[m][n] = (f32x4){0.f, 0.f, 0.f, 0.f};
        bf16x8 bfr[2];
        #pragma unroll
        for (int n = 0; n < 2; ++n)
            bfr[n] = *(const bf16x8*)(kvT + h * 1024 + (n * 16 + li) * 32 + lg * 8);
        #pragma unroll
        for (int m = 0; m < 4; ++m) {
            bf16x8 af = *(const bf16x8*)(sQ + (m * 16 + li) * DM + h * 32 + lg * 8);
            #pragma unroll
            for (int n = 0; n < 2; ++n)
                acc[m][n] = __builtin_amdgcn_mfma_f32_16x16x32_bf16(af, bfr[n], acc[m][n], 0, 0, 0);
        }
        #pragma unroll
        for (int m = 0; m < 4; ++m)
            #pragma unroll
            for (int n = 0; n < 2; ++n)
                #pragma unroll
                for (int j = 0; j < 4; ++j) {
                    int r = m * 16 + lg * 4 + j;
                    int tok = sTok[r];
                    if (tok >= 0) {
                        float o = acc[m][n][j] / (zl[r * NHEAD + h] + 1e-6f);
                        msgb[(size_t)(b * SEQ + tok) * DM + h * 32 + n * 16 + li] = f2bf(o);
                    }
                }
    }
}

extern "C" void kernel_launch(void* const* d_in, const int* in_sizes, int n_in,
                              void* d_out, int out_size, void* d_ws, size_t ws_size,
                              hipStream_t stream)
{
    const float* feat = (const float*)d_in[1];
    const float* fc   = (const float*)d_in[2];
    const float* Wq   = (const float*)d_in[3];
    const float* Wk   = (const float*)d_in[4];
    const float* Wv   = (const float*)d_in[5];
    const float* Wm   = (const float*)d_in[6];
    const float* W1   = (const float*)d_in[7];
    const float* W2   = (const float*)d_in[8];
    const float* g1   = (const float*)d_in[9];
    const float* b1   = (const float*)d_in[10];
    const float* g2   = (const float*)d_in[11];
    const float* b2   = (const float*)d_in[12];
    float* x = (float*)d_out;

    char* ws = (char*)d_ws;
    auto alloc = [&](size_t bytes) { char* p = ws; ws += (bytes + 255) & ~(size_t)255; return p; };
    int*   seg    = (int*)  alloc((size_t)M_TOK * 4);
    int*   cnt    = (int*)  alloc((size_t)BATCH * 16 * KCLS * 4);
    int*   cbase  = (int*)  alloc((size_t)BATCH * 16 * KCLS * 4);
    int*   pidxp  = (int*)  alloc((size_t)BATCH * PADPOS * 4);
    int*   psegp  = (int*)  alloc((size_t)BATCH * PADPOS * 4);
    int*   sortposG = (int*)alloc((size_t)M_TOK * 4);
    int*   wseg   = (int*)  alloc((size_t)BATCH * NWIN * 4);
    float* fcn    = (float*)alloc((size_t)BATCH * KCLS * 4);
    float* KV     = (float*)alloc((size_t)BATCH * KCLS * NHEAD * HD * HD * 4);
    float* Ks     = (float*)alloc((size_t)BATCH * KCLS * NHEAD * HD * 4);
    unsigned short* xm = (unsigned short*)alloc((size_t)M_TOK * 512 * 2);
    char* bufA = alloc((size_t)M_TOK * 512 * 2);   // hb bf16 [M][512] / msgb bf16 [M][256] / part (27MB)
    unsigned short* Qs   = (unsigned short*)alloc((size_t)BATCH * PADPOS * DM * 2);
    unsigned short* Ksrt = (unsigned short*)alloc((size_t)BATCH * PADPOS * DM * 2);
    unsigned short* Vsrt = (unsigned short*)alloc((size_t)BATCH * PADPOS * DM * 2);
    unsigned short* WqkvT = (unsigned short*)alloc((size_t)NL * 768 * 256 * 2);
    unsigned short* WmT   = (unsigned short*)alloc((size_t)NL * 256 * 256 * 2);
    unsigned short* W1T   = (unsigned short*)alloc((size_t)NL * 512 * 512 * 2);
    unsigned short* W2T   = (unsigned short*)alloc((size_t)NL * 256 * 512 * 2);

    unsigned short* hb   = (unsigned short*)bufA;
    unsigned short* msgb = (unsigned short*)bufA;
    float*          part = (float*)bufA;           // overlay: dead intervals verified

    for (int li = 0; li < NL; ++li) {
        transpose_bf16<<<dim3(4, 4), 256, 0, stream>>>(Wq + (size_t)li*65536, WqkvT + (size_t)li*768*256, 256, 256);
        transpose_bf16<<<dim3(4, 4), 256, 0, stream>>>(Wk + (size_t)li*65536, WqkvT + (size_t)li*768*256 + 65536, 256, 256);
        transpose_bf16<<<dim3(4, 4), 256, 0, stream>>>(Wv + (size_t)li*65536, WqkvT + (size_t)li*768*256 + 131072, 256, 256);
        transpose_bf16<<<dim3(4, 4), 256, 0, stream>>>(Wm + (size_t)li*65536, WmT + (size_t)li*65536, 256, 256);
        transpose_bf16<<<dim3(8, 8), 256, 0, stream>>>(W1 + (size_t)li*262144, W1T + (size_t)li*262144, 512, 512);
        transpose_bf16<<<dim3(8, 4), 256, 0, stream>>>(W2 + (size_t)li*131072, W2T + (size_t)li*131072, 512, 256);
    }

    // fc norms (bitwise-identical reduce), then fused init+route
    fcn_kernel<<<BATCH * KCLS, 64, 0, stream>>>(fc, fcn);
    route_kernel<<<8192, 256, 0, stream>>>(feat, fc, fcn, x, xm, seg);

    // deterministic padded cluster sort (once; reused by all layers)
    seg_count<<<BATCH * 16, 256, 0, stream>>>(seg, cnt);
    seg_scan<<<1, 256, 0, stream>>>(cnt, cbase, wseg, psegp);
    hipMemsetAsync(pidxp, 0xFF, (size_t)BATCH * PADPOS * 4, stream);
    seg_scatter<<<BATCH * 16, 256, 0, stream>>>(seg, cbase, pidxp, sortposG);
    zero_pads<<<BATCH * PADPOS / 8, 256, 0, stream>>>(pidxp, Ksrt, Vsrt);

    for (int li = 0; li < NL; ++li) {
        const unsigned short* wqkv = WqkvT + (size_t)li * 768 * 256;
        const unsigned short* wm   = WmT + (size_t)li * 65536;
        const unsigned short* w1   = W1T + (size_t)li * 262144;
        const unsigned short* w2   = W2T + (size_t)li * 131072;

        // QKV GEMM writes Q/K/V at sorted padded rows (elu+1 on Q,K)
        mfma_gemm<256, 512, 1><<<dim3(256, 3), 512, 0, stream>>>(xm, wqkv, sortposG, Qs, Ksrt, Vsrt);

        // KV/Ksum: LDS-staged walk, per-64-group check, direct flush, range-checked reduce
        kv_kernel<<<BATCH * NHEAD * KVWIN, 256, 0, stream>>>(Ksrt, Vsrt, psegp, part);
        kv_reduce<<<BATCH * NHEAD * KCLS, 256, 0, stream>>>(part, psegp, KV, Ks);

        // msgb (bf16, original token order) <- attention message via MFMA
        msg_kernel<<<BATCH * NWIN, 256, 0, stream>>>(Qs, KV, Ks, pidxp, wseg, msgb);

        gemm_ln<256, 1><<<512, 256, 0, stream>>>(msgb, wm, g1 + li * DM, b1 + li * DM, nullptr, xm);

        mfma_gemm<512, 512, 2><<<dim3(256, 2), 512, 0, stream>>>(xm, w1, nullptr, hb, nullptr, nullptr);

        gemm_ln<512, 2><<<512, 256, 0, stream>>>(hb, w2, g2 + li * DM, b2 + li * DM, x, xm);
    }
}